// Round 8
// baseline (710.477 us; speedup 1.0000x reference)
//
#include <hip/hip_runtime.h>
#include <hip/hip_bf16.h>

#define N_NODES 50000
#define N_EDGES 800000
#define DIM 128
#define NLAYERS 3

typedef short bf16x8 __attribute__((ext_vector_type(8)));
typedef float floatx4 __attribute__((ext_vector_type(4)));

__device__ __forceinline__ unsigned short f2bf(float f) {
  unsigned int u = __builtin_bit_cast(unsigned int, f);
  return (unsigned short)((u + 0x7FFFu + ((u >> 16) & 1u)) >> 16);
}
__device__ __forceinline__ float bf2f(unsigned short h) {
  return __builtin_bit_cast(float, (unsigned int)h << 16);
}
__device__ __forceinline__ float bfhi(float f, unsigned short& hb) {
  unsigned int u = __builtin_bit_cast(unsigned int, f);
  unsigned int r = (u + 0x7FFFu + ((u >> 16) & 1u)) & 0xFFFF0000u;
  hb = (unsigned short)(r >> 16);
  return __builtin_bit_cast(float, r);
}
__device__ __forceinline__ float2 bf2f2(unsigned int u) {
  float lo = __builtin_bit_cast(float, u << 16);
  float hi = __builtin_bit_cast(float, u & 0xFFFF0000u);
  return make_float2(lo, hi);
}

// ---------------- embedding gather -> bf16 residual ----------------
__global__ __launch_bounds__(256) void embed_kernel(
    const int* __restrict__ idx, const float* __restrict__ emb,
    unsigned short* __restrict__ xb)
{
  int gid = blockIdx.x * 256 + threadIdx.x;
  int n = gid >> 5;
  int c = (gid & 31) << 2;
  if (n >= N_NODES) return;
  int e = idx[n];
  float4 val = *(const float4*)(emb + (size_t)e * DIM + c);
  ushort4 pk;
  pk.x = f2bf(val.x); pk.y = f2bf(val.y); pk.z = f2bf(val.z); pk.w = f2bf(val.w);
  *(ushort4*)(xb + (size_t)n * DIM + c) = pk;
}

// ---------------- CSR build ----------------
__global__ __launch_bounds__(256) void hist_kernel(
    const int* __restrict__ e1, int* __restrict__ counts)
{
  int i = blockIdx.x * 256 + threadIdx.x;
  if (i < N_EDGES) atomicAdd(&counts[e1[i]], 1);
}

__global__ __launch_bounds__(256) void scan_local(
    const int* __restrict__ counts, int* __restrict__ offsets,
    int* __restrict__ bsums)
{
  __shared__ int buf[256];
  int t = threadIdx.x;
  int i = blockIdx.x * 256 + t;
  int v = (i < N_NODES) ? counts[i] : 0;
  buf[t] = v;
  __syncthreads();
  int s = v;
#pragma unroll
  for (int off = 1; off < 256; off <<= 1) {
    int t2 = (t >= off) ? buf[t - off] : 0;
    __syncthreads();
    s += t2;
    buf[t] = s;
    __syncthreads();
  }
  if (i < N_NODES) offsets[i] = s - v;
  if (t == 255) bsums[blockIdx.x] = s;
}

__global__ void scan_bsums(int* __restrict__ bsums, int nblk)
{
  __shared__ int buf[256];
  int t = threadIdx.x;
  int v = (t < nblk) ? bsums[t] : 0;
  buf[t] = v;
  __syncthreads();
  int s = v;
#pragma unroll
  for (int off = 1; off < 256; off <<= 1) {
    int t2 = (t >= off) ? buf[t - off] : 0;
    __syncthreads();
    s += t2;
    buf[t] = s;
    __syncthreads();
  }
  if (t < nblk) bsums[t] = s - v;
}

__global__ __launch_bounds__(256) void scan_add(
    int* __restrict__ offsets, const int* __restrict__ bsums)
{
  int i = blockIdx.x * 256 + threadIdx.x;
  if (i < N_NODES) offsets[i] += bsums[blockIdx.x];
  if (i == 0) offsets[N_NODES] = N_EDGES;
}

__global__ __launch_bounds__(256) void scatter_kernel(
    const int* __restrict__ e0, const int* __restrict__ e1,
    const int* __restrict__ offsets, int* __restrict__ fill,
    int* __restrict__ csr)
{
  int i = blockIdx.x * 256 + threadIdx.x;
  if (i >= N_EDGES) return;
  int d = e1[i];
  int pos = offsets[d] + atomicAdd(&fill[d], 1);
  csr[pos] = e0[i];
}

// ---------------- combined weight prep (one dispatch) ----------------
// seg A: qkv single-plane (q,k,v -> Ndst 384): 3*3*16*128 = 18432 frags
// seg B: wo hi/lo: 3*16*128 = 6144
// seg C: wf1 hi/lo: 3*16*256 = 12288
// seg D: wf2 hi/lo: 3*32*128 = 12288   total 49152
__global__ __launch_bounds__(256) void prep_all(
    const float* __restrict__ Wq, const float* __restrict__ Wk,
    const float* __restrict__ Wv, const float* __restrict__ Wo,
    const float* __restrict__ Wf1, const float* __restrict__ Wf2,
    unsigned short* __restrict__ wqkv, unsigned short* __restrict__ wo,
    unsigned short* __restrict__ wf1, unsigned short* __restrict__ wf2)
{
  int g = blockIdx.x * 256 + threadIdx.x;
  if (g < 18432) {
    int srcId = g / 6144; int rem = g - srcId * 6144;
    const float* W = (srcId == 0) ? Wq : (srcId == 1) ? Wk : Wv;
    int l = rem / 2048; int r2 = rem & 2047; int kq = r2 >> 7; int n = r2 & 127;
    const float* Wl = W + (size_t)l * 128 * 128;
    unsigned short* base = wqkv + (size_t)l * 128 * 384 + (size_t)(kq * 384 + srcId * 128 + n) * 8;
#pragma unroll
    for (int j = 0; j < 8; j++)
      base[j] = f2bf(Wl[(size_t)(kq * 8 + j) * 128 + n]);
    return;
  }
  g -= 18432;
  if (g < 6144) {   // wo hi/lo
    int l = g / 2048; int r2 = g & 2047; int kq = r2 >> 7; int n = r2 & 127;
    const float* Wl = Wo + (size_t)l * 128 * 128;
    unsigned short* basehi = wo + (size_t)l * 2 * 128 * 128 + (size_t)(kq * 128 + n) * 8;
#pragma unroll
    for (int j = 0; j < 8; j++) {
      float f = Wl[(size_t)(kq * 8 + j) * 128 + n];
      unsigned short hb; float hf = bfhi(f, hb);
      basehi[j] = hb; basehi[16384 + j] = f2bf(f - hf);
    }
    return;
  }
  g -= 6144;
  if (g < 12288) {  // wf1 hi/lo (N=256)
    int l = g / 4096; int r2 = g & 4095; int kq = r2 >> 8; int n = r2 & 255;
    const float* Wl = Wf1 + (size_t)l * 128 * 256;
    unsigned short* basehi = wf1 + (size_t)l * 2 * 128 * 256 + (size_t)(kq * 256 + n) * 8;
#pragma unroll
    for (int j = 0; j < 8; j++) {
      float f = Wl[(size_t)(kq * 8 + j) * 256 + n];
      unsigned short hb; float hf = bfhi(f, hb);
      basehi[j] = hb; basehi[32768 + j] = f2bf(f - hf);
    }
    return;
  }
  g -= 12288;
  if (g < 12288) {  // wf2 hi/lo (K=256, N=128)
    int l = g / 4096; int r2 = g & 4095; int kq = r2 >> 7; int n = r2 & 127;
    const float* Wl = Wf2 + (size_t)l * 256 * 128;
    unsigned short* basehi = wf2 + (size_t)l * 2 * 256 * 128 + (size_t)(kq * 128 + n) * 8;
#pragma unroll
    for (int j = 0; j < 8; j++) {
      float f = Wl[(size_t)(kq * 8 + j) * 128 + n];
      unsigned short hb; float hf = bfhi(f, hb);
      basehi[j] = hb; basehi[32768 + j] = f2bf(f - hf);
    }
  }
}

// ---------------- QKV GEMM (layer 0 only): bf16 A, single-plane W, bf16 out ----------------
__global__ __launch_bounds__(256) void mfma_gemm_qkv(
    const unsigned short* __restrict__ Ab,
    const unsigned short* __restrict__ Wp,
    const float* __restrict__ bq, const float* __restrict__ bk,
    const float* __restrict__ bv,
    unsigned short* __restrict__ out, int nrows)
{
  constexpr int K = 128, N = 384, CT = 8;
  __shared__ unsigned short SW[16 * 128 * 8];   // 32 KB
  int tid = threadIdx.x;
  int c0 = blockIdx.y * 128;
  const float* bias = (blockIdx.y == 0) ? bq : (blockIdx.y == 1) ? bk : bv;
  int wave = tid >> 6, lane = tid & 63;
  int quad = lane >> 4, l16 = lane & 15;
  int row0 = blockIdx.x * 128 + wave * 32;

  floatx4 acc[2][CT];
#pragma unroll
  for (int rt = 0; rt < 2; rt++)
#pragma unroll
    for (int ct = 0; ct < CT; ct++) acc[rt][ct] = (floatx4)(0.f);

  const unsigned short* arow[2];
#pragma unroll
  for (int rt = 0; rt < 2; rt++) {
    int r = min(row0 + rt * 16 + l16, nrows - 1);
    arow[rt] = Ab + (size_t)r * K + quad * 8;
  }
#pragma unroll 4
  for (int f = tid; f < 16 * 128; f += 256) {
    int kq = f >> 7;
    int n = f & 127;
    *(bf16x8*)&SW[f * 8] = *(const bf16x8*)&Wp[(size_t)(kq * N + c0 + n) * 8];
  }
  __syncthreads();
#pragma unroll
  for (int kb = 0; kb < 4; ++kb) {
    bf16x8 av[2];
#pragma unroll
    for (int rt = 0; rt < 2; rt++)
      av[rt] = *(const bf16x8*)(arow[rt] + kb * 32);
#pragma unroll
    for (int ct = 0; ct < CT; ct++) {
      bf16x8 bh = *(bf16x8*)&SW[((kb * 4 + quad) * 128 + ct * 16 + l16) * 8];
#pragma unroll
      for (int rt = 0; rt < 2; rt++)
        acc[rt][ct] = __builtin_amdgcn_mfma_f32_16x16x32_bf16(av[rt], bh, acc[rt][ct], 0, 0, 0);
    }
  }
#pragma unroll
  for (int ct = 0; ct < CT; ct++) {
    float bvv = bias[ct * 16 + l16];
    int col = c0 + ct * 16 + l16;
#pragma unroll
    for (int rt = 0; rt < 2; rt++)
#pragma unroll
      for (int i = 0; i < 4; i++) {
        int r = row0 + rt * 16 + quad * 4 + i;
        if (r < nrows)
          out[(size_t)r * 384 + col] = f2bf(acc[rt][ct][i] + bvv);
      }
  }
}

// ================ chain1: O-GEMM + LN1 + FFN1 ================
// 64 rows/block, 4 waves, 16 rows/wave, barrier-free. B-frags batch-loaded
// (16 loads -> one waitcnt -> 16 MFMAs) for latency hiding.
#define LSTR 136
__global__ __launch_bounds__(256) void chain1_kernel(
    const unsigned short* __restrict__ a,      // [N,128] attn out
    const unsigned short* __restrict__ xb,     // [N,128] residual h (read)
    unsigned short* __restrict__ xr,           // [N,128] x1 out
    unsigned short* __restrict__ ffh,          // [N,256] ffn hidden out
    const unsigned short* __restrict__ wo, const float* __restrict__ bo,
    const float* __restrict__ g1, const float* __restrict__ be1,
    const unsigned short* __restrict__ wf1, const float* __restrict__ bf1,
    int nrows)
{
  __shared__ unsigned short Y[64 * LSTR];  // 17 KB
  int tid = threadIdx.x;
  int wave = tid >> 6, lane = tid & 63;
  int quad = lane >> 4, l16 = lane & 15;
  int rbase = blockIdx.x * 64;
  int wrow = wave * 16;

  // ---- O-GEMM ----
  floatx4 accO[8];
#pragma unroll
  for (int cc = 0; cc < 8; cc++) accO[cc] = (floatx4)(0.f);
  {
    int grA = min(rbase + wrow + l16, nrows - 1);
    const unsigned short* arow = a + (size_t)grA * 128 + quad * 8;
#pragma unroll
    for (int kb = 0; kb < 4; kb++) {
      bf16x8 av = *(const bf16x8*)(arow + kb * 32);
      int kq = kb * 4 + quad;
      bf16x8 bh[8], bl[8];
#pragma unroll
      for (int cc = 0; cc < 8; cc++) {
        const unsigned short* bp = wo + (size_t)(kq * 128 + cc * 16 + l16) * 8;
        bh[cc] = *(const bf16x8*)bp;
        bl[cc] = *(const bf16x8*)(bp + 16384);
      }
#pragma unroll
      for (int cc = 0; cc < 8; cc++) {
        accO[cc] = __builtin_amdgcn_mfma_f32_16x16x32_bf16(av, bh[cc], accO[cc], 0, 0, 0);
        accO[cc] = __builtin_amdgcn_mfma_f32_16x16x32_bf16(av, bl[cc], accO[cc], 0, 0, 0);
      }
    }
  }

  // ---- LN1: x1 = LN(h + y) -> xr; y -> Y (per-wave private) ----
  {
    float biasO[8], g1v[8], b1v[8];
#pragma unroll
    for (int cc = 0; cc < 8; cc++) {
      int col = cc * 16 + l16;
      biasO[cc] = bo[col]; g1v[cc] = g1[col]; b1v[cc] = be1[col];
    }
#pragma unroll
    for (int i = 0; i < 4; i++) {
      int lrow = wrow + quad * 4 + i;
      int grow = rbase + lrow;
      int growc = min(grow, nrows - 1);
      float t[8]; float s = 0.f;
#pragma unroll
      for (int cc = 0; cc < 8; cc++) {
        float yv = accO[cc][i] + biasO[cc];
        Y[lrow * LSTR + cc * 16 + l16] = f2bf(yv);
        t[cc] = yv + bf2f(xb[(size_t)growc * 128 + cc * 16 + l16]);
        s += t[cc];
      }
      s += __shfl_xor(s, 1); s += __shfl_xor(s, 2);
      s += __shfl_xor(s, 4); s += __shfl_xor(s, 8);
      float mean = s * (1.f / 128.f);
      float vv = 0.f;
#pragma unroll
      for (int cc = 0; cc < 8; cc++) { float d = t[cc] - mean; vv += d * d; }
      vv += __shfl_xor(vv, 1); vv += __shfl_xor(vv, 2);
      vv += __shfl_xor(vv, 4); vv += __shfl_xor(vv, 8);
      float inv = rsqrtf(vv * (1.f / 128.f) + 1e-5f);
      if (grow < nrows) {
#pragma unroll
        for (int cc = 0; cc < 8; cc++)
          xr[(size_t)grow * 128 + cc * 16 + l16] =
              f2bf((t[cc] - mean) * inv * g1v[cc] + b1v[cc]);
      }
    }
  }

  // ---- FFN1 (K=128, N=256 in two 128-col halves), relu, -> ffh ----
  bf16x8 avY[4];
#pragma unroll
  for (int kb = 0; kb < 4; kb++)
    avY[kb] = *(bf16x8*)&Y[(wrow + l16) * LSTR + kb * 32 + quad * 8];
#pragma unroll
  for (int h = 0; h < 2; h++) {
    floatx4 accF[8];
#pragma unroll
    for (int cc = 0; cc < 8; cc++) accF[cc] = (floatx4)(0.f);
#pragma unroll
    for (int kb = 0; kb < 4; kb++) {
      int kq = kb * 4 + quad;
      bf16x8 bh[8], bl[8];
#pragma unroll
      for (int cc = 0; cc < 8; cc++) {
        const unsigned short* bp = wf1 + (size_t)(kq * 256 + h * 128 + cc * 16 + l16) * 8;
        bh[cc] = *(const bf16x8*)bp;
        bl[cc] = *(const bf16x8*)(bp + 32768);
      }
#pragma unroll
      for (int cc = 0; cc < 8; cc++) {
        accF[cc] = __builtin_amdgcn_mfma_f32_16x16x32_bf16(avY[kb], bh[cc], accF[cc], 0, 0, 0);
        accF[cc] = __builtin_amdgcn_mfma_f32_16x16x32_bf16(avY[kb], bl[cc], accF[cc], 0, 0, 0);
      }
    }
#pragma unroll
    for (int i = 0; i < 4; i++) {
      int grow = rbase + wrow + quad * 4 + i;
      if (grow < nrows) {
#pragma unroll
        for (int cc = 0; cc < 8; cc++) {
          float fv = fmaxf(accF[cc][i] + bf1[h * 128 + cc * 16 + l16], 0.f);
          ffh[(size_t)grow * 256 + h * 128 + cc * 16 + l16] = f2bf(fv);
        }
      }
    }
  }
}

// ================ chain2: FFN2 + LN2 + QKV(next) ================
template<bool LAST>
__global__ __launch_bounds__(256) void chain2_kernel(
    const unsigned short* __restrict__ ffh,    // [N,256]
    const unsigned short* __restrict__ xr,     // [N,128] x1 (read)
    unsigned short* __restrict__ xb,           // [N,128] x2 out (next residual)
    unsigned short* __restrict__ qkv,          // [N,384] out
    const unsigned short* __restrict__ wf2, const float* __restrict__ bf2,
    const float* __restrict__ g2, const float* __restrict__ be2,
    const unsigned short* __restrict__ wqkv,
    const float* __restrict__ bq, const float* __restrict__ bk,
    const float* __restrict__ bv, int nrows)
{
  __shared__ unsigned short Y[64 * LSTR];  // 17 KB
  int tid = threadIdx.x;
  int wave = tid >> 6, lane = tid & 63;
  int quad = lane >> 4, l16 = lane & 15;
  int rbase = blockIdx.x * 64;
  int wrow = wave * 16;

  // ---- FFN2 (K=256) ----
  floatx4 acc2[8];
#pragma unroll
  for (int cc = 0; cc < 8; cc++) acc2[cc] = (floatx4)(0.f);
  {
    int grA = min(rbase + wrow + l16, nrows - 1);
    const unsigned short* arow = ffh + (size_t)grA * 256 + quad * 8;
#pragma unroll
    for (int h = 0; h < 2; h++) {
#pragma unroll
      for (int kb = 0; kb < 4; kb++) {
        bf16x8 av = *(const bf16x8*)(arow + h * 128 + kb * 32);
        int kq = h * 16 + kb * 4 + quad;
        bf16x8 bh[8], bl[8];
#pragma unroll
        for (int cc = 0; cc < 8; cc++) {
          const unsigned short* bp = wf2 + (size_t)(kq * 128 + cc * 16 + l16) * 8;
          bh[cc] = *(const bf16x8*)bp;
          bl[cc] = *(const bf16x8*)(bp + 32768);
        }
#pragma unroll
        for (int cc = 0; cc < 8; cc++) {
          acc2[cc] = __builtin_amdgcn_mfma_f32_16x16x32_bf16(av, bh[cc], acc2[cc], 0, 0, 0);
          acc2[cc] = __builtin_amdgcn_mfma_f32_16x16x32_bf16(av, bl[cc], acc2[cc], 0, 0, 0);
        }
      }
    }
  }

  // ---- LN2: x2 = LN(x1 + ffn2) -> xb; x2 -> Y ----
  {
    float bias2[8], g2v[8], b2v[8];
#pragma unroll
    for (int cc = 0; cc < 8; cc++) {
      int col = cc * 16 + l16;
      bias2[cc] = bf2[col]; g2v[cc] = g2[col]; b2v[cc] = be2[col];
    }
#pragma unroll
    for (int i = 0; i < 4; i++) {
      int lrow = wrow + quad * 4 + i;
      int grow = rbase + lrow;
      int growc = min(grow, nrows - 1);
      float t[8]; float s = 0.f;
#pragma unroll
      for (int cc = 0; cc < 8; cc++) {
        t[cc] = acc2[cc][i] + bias2[cc] + bf2f(xr[(size_t)growc * 128 + cc * 16 + l16]);
        s += t[cc];
      }
      s += __shfl_xor(s, 1); s += __shfl_xor(s, 2);
      s += __shfl_xor(s, 4); s += __shfl_xor(s, 8);
      float mean = s * (1.f / 128.f);
      float vv = 0.f;
#pragma unroll
      for (int cc = 0; cc < 8; cc++) { float d = t[cc] - mean; vv += d * d; }
      vv += __shfl_xor(vv, 1); vv += __shfl_xor(vv, 2);
      vv += __shfl_xor(vv, 4); vv += __shfl_xor(vv, 8);
      float inv = rsqrtf(vv * (1.f / 128.f) + 1e-5f);
#pragma unroll
      for (int cc = 0; cc < 8; cc++) {
        float o = (t[cc] - mean) * inv * g2v[cc] + b2v[cc];
        unsigned short ob = f2bf(o);
        Y[lrow * LSTR + cc * 16 + l16] = ob;
        if (grow < nrows) xb[(size_t)grow * 128 + cc * 16 + l16] = ob;
      }
    }
  }

  // ---- QKV for next layer ----
  if (!LAST) {
    bf16x8 avQ[4];
#pragma unroll
    for (int kb = 0; kb < 4; kb++)
      avQ[kb] = *(bf16x8*)&Y[(wrow + l16) * LSTR + kb * 32 + quad * 8];
#pragma unroll
    for (int c = 0; c < 3; c++) {
      floatx4 accQ[8];
#pragma unroll
      for (int ct = 0; ct < 8; ct++) accQ[ct] = (floatx4)(0.f);
#pragma unroll
      for (int kb = 0; kb < 4; kb++) {
        int kq = kb * 4 + quad;
        bf16x8 bh[8];
#pragma unroll
        for (int ct = 0; ct < 8; ct++)
          bh[ct] = *(const bf16x8*)&wqkv[(size_t)(kq * 384 + c * 128 + ct * 16 + l16) * 8];
#pragma unroll
        for (int ct = 0; ct < 8; ct++)
          accQ[ct] = __builtin_amdgcn_mfma_f32_16x16x32_bf16(avQ[kb], bh[ct], accQ[ct], 0, 0, 0);
      }
      const float* bias = (c == 0) ? bq : (c == 1) ? bk : bv;
#pragma unroll
      for (int ct = 0; ct < 8; ct++) {
        float bvv = bias[ct * 16 + l16];
#pragma unroll
        for (int i = 0; i < 4; i++) {
          int grow = rbase + wrow + quad * 4 + i;
          if (grow < nrows)
            qkv[(size_t)grow * 384 + c * 128 + ct * 16 + l16] = f2bf(accQ[ct][i] + bvv);
        }
      }
    }
  }
}
#undef LSTR

// ---------------- fused edge attention (bf16 qkv), one wave per dst node, x4 unroll ----------------
__global__ __launch_bounds__(256) void attn_kernel(
    const unsigned short* __restrict__ qkv,
    const int* __restrict__ offsets, const int* __restrict__ csr,
    unsigned short* __restrict__ attn)
{
  int node = blockIdx.x * 4 + (threadIdx.x >> 6);
  int lane = threadIdx.x & 63;
  if (node >= N_NODES) return;
  float2 q2 = bf2f2(*(const unsigned int*)(qkv + (size_t)node * 384 + lane * 2));
  float wx = 0.f, wy = 0.f, z = 0.f;
  int j = offsets[node], end = offsets[node + 1];
  for (; j + 4 <= end; j += 4) {
    int4 s4 = *(const int4*)(csr + j);
    const unsigned short* r0 = qkv + (size_t)s4.x * 384 + 128;
    const unsigned short* r1 = qkv + (size_t)s4.y * 384 + 128;
    const unsigned short* r2 = qkv + (size_t)s4.z * 384 + 128;
    const unsigned short* r3 = qkv + (size_t)s4.w * 384 + 128;
    unsigned int ku0 = *(const unsigned int*)(r0 + lane * 2);
    unsigned int ku1 = *(const unsigned int*)(r1 + lane * 2);
    unsigned int ku2 = *(const unsigned int*)(r2 + lane * 2);
    unsigned int ku3 = *(const unsigned int*)(r3 + lane * 2);
    unsigned int vu0 = *(const unsigned int*)(r0 + 128 + lane * 2);
    unsigned int vu1 = *(const unsigned int*)(r1 + 128 + lane * 2);
    unsigned int vu2 = *(const unsigned int*)(r2 + 128 + lane * 2);
    unsigned int vu3 = *(const unsigned int*)(r3 + 128 + lane * 2);
    float2 k0 = bf2f2(ku0), k1 = bf2f2(ku1), k2 = bf2f2(ku2), k3 = bf2f2(ku3);
    float p0 = k0.x * q2.x + k0.y * q2.y;
    float p1 = k1.x * q2.x + k1.y * q2.y;
    float p2 = k2.x * q2.x + k2.y * q2.y;
    float p3 = k3.x * q2.x + k3.y * q2.y;
    p0 += __shfl_xor(p0, 1); p1 += __shfl_xor(p1, 1);
    p2 += __shfl_xor(p2, 1); p3 += __shfl_xor(p3, 1);
    p0 += __shfl_xor(p0, 2); p1 += __shfl_xor(p1, 2);
    p2 += __shfl_xor(p2, 2); p3 += __shfl_xor(p3, 2);
    p0 += __shfl_xor(p0, 4); p1 += __shfl_xor(p1, 4);
    p2 += __shfl_xor(p2, 4); p3 += __shfl_xor(p3, 4);
    float sc0 = __expf(fminf(fmaxf(p0 * 0.25f, -5.f), 5.f));
    float sc1 = __expf(fminf(fmaxf(p1 * 0.25f, -5.f), 5.f));
    float sc2 = __expf(fminf(fmaxf(p2 * 0.25f, -5.f), 5.f));
    float sc3 = __expf(fminf(fmaxf(p3 * 0.25f, -5.f), 5.f));
    float2 v0 = bf2f2(vu0), v1 = bf2f2(vu1), v2 = bf2f2(vu2), v3 = bf2f2(vu3);
    wx = fmaf(sc0, v0.x, wx); wy = fmaf(sc0, v0.y, wy);
    wx = fmaf(sc1, v1.x, wx); wy = fmaf(sc1, v1.y, wy);
    wx = fmaf(sc2, v2.x, wx); wy = fmaf(sc2, v2.y, wy);
    wx = fmaf(sc3, v3.x, wx); wy = fmaf(sc3, v3.y, wy);
    z += (sc0 + sc1) + (sc2 + sc3);
  }
  for (; j < end; ++j) {
    int s = csr[j];
    const unsigned short* r0 = qkv + (size_t)s * 384 + 128;
    float2 k2 = bf2f2(*(const unsigned int*)(r0 + lane * 2));
    float p = k2.x * q2.x + k2.y * q2.y;
    p += __shfl_xor(p, 1); p += __shfl_xor(p, 2); p += __shfl_xor(p, 4);
    float sc = __expf(fminf(fmaxf(p * 0.25f, -5.f), 5.f));
    float2 v2 = bf2f2(*(const unsigned int*)(r0 + 128 + lane * 2));
    wx = fmaf(sc, v2.x, wx); wy = fmaf(sc, v2.y, wy);
    z += sc;
  }
  float inv = 1.f / (z + 1e-6f);
  unsigned int pack = (unsigned int)f2bf(wx * inv) | ((unsigned int)f2bf(wy * inv) << 16);
  *(unsigned int*)(attn + (size_t)node * DIM + lane * 2) = pack;
}

// ---------------- column mean over nodes (bf16 in, fp32 acc) ----------------
__global__ __launch_bounds__(256) void colmean_kernel(
    const unsigned short* __restrict__ xb, float* __restrict__ mean)
{
  int col = threadIdx.x & 127;
  int half = threadIdx.x >> 7;
  float acc = 0.f;
  for (int r = blockIdx.x * 2 + half; r < N_NODES; r += gridDim.x * 2)
    acc += bf2f(xb[(size_t)r * DIM + col]);
  __shared__ float s[256];
  s[threadIdx.x] = acc;
  __syncthreads();
  if (threadIdx.x < 128) atomicAdd(&mean[col], s[threadIdx.x] + s[threadIdx.x + 128]);
}

// ---------------- readout MLP 128->64->32->10 ----------------
__global__ void readout_kernel(
    const float* __restrict__ mean,
    const float* __restrict__ mW0, const float* __restrict__ mb0,
    const float* __restrict__ mW1, const float* __restrict__ mb1,
    const float* __restrict__ mW2, const float* __restrict__ mb2,
    float* __restrict__ out)
{
  __shared__ float sx[128], h0[64], h1[32];
  int t = threadIdx.x;
  sx[t] = mean[t] * (1.f / (float)N_NODES);
  __syncthreads();
  if (t < 64) {
    float a = mb0[t];
    for (int i = 0; i < 128; i++) a = fmaf(sx[i], mW0[i * 64 + t], a);
    h0[t] = fmaxf(a, 0.f);
  }
  __syncthreads();
  if (t < 32) {
    float a = mb1[t];
    for (int i = 0; i < 64; i++) a = fmaf(h0[i], mW1[i * 32 + t], a);
    h1[t] = fmaxf(a, 0.f);
  }
  __syncthreads();
  if (t < 10) {
    float a = mb2[t];
    for (int i = 0; i < 32; i++) a = fmaf(h1[i], mW2[i * 10 + t], a);
    out[t] = a;
  }
}

extern "C" void kernel_launch(void* const* d_in, const int* in_sizes, int n_in,
                              void* d_out, int out_size, void* d_ws, size_t ws_size,
                              hipStream_t stream) {
  const int*   x_idx = (const int*)d_in[0];
  const int*   eidx  = (const int*)d_in[1];
  const float* emb   = (const float*)d_in[2];
  const float* Wq = (const float*)d_in[3];  const float* bq = (const float*)d_in[4];
  const float* Wk = (const float*)d_in[5];  const float* bk = (const float*)d_in[6];
  const float* Wv = (const float*)d_in[7];  const float* bv = (const float*)d_in[8];
  const float* Wo = (const float*)d_in[9];  const float* bo = (const float*)d_in[10];
  const float* g1 = (const float*)d_in[11]; const float* be1 = (const float*)d_in[12];
  const float* Wf1 = (const float*)d_in[13]; const float* bf1 = (const float*)d_in[14];
  const float* Wf2 = (const float*)d_in[15]; const float* bf2 = (const float*)d_in[16];
  const float* g2 = (const float*)d_in[17]; const float* be2 = (const float*)d_in[18];
  const float* mW0 = (const float*)d_in[19]; const float* mb0 = (const float*)d_in[20];
  const float* mW1 = (const float*)d_in[21]; const float* mb1 = (const float*)d_in[22];
  const float* mW2 = (const float*)d_in[23]; const float* mb2 = (const float*)d_in[24];
  float* out = (float*)d_out;

  const size_t NX = (size_t)N_NODES * DIM;
  unsigned short* xb  = (unsigned short*)d_ws;                // bf16 residual
  unsigned short* qkv = xb + NX;                              // [N,384]
  unsigned short* a   = qkv + (size_t)N_NODES * 384;          // attn out
  unsigned short* xr  = a + NX;                               // x1 (post-LN1)
  unsigned short* ffh = xr + NX;                              // [N,256]

  unsigned short* wqkv_p = ffh + (size_t)N_NODES * 256;       // 3*128*384
  unsigned short* wo_p   = wqkv_p + 3 * 128 * 384;            // 3*2*128*128
  unsigned short* wf1_p  = wo_p   + 3 * 2 * 128 * 128;        // 3*2*128*256
  unsigned short* wf2_p  = wf1_p  + 3 * 2 * 128 * 256;        // 3*2*256*128
  unsigned short* wend   = wf2_p  + 3 * 2 * 256 * 128;

  int* counts  = (int*)wend;
  int* fill    = counts + N_NODES;
  float* meanb = (float*)(fill + N_NODES);
  int* offsets = (int*)(meanb + DIM);
  int* bsums   = offsets + N_NODES + 1;
  int* csr     = bsums + 256;

  const int* e0 = eidx;
  const int* e1 = eidx + N_EDGES;

  hipMemsetAsync(counts, 0, (2 * N_NODES + DIM) * sizeof(int), stream);

  prep_all<<<192, 256, 0, stream>>>(Wq, Wk, Wv, Wo, Wf1, Wf2,
                                    wqkv_p, wo_p, wf1_p, wf2_p);

  embed_kernel<<<(N_NODES * 32 + 255) / 256, 256, 0, stream>>>(x_idx, emb, xb);
  hist_kernel<<<(N_EDGES + 255) / 256, 256, 0, stream>>>(e1, counts);
  int nblk = (N_NODES + 255) / 256;
  scan_local<<<nblk, 256, 0, stream>>>(counts, offsets, bsums);
  scan_bsums<<<1, 256, 0, stream>>>(bsums, nblk);
  scan_add<<<nblk, 256, 0, stream>>>(offsets, bsums);
  scatter_kernel<<<(N_EDGES + 255) / 256, 256, 0, stream>>>(e0, e1, offsets, fill, csr);

  int gx = (N_NODES + 127) / 128;      // qkv0
  int gc = (N_NODES + 63) / 64;        // 782 (chain1/2)
  int nb4 = (N_NODES + 3) / 4;

  mfma_gemm_qkv<<<dim3(gx, 3), 256, 0, stream>>>(xb, wqkv_p, bq, bk, bv, qkv, N_NODES);

  for (int l = 0; l < NLAYERS; ++l) {
    const unsigned short* wo_l   = wo_p   + (size_t)l * 2 * 128 * 128;
    const unsigned short* wf1_l  = wf1_p  + (size_t)l * 2 * 128 * 256;
    const unsigned short* wf2_l  = wf2_p  + (size_t)l * 2 * 256 * 128;
    const unsigned short* wqkv_n = wqkv_p + (size_t)(l + 1) * 128 * 384;
    const float* bo_l  = bo  + (size_t)l * DIM;
    const float* g1_l  = g1  + (size_t)l * DIM;
    const float* be1_l = be1 + (size_t)l * DIM;
    const float* bf1_l = bf1 + (size_t)l * 2 * DIM;
    const float* bf2_l = bf2 + (size_t)l * DIM;
    const float* g2_l  = g2  + (size_t)l * DIM;
    const float* be2_l = be2 + (size_t)l * DIM;

    attn_kernel<<<nb4, 256, 0, stream>>>(qkv, offsets, csr, a);
    chain1_kernel<<<gc, 256, 0, stream>>>(
        a, xb, xr, ffh, wo_l, bo_l, g1_l, be1_l, wf1_l, bf1_l, N_NODES);
    if (l < NLAYERS - 1) {
      chain2_kernel<false><<<gc, 256, 0, stream>>>(
          ffh, xr, xb, qkv, wf2_l, bf2_l, g2_l, be2_l, wqkv_n,
          bq + (size_t)(l + 1) * DIM, bk + (size_t)(l + 1) * DIM,
          bv + (size_t)(l + 1) * DIM, N_NODES);
    } else {
      chain2_kernel<true><<<gc, 256, 0, stream>>>(
          ffh, xr, xb, qkv, wf2_l, bf2_l, g2_l, be2_l, wqkv_p,
          bq, bk, bv, N_NODES);
    }
  }

  colmean_kernel<<<128, 256, 0, stream>>>(xb, meanb);
  readout_kernel<<<1, 128, 0, stream>>>(meanb, mW0, mb0, mW1, mb1, mW2, mb2, out);
}

// Round 9
// 694.698 us; speedup vs baseline: 1.0227x; 1.0227x over previous
//
#include <hip/hip_runtime.h>
#include <hip/hip_bf16.h>

#define N_NODES 50000
#define N_EDGES 800000
#define DIM 128
#define NLAYERS 3

typedef short bf16x8 __attribute__((ext_vector_type(8)));
typedef float floatx4 __attribute__((ext_vector_type(4)));

__device__ __forceinline__ unsigned short f2bf(float f) {
  unsigned int u = __builtin_bit_cast(unsigned int, f);
  return (unsigned short)((u + 0x7FFFu + ((u >> 16) & 1u)) >> 16);
}
__device__ __forceinline__ float bf2f(unsigned short h) {
  return __builtin_bit_cast(float, (unsigned int)h << 16);
}
__device__ __forceinline__ float bfhi(float f, unsigned short& hb) {
  unsigned int u = __builtin_bit_cast(unsigned int, f);
  unsigned int r = (u + 0x7FFFu + ((u >> 16) & 1u)) & 0xFFFF0000u;
  hb = (unsigned short)(r >> 16);
  return __builtin_bit_cast(float, r);
}
__device__ __forceinline__ float2 bf2f2(unsigned int u) {
  float lo = __builtin_bit_cast(float, u << 16);
  float hi = __builtin_bit_cast(float, u & 0xFFFF0000u);
  return make_float2(lo, hi);
}

// ---------------- embedding gather -> bf16 residual ----------------
__global__ __launch_bounds__(256) void embed_kernel(
    const int* __restrict__ idx, const float* __restrict__ emb,
    unsigned short* __restrict__ xb)
{
  int gid = blockIdx.x * 256 + threadIdx.x;
  int n = gid >> 5;
  int c = (gid & 31) << 2;
  if (n >= N_NODES) return;
  int e = idx[n];
  float4 val = *(const float4*)(emb + (size_t)e * DIM + c);
  ushort4 pk;
  pk.x = f2bf(val.x); pk.y = f2bf(val.y); pk.z = f2bf(val.z); pk.w = f2bf(val.w);
  *(ushort4*)(xb + (size_t)n * DIM + c) = pk;
}

// ---------------- CSR build ----------------
__global__ __launch_bounds__(256) void hist_kernel(
    const int* __restrict__ e1, int* __restrict__ counts)
{
  int i = blockIdx.x * 256 + threadIdx.x;
  if (i < N_EDGES) atomicAdd(&counts[e1[i]], 1);
}

__global__ __launch_bounds__(256) void scan_local(
    const int* __restrict__ counts, int* __restrict__ offsets,
    int* __restrict__ bsums)
{
  __shared__ int buf[256];
  int t = threadIdx.x;
  int i = blockIdx.x * 256 + t;
  int v = (i < N_NODES) ? counts[i] : 0;
  buf[t] = v;
  __syncthreads();
  int s = v;
#pragma unroll
  for (int off = 1; off < 256; off <<= 1) {
    int t2 = (t >= off) ? buf[t - off] : 0;
    __syncthreads();
    s += t2;
    buf[t] = s;
    __syncthreads();
  }
  if (i < N_NODES) offsets[i] = s - v;
  if (t == 255) bsums[blockIdx.x] = s;
}

__global__ void scan_bsums(int* __restrict__ bsums, int nblk)
{
  __shared__ int buf[256];
  int t = threadIdx.x;
  int v = (t < nblk) ? bsums[t] : 0;
  buf[t] = v;
  __syncthreads();
  int s = v;
#pragma unroll
  for (int off = 1; off < 256; off <<= 1) {
    int t2 = (t >= off) ? buf[t - off] : 0;
    __syncthreads();
    s += t2;
    buf[t] = s;
    __syncthreads();
  }
  if (t < nblk) bsums[t] = s - v;
}

__global__ __launch_bounds__(256) void scan_add(
    int* __restrict__ offsets, const int* __restrict__ bsums)
{
  int i = blockIdx.x * 256 + threadIdx.x;
  if (i < N_NODES) offsets[i] += bsums[blockIdx.x];
  if (i == 0) offsets[N_NODES] = N_EDGES;
}

__global__ __launch_bounds__(256) void scatter_kernel(
    const int* __restrict__ e0, const int* __restrict__ e1,
    const int* __restrict__ offsets, int* __restrict__ fill,
    int* __restrict__ csr)
{
  int i = blockIdx.x * 256 + threadIdx.x;
  if (i >= N_EDGES) return;
  int d = e1[i];
  int pos = offsets[d] + atomicAdd(&fill[d], 1);
  csr[pos] = e0[i];
}

// ---------------- combined weight prep (one dispatch) ----------------
__global__ __launch_bounds__(256) void prep_all(
    const float* __restrict__ Wq, const float* __restrict__ Wk,
    const float* __restrict__ Wv, const float* __restrict__ Wo,
    const float* __restrict__ Wf1, const float* __restrict__ Wf2,
    unsigned short* __restrict__ wqkv, unsigned short* __restrict__ wo,
    unsigned short* __restrict__ wf1, unsigned short* __restrict__ wf2)
{
  int g = blockIdx.x * 256 + threadIdx.x;
  if (g < 18432) {
    int srcId = g / 6144; int rem = g - srcId * 6144;
    const float* W = (srcId == 0) ? Wq : (srcId == 1) ? Wk : Wv;
    int l = rem / 2048; int r2 = rem & 2047; int kq = r2 >> 7; int n = r2 & 127;
    const float* Wl = W + (size_t)l * 128 * 128;
    unsigned short* base = wqkv + (size_t)l * 128 * 384 + (size_t)(kq * 384 + srcId * 128 + n) * 8;
#pragma unroll
    for (int j = 0; j < 8; j++)
      base[j] = f2bf(Wl[(size_t)(kq * 8 + j) * 128 + n]);
    return;
  }
  g -= 18432;
  if (g < 6144) {
    int l = g / 2048; int r2 = g & 2047; int kq = r2 >> 7; int n = r2 & 127;
    const float* Wl = Wo + (size_t)l * 128 * 128;
    unsigned short* basehi = wo + (size_t)l * 2 * 128 * 128 + (size_t)(kq * 128 + n) * 8;
#pragma unroll
    for (int j = 0; j < 8; j++) {
      float f = Wl[(size_t)(kq * 8 + j) * 128 + n];
      unsigned short hb; float hf = bfhi(f, hb);
      basehi[j] = hb; basehi[16384 + j] = f2bf(f - hf);
    }
    return;
  }
  g -= 6144;
  if (g < 12288) {
    int l = g / 4096; int r2 = g & 4095; int kq = r2 >> 8; int n = r2 & 255;
    const float* Wl = Wf1 + (size_t)l * 128 * 256;
    unsigned short* basehi = wf1 + (size_t)l * 2 * 128 * 256 + (size_t)(kq * 256 + n) * 8;
#pragma unroll
    for (int j = 0; j < 8; j++) {
      float f = Wl[(size_t)(kq * 8 + j) * 256 + n];
      unsigned short hb; float hf = bfhi(f, hb);
      basehi[j] = hb; basehi[32768 + j] = f2bf(f - hf);
    }
    return;
  }
  g -= 12288;
  if (g < 12288) {
    int l = g / 4096; int r2 = g & 4095; int kq = r2 >> 7; int n = r2 & 127;
    const float* Wl = Wf2 + (size_t)l * 256 * 128;
    unsigned short* basehi = wf2 + (size_t)l * 2 * 256 * 128 + (size_t)(kq * 128 + n) * 8;
#pragma unroll
    for (int j = 0; j < 8; j++) {
      float f = Wl[(size_t)(kq * 8 + j) * 128 + n];
      unsigned short hb; float hf = bfhi(f, hb);
      basehi[j] = hb; basehi[32768 + j] = f2bf(f - hf);
    }
  }
}

// ---------------- QKV GEMM (layer 0 only) ----------------
__global__ __launch_bounds__(256) void mfma_gemm_qkv(
    const unsigned short* __restrict__ Ab,
    const unsigned short* __restrict__ Wp,
    const float* __restrict__ bq, const float* __restrict__ bk,
    const float* __restrict__ bv,
    unsigned short* __restrict__ out, int nrows)
{
  constexpr int K = 128, N = 384, CT = 8;
  __shared__ unsigned short SW[16 * 128 * 8];   // 32 KB
  int tid = threadIdx.x;
  int c0 = blockIdx.y * 128;
  const float* bias = (blockIdx.y == 0) ? bq : (blockIdx.y == 1) ? bk : bv;
  int wave = tid >> 6, lane = tid & 63;
  int quad = lane >> 4, l16 = lane & 15;
  int row0 = blockIdx.x * 128 + wave * 32;

  floatx4 acc[2][CT];
#pragma unroll
  for (int rt = 0; rt < 2; rt++)
#pragma unroll
    for (int ct = 0; ct < CT; ct++) acc[rt][ct] = (floatx4)(0.f);

  const unsigned short* arow[2];
#pragma unroll
  for (int rt = 0; rt < 2; rt++) {
    int r = min(row0 + rt * 16 + l16, nrows - 1);
    arow[rt] = Ab + (size_t)r * K + quad * 8;
  }
#pragma unroll 4
  for (int f = tid; f < 16 * 128; f += 256) {
    int kq = f >> 7;
    int n = f & 127;
    *(bf16x8*)&SW[f * 8] = *(const bf16x8*)&Wp[(size_t)(kq * N + c0 + n) * 8];
  }
  __syncthreads();
#pragma unroll
  for (int kb = 0; kb < 4; ++kb) {
    bf16x8 av[2];
#pragma unroll
    for (int rt = 0; rt < 2; rt++)
      av[rt] = *(const bf16x8*)(arow[rt] + kb * 32);
#pragma unroll
    for (int ct = 0; ct < CT; ct++) {
      bf16x8 bh = *(bf16x8*)&SW[((kb * 4 + quad) * 128 + ct * 16 + l16) * 8];
#pragma unroll
      for (int rt = 0; rt < 2; rt++)
        acc[rt][ct] = __builtin_amdgcn_mfma_f32_16x16x32_bf16(av[rt], bh, acc[rt][ct], 0, 0, 0);
    }
  }
#pragma unroll
  for (int ct = 0; ct < CT; ct++) {
    float bvv = bias[ct * 16 + l16];
    int col = c0 + ct * 16 + l16;
#pragma unroll
    for (int rt = 0; rt < 2; rt++)
#pragma unroll
      for (int i = 0; i < 4; i++) {
        int r = row0 + rt * 16 + quad * 4 + i;
        if (r < nrows)
          out[(size_t)r * 384 + col] = f2bf(acc[rt][ct][i] + bvv);
      }
  }
}

// ================ chain1: O-GEMM + LN1 + FFN1 (2 waves x 32 rows) ================
#define LSTR 136
__global__ __launch_bounds__(128) void chain1_kernel(
    const unsigned short* __restrict__ a,
    const unsigned short* __restrict__ xb,
    unsigned short* __restrict__ xr,
    unsigned short* __restrict__ ffh,
    const unsigned short* __restrict__ wo, const float* __restrict__ bo,
    const float* __restrict__ g1, const float* __restrict__ be1,
    const unsigned short* __restrict__ wf1, const float* __restrict__ bf1,
    int nrows)
{
  __shared__ unsigned short Y[64 * LSTR];  // 17 KB
  int tid = threadIdx.x;
  int wave = tid >> 6, lane = tid & 63;
  int quad = lane >> 4, l16 = lane & 15;
  int rbase = blockIdx.x * 64;
  int wrow = wave * 32;

  // ---- O-GEMM (rt=2) ----
  floatx4 accO[2][8];
#pragma unroll
  for (int rt = 0; rt < 2; rt++)
#pragma unroll
    for (int cc = 0; cc < 8; cc++) accO[rt][cc] = (floatx4)(0.f);
  {
    const unsigned short* arow[2];
#pragma unroll
    for (int rt = 0; rt < 2; rt++) {
      int r = min(rbase + wrow + rt * 16 + l16, nrows - 1);
      arow[rt] = a + (size_t)r * 128 + quad * 8;
    }
#pragma unroll
    for (int kb = 0; kb < 4; kb++) {
      bf16x8 av[2];
#pragma unroll
      for (int rt = 0; rt < 2; rt++) av[rt] = *(const bf16x8*)(arow[rt] + kb * 32);
      int kq = kb * 4 + quad;
      bf16x8 bh[8], bl[8];
#pragma unroll
      for (int cc = 0; cc < 8; cc++) {
        const unsigned short* bp = wo + (size_t)(kq * 128 + cc * 16 + l16) * 8;
        bh[cc] = *(const bf16x8*)bp;
        bl[cc] = *(const bf16x8*)(bp + 16384);
      }
#pragma unroll
      for (int cc = 0; cc < 8; cc++)
#pragma unroll
        for (int rt = 0; rt < 2; rt++) {
          accO[rt][cc] = __builtin_amdgcn_mfma_f32_16x16x32_bf16(av[rt], bh[cc], accO[rt][cc], 0, 0, 0);
          accO[rt][cc] = __builtin_amdgcn_mfma_f32_16x16x32_bf16(av[rt], bl[cc], accO[rt][cc], 0, 0, 0);
        }
    }
  }

  // ---- LN1 -> xr; y -> Y ----
  {
    float biasO[8], g1v[8], b1v[8];
#pragma unroll
    for (int cc = 0; cc < 8; cc++) {
      int col = cc * 16 + l16;
      biasO[cc] = bo[col]; g1v[cc] = g1[col]; b1v[cc] = be1[col];
    }
#pragma unroll
    for (int rt = 0; rt < 2; rt++) {
#pragma unroll
      for (int i = 0; i < 4; i++) {
        int lrow = wrow + rt * 16 + quad * 4 + i;
        int grow = rbase + lrow;
        int growc = min(grow, nrows - 1);
        float t[8]; float s = 0.f;
#pragma unroll
        for (int cc = 0; cc < 8; cc++) {
          float yv = accO[rt][cc][i] + biasO[cc];
          Y[lrow * LSTR + cc * 16 + l16] = f2bf(yv);
          t[cc] = yv + bf2f(xb[(size_t)growc * 128 + cc * 16 + l16]);
          s += t[cc];
        }
        s += __shfl_xor(s, 1); s += __shfl_xor(s, 2);
        s += __shfl_xor(s, 4); s += __shfl_xor(s, 8);
        float mean = s * (1.f / 128.f);
        float vv = 0.f;
#pragma unroll
        for (int cc = 0; cc < 8; cc++) { float d = t[cc] - mean; vv += d * d; }
        vv += __shfl_xor(vv, 1); vv += __shfl_xor(vv, 2);
        vv += __shfl_xor(vv, 4); vv += __shfl_xor(vv, 8);
        float inv = rsqrtf(vv * (1.f / 128.f) + 1e-5f);
        if (grow < nrows) {
#pragma unroll
          for (int cc = 0; cc < 8; cc++)
            xr[(size_t)grow * 128 + cc * 16 + l16] =
                f2bf((t[cc] - mean) * inv * g1v[cc] + b1v[cc]);
        }
      }
    }
  }

  // ---- FFN1 ----
  bf16x8 avY[2][4];
#pragma unroll
  for (int rt = 0; rt < 2; rt++)
#pragma unroll
    for (int kb = 0; kb < 4; kb++)
      avY[rt][kb] = *(bf16x8*)&Y[(wrow + rt * 16 + l16) * LSTR + kb * 32 + quad * 8];
#pragma unroll
  for (int h = 0; h < 2; h++) {
    floatx4 accF[2][8];
#pragma unroll
    for (int rt = 0; rt < 2; rt++)
#pragma unroll
      for (int cc = 0; cc < 8; cc++) accF[rt][cc] = (floatx4)(0.f);
#pragma unroll
    for (int kb = 0; kb < 4; kb++) {
      int kq = kb * 4 + quad;
      bf16x8 bh[8], bl[8];
#pragma unroll
      for (int cc = 0; cc < 8; cc++) {
        const unsigned short* bp = wf1 + (size_t)(kq * 256 + h * 128 + cc * 16 + l16) * 8;
        bh[cc] = *(const bf16x8*)bp;
        bl[cc] = *(const bf16x8*)(bp + 32768);
      }
#pragma unroll
      for (int cc = 0; cc < 8; cc++)
#pragma unroll
        for (int rt = 0; rt < 2; rt++) {
          accF[rt][cc] = __builtin_amdgcn_mfma_f32_16x16x32_bf16(avY[rt][kb], bh[cc], accF[rt][cc], 0, 0, 0);
          accF[rt][cc] = __builtin_amdgcn_mfma_f32_16x16x32_bf16(avY[rt][kb], bl[cc], accF[rt][cc], 0, 0, 0);
        }
    }
#pragma unroll
    for (int rt = 0; rt < 2; rt++)
#pragma unroll
      for (int i = 0; i < 4; i++) {
        int grow = rbase + wrow + rt * 16 + quad * 4 + i;
        if (grow < nrows) {
#pragma unroll
          for (int cc = 0; cc < 8; cc++) {
            float fv = fmaxf(accF[rt][cc][i] + bf1[h * 128 + cc * 16 + l16], 0.f);
            ffh[(size_t)grow * 256 + h * 128 + cc * 16 + l16] = f2bf(fv);
          }
        }
      }
  }
}

// ================ chain2: FFN2 + LN2 + QKV(next) (2 waves x 32 rows) ================
template<bool LAST>
__global__ __launch_bounds__(128) void chain2_kernel(
    const unsigned short* __restrict__ ffh,
    const unsigned short* __restrict__ xr,
    unsigned short* __restrict__ xb,
    unsigned short* __restrict__ qkv,
    const unsigned short* __restrict__ wf2, const float* __restrict__ bf2,
    const float* __restrict__ g2, const float* __restrict__ be2,
    const unsigned short* __restrict__ wqkv,
    const float* __restrict__ bq, const float* __restrict__ bk,
    const float* __restrict__ bv, int nrows)
{
  __shared__ unsigned short Y[64 * LSTR];  // 17 KB
  int tid = threadIdx.x;
  int wave = tid >> 6, lane = tid & 63;
  int quad = lane >> 4, l16 = lane & 15;
  int rbase = blockIdx.x * 64;
  int wrow = wave * 32;

  // ---- FFN2 (K=256, rt=2) ----
  floatx4 acc2[2][8];
#pragma unroll
  for (int rt = 0; rt < 2; rt++)
#pragma unroll
    for (int cc = 0; cc < 8; cc++) acc2[rt][cc] = (floatx4)(0.f);
  {
    const unsigned short* arow[2];
#pragma unroll
    for (int rt = 0; rt < 2; rt++) {
      int r = min(rbase + wrow + rt * 16 + l16, nrows - 1);
      arow[rt] = ffh + (size_t)r * 256 + quad * 8;
    }
#pragma unroll
    for (int h = 0; h < 2; h++) {
#pragma unroll
      for (int kb = 0; kb < 4; kb++) {
        bf16x8 av[2];
#pragma unroll
        for (int rt = 0; rt < 2; rt++) av[rt] = *(const bf16x8*)(arow[rt] + h * 128 + kb * 32);
        int kq = h * 16 + kb * 4 + quad;
        bf16x8 bh[8], bl[8];
#pragma unroll
        for (int cc = 0; cc < 8; cc++) {
          const unsigned short* bp = wf2 + (size_t)(kq * 128 + cc * 16 + l16) * 8;
          bh[cc] = *(const bf16x8*)bp;
          bl[cc] = *(const bf16x8*)(bp + 32768);
        }
#pragma unroll
        for (int cc = 0; cc < 8; cc++)
#pragma unroll
          for (int rt = 0; rt < 2; rt++) {
            acc2[rt][cc] = __builtin_amdgcn_mfma_f32_16x16x32_bf16(av[rt], bh[cc], acc2[rt][cc], 0, 0, 0);
            acc2[rt][cc] = __builtin_amdgcn_mfma_f32_16x16x32_bf16(av[rt], bl[cc], acc2[rt][cc], 0, 0, 0);
          }
      }
    }
  }

  // ---- LN2 -> xb; x2 -> Y ----
  {
    float bias2[8], g2v[8], b2v[8];
#pragma unroll
    for (int cc = 0; cc < 8; cc++) {
      int col = cc * 16 + l16;
      bias2[cc] = bf2[col]; g2v[cc] = g2[col]; b2v[cc] = be2[col];
    }
#pragma unroll
    for (int rt = 0; rt < 2; rt++) {
#pragma unroll
      for (int i = 0; i < 4; i++) {
        int lrow = wrow + rt * 16 + quad * 4 + i;
        int grow = rbase + lrow;
        int growc = min(grow, nrows - 1);
        float t[8]; float s = 0.f;
#pragma unroll
        for (int cc = 0; cc < 8; cc++) {
          t[cc] = acc2[rt][cc][i] + bias2[cc] + bf2f(xr[(size_t)growc * 128 + cc * 16 + l16]);
          s += t[cc];
        }
        s += __shfl_xor(s, 1); s += __shfl_xor(s, 2);
        s += __shfl_xor(s, 4); s += __shfl_xor(s, 8);
        float mean = s * (1.f / 128.f);
        float vv = 0.f;
#pragma unroll
        for (int cc = 0; cc < 8; cc++) { float d = t[cc] - mean; vv += d * d; }
        vv += __shfl_xor(vv, 1); vv += __shfl_xor(vv, 2);
        vv += __shfl_xor(vv, 4); vv += __shfl_xor(vv, 8);
        float inv = rsqrtf(vv * (1.f / 128.f) + 1e-5f);
#pragma unroll
        for (int cc = 0; cc < 8; cc++) {
          float o = (t[cc] - mean) * inv * g2v[cc] + b2v[cc];
          unsigned short ob = f2bf(o);
          Y[lrow * LSTR + cc * 16 + l16] = ob;
          if (grow < nrows) xb[(size_t)grow * 128 + cc * 16 + l16] = ob;
        }
      }
    }
  }

  // ---- QKV next ----
  if (!LAST) {
    bf16x8 avQ[2][4];
#pragma unroll
    for (int rt = 0; rt < 2; rt++)
#pragma unroll
      for (int kb = 0; kb < 4; kb++)
        avQ[rt][kb] = *(bf16x8*)&Y[(wrow + rt * 16 + l16) * LSTR + kb * 32 + quad * 8];
#pragma unroll
    for (int c = 0; c < 3; c++) {
      floatx4 accQ[2][8];
#pragma unroll
      for (int rt = 0; rt < 2; rt++)
#pragma unroll
        for (int ct = 0; ct < 8; ct++) accQ[rt][ct] = (floatx4)(0.f);
#pragma unroll
      for (int kb = 0; kb < 4; kb++) {
        int kq = kb * 4 + quad;
        bf16x8 bh[8];
#pragma unroll
        for (int ct = 0; ct < 8; ct++)
          bh[ct] = *(const bf16x8*)&wqkv[(size_t)(kq * 384 + c * 128 + ct * 16 + l16) * 8];
#pragma unroll
        for (int ct = 0; ct < 8; ct++)
#pragma unroll
          for (int rt = 0; rt < 2; rt++)
            accQ[rt][ct] = __builtin_amdgcn_mfma_f32_16x16x32_bf16(avQ[rt][kb], bh[ct], accQ[rt][ct], 0, 0, 0);
      }
      const float* bias = (c == 0) ? bq : (c == 1) ? bk : bv;
#pragma unroll
      for (int ct = 0; ct < 8; ct++) {
        float bvv = bias[ct * 16 + l16];
#pragma unroll
        for (int rt = 0; rt < 2; rt++)
#pragma unroll
          for (int i = 0; i < 4; i++) {
            int grow = rbase + wrow + rt * 16 + quad * 4 + i;
            if (grow < nrows)
              qkv[(size_t)grow * 384 + c * 128 + ct * 16 + l16] = f2bf(accQ[rt][ct][i] + bvv);
          }
      }
    }
  }
}
#undef LSTR

// ---------------- fused edge attention: one wave per dst node, x8 unroll ----------------
// sc = exp(clip(p/4,-5,5)) computed as exp2(clip(p*C, -5*log2e, 5*log2e)), C = 0.25*log2e
#define ATTN_C  0.36067376022f
#define ATTN_L  7.21347520444f
__device__ __forceinline__ float edge_score(float p) {
  float t = fminf(fmaxf(p * ATTN_C, -ATTN_L), ATTN_L);   // -> v_med3
  return __builtin_amdgcn_exp2f(t);
}
__global__ __launch_bounds__(256) void attn_kernel(
    const unsigned short* __restrict__ qkv,
    const int* __restrict__ offsets, const int* __restrict__ csr,
    unsigned short* __restrict__ attn)
{
  int node = blockIdx.x * 4 + (threadIdx.x >> 6);
  int lane = threadIdx.x & 63;
  if (node >= N_NODES) return;
  float2 q2 = bf2f2(*(const unsigned int*)(qkv + (size_t)node * 384 + lane * 2));
  const unsigned short* kbase = qkv + 128 + lane * 2;
  float wx = 0.f, wy = 0.f, z = 0.f;
  int j = offsets[node], end = offsets[node + 1];
  for (; j + 8 <= end; j += 8) {
    int s[8];
#pragma unroll
    for (int u = 0; u < 8; u++) s[u] = csr[j + u];
    unsigned int ku[8], vu[8];
#pragma unroll
    for (int u = 0; u < 8; u++) {
      const unsigned short* r = kbase + (size_t)s[u] * 384;
      ku[u] = *(const unsigned int*)r;
      vu[u] = *(const unsigned int*)(r + 128);
    }
    float p[8];
#pragma unroll
    for (int u = 0; u < 8; u++) {
      float2 k2 = bf2f2(ku[u]);
      p[u] = k2.x * q2.x + k2.y * q2.y;
    }
#pragma unroll
    for (int u = 0; u < 8; u++) p[u] += __shfl_xor(p[u], 1);
#pragma unroll
    for (int u = 0; u < 8; u++) p[u] += __shfl_xor(p[u], 2);
#pragma unroll
    for (int u = 0; u < 8; u++) p[u] += __shfl_xor(p[u], 4);
#pragma unroll
    for (int u = 0; u < 8; u++) {
      float sc = edge_score(p[u]);
      float2 v2 = bf2f2(vu[u]);
      wx = fmaf(sc, v2.x, wx);
      wy = fmaf(sc, v2.y, wy);
      z += sc;
    }
  }
  for (; j < end; ++j) {
    int s = csr[j];
    const unsigned short* r = kbase + (size_t)s * 384;
    float2 k2 = bf2f2(*(const unsigned int*)r);
    float p = k2.x * q2.x + k2.y * q2.y;
    p += __shfl_xor(p, 1); p += __shfl_xor(p, 2); p += __shfl_xor(p, 4);
    float sc = edge_score(p);
    float2 v2 = bf2f2(*(const unsigned int*)(r + 128));
    wx = fmaf(sc, v2.x, wx); wy = fmaf(sc, v2.y, wy);
    z += sc;
  }
  float inv = 1.f / (z + 1e-6f);
  unsigned int pack = (unsigned int)f2bf(wx * inv) | ((unsigned int)f2bf(wy * inv) << 16);
  *(unsigned int*)(attn + (size_t)node * DIM + lane * 2) = pack;
}

// ---------------- column mean over nodes (bf16 in, fp32 acc) ----------------
__global__ __launch_bounds__(256) void colmean_kernel(
    const unsigned short* __restrict__ xb, float* __restrict__ mean)
{
  int col = threadIdx.x & 127;
  int half = threadIdx.x >> 7;
  float acc = 0.f;
  for (int r = blockIdx.x * 2 + half; r < N_NODES; r += gridDim.x * 2)
    acc += bf2f(xb[(size_t)r * DIM + col]);
  __shared__ float s[256];
  s[threadIdx.x] = acc;
  __syncthreads();
  if (threadIdx.x < 128) atomicAdd(&mean[col], s[threadIdx.x] + s[threadIdx.x + 128]);
}

// ---------------- readout MLP 128->64->32->10 ----------------
__global__ void readout_kernel(
    const float* __restrict__ mean,
    const float* __restrict__ mW0, const float* __restrict__ mb0,
    const float* __restrict__ mW1, const float* __restrict__ mb1,
    const float* __restrict__ mW2, const float* __restrict__ mb2,
    float* __restrict__ out)
{
  __shared__ float sx[128], h0[64], h1[32];
  int t = threadIdx.x;
  sx[t] = mean[t] * (1.f / (float)N_NODES);
  __syncthreads();
  if (t < 64) {
    float a = mb0[t];
    for (int i = 0; i < 128; i++) a = fmaf(sx[i], mW0[i * 64 + t], a);
    h0[t] = fmaxf(a, 0.f);
  }
  __syncthreads();
  if (t < 32) {
    float a = mb1[t];
    for (int i = 0; i < 64; i++) a = fmaf(h0[i], mW1[i * 32 + t], a);
    h1[t] = fmaxf(a, 0.f);
  }
  __syncthreads();
  if (t < 10) {
    float a = mb2[t];
    for (int i = 0; i < 32; i++) a = fmaf(h1[i], mW2[i * 10 + t], a);
    out[t] = a;
  }
}

extern "C" void kernel_launch(void* const* d_in, const int* in_sizes, int n_in,
                              void* d_out, int out_size, void* d_ws, size_t ws_size,
                              hipStream_t stream) {
  const int*   x_idx = (const int*)d_in[0];
  const int*   eidx  = (const int*)d_in[1];
  const float* emb   = (const float*)d_in[2];
  const float* Wq = (const float*)d_in[3];  const float* bq = (const float*)d_in[4];
  const float* Wk = (const float*)d_in[5];  const float* bk = (const float*)d_in[6];
  const float* Wv = (const float*)d_in[7];  const float* bv = (const float*)d_in[8];
  const float* Wo = (const float*)d_in[9];  const float* bo = (const float*)d_in[10];
  const float* g1 = (const float*)d_in[11]; const float* be1 = (const float*)d_in[12];
  const float* Wf1 = (const float*)d_in[13]; const float* bf1 = (const float*)d_in[14];
  const float* Wf2 = (const float*)d_in[15]; const float* bf2 = (const float*)d_in[16];
  const float* g2 = (const float*)d_in[17]; const float* be2 = (const float*)d_in[18];
  const float* mW0 = (const float*)d_in[19]; const float* mb0 = (const float*)d_in[20];
  const float* mW1 = (const float*)d_in[21]; const float* mb1 = (const float*)d_in[22];
  const float* mW2 = (const float*)d_in[23]; const float* mb2 = (const float*)d_in[24];
  float* out = (float*)d_out;

  const size_t NX = (size_t)N_NODES * DIM;
  unsigned short* xb  = (unsigned short*)d_ws;
  unsigned short* qkv = xb + NX;
  unsigned short* a   = qkv + (size_t)N_NODES * 384;
  unsigned short* xr  = a + NX;
  unsigned short* ffh = xr + NX;

  unsigned short* wqkv_p = ffh + (size_t)N_NODES * 256;
  unsigned short* wo_p   = wqkv_p + 3 * 128 * 384;
  unsigned short* wf1_p  = wo_p   + 3 * 2 * 128 * 128;
  unsigned short* wf2_p  = wf1_p  + 3 * 2 * 128 * 256;
  unsigned short* wend   = wf2_p  + 3 * 2 * 256 * 128;

  int* counts  = (int*)wend;
  int* fill    = counts + N_NODES;
  float* meanb = (float*)(fill + N_NODES);
  int* offsets = (int*)(meanb + DIM);
  int* bsums   = offsets + N_NODES + 1;
  int* csr     = bsums + 256;

  const int* e0 = eidx;
  const int* e1 = eidx + N_EDGES;

  hipMemsetAsync(counts, 0, (2 * N_NODES + DIM) * sizeof(int), stream);

  prep_all<<<192, 256, 0, stream>>>(Wq, Wk, Wv, Wo, Wf1, Wf2,
                                    wqkv_p, wo_p, wf1_p, wf2_p);

  embed_kernel<<<(N_NODES * 32 + 255) / 256, 256, 0, stream>>>(x_idx, emb, xb);
  hist_kernel<<<(N_EDGES + 255) / 256, 256, 0, stream>>>(e1, counts);
  int nblk = (N_NODES + 255) / 256;
  scan_local<<<nblk, 256, 0, stream>>>(counts, offsets, bsums);
  scan_bsums<<<1, 256, 0, stream>>>(bsums, nblk);
  scan_add<<<nblk, 256, 0, stream>>>(offsets, bsums);
  scatter_kernel<<<(N_EDGES + 255) / 256, 256, 0, stream>>>(e0, e1, offsets, fill, csr);

  int gx = (N_NODES + 127) / 128;
  int gc = (N_NODES + 63) / 64;        // 782, 128-thread blocks
  int nb4 = (N_NODES + 3) / 4;

  mfma_gemm_qkv<<<dim3(gx, 3), 256, 0, stream>>>(xb, wqkv_p, bq, bk, bv, qkv, N_NODES);

  for (int l = 0; l < NLAYERS; ++l) {
    const unsigned short* wo_l   = wo_p   + (size_t)l * 2 * 128 * 128;
    const unsigned short* wf1_l  = wf1_p  + (size_t)l * 2 * 128 * 256;
    const unsigned short* wf2_l  = wf2_p  + (size_t)l * 2 * 256 * 128;
    const unsigned short* wqkv_n = wqkv_p + (size_t)(l + 1) * 128 * 384;
    const float* bo_l  = bo  + (size_t)l * DIM;
    const float* g1_l  = g1  + (size_t)l * DIM;
    const float* be1_l = be1 + (size_t)l * DIM;
    const float* bf1_l = bf1 + (size_t)l * 2 * DIM;
    const float* bf2_l = bf2 + (size_t)l * DIM;
    const float* g2_l  = g2  + (size_t)l * DIM;
    const float* be2_l = be2 + (size_t)l * DIM;

    attn_kernel<<<nb4, 256, 0, stream>>>(qkv, offsets, csr, a);
    chain1_kernel<<<gc, 128, 0, stream>>>(
        a, xb, xr, ffh, wo_l, bo_l, g1_l, be1_l, wf1_l, bf1_l, N_NODES);
    if (l < NLAYERS - 1) {
      chain2_kernel<false><<<gc, 128, 0, stream>>>(
          ffh, xr, xb, qkv, wf2_l, bf2_l, g2_l, be2_l, wqkv_n,
          bq + (size_t)(l + 1) * DIM, bk + (size_t)(l + 1) * DIM,
          bv + (size_t)(l + 1) * DIM, N_NODES);
    } else {
      chain2_kernel<true><<<gc, 128, 0, stream>>>(
          ffh, xr, xb, qkv, wf2_l, bf2_l, g2_l, be2_l, wqkv_p,
          bq, bk, bv, N_NODES);
    }
  }

  colmean_kernel<<<128, 256, 0, stream>>>(xb, meanb);
  readout_kernel<<<1, 128, 0, stream>>>(meanb, mW0, mb0, mW1, mb1, mW2, mb2, out);
}

// Round 10
// 643.085 us; speedup vs baseline: 1.1048x; 1.0803x over previous
//
#include <hip/hip_runtime.h>
#include <hip/hip_bf16.h>

#define N_NODES 50000
#define N_EDGES 800000
#define DIM 128
#define NLAYERS 3

typedef short bf16x8 __attribute__((ext_vector_type(8)));
typedef float floatx4 __attribute__((ext_vector_type(4)));

__device__ __forceinline__ unsigned short f2bf(float f) {
  unsigned int u = __builtin_bit_cast(unsigned int, f);
  return (unsigned short)((u + 0x7FFFu + ((u >> 16) & 1u)) >> 16);
}
__device__ __forceinline__ float bf2f(unsigned short h) {
  return __builtin_bit_cast(float, (unsigned int)h << 16);
}
__device__ __forceinline__ float2 bf2f2(unsigned int u) {
  float lo = __builtin_bit_cast(float, u << 16);
  float hi = __builtin_bit_cast(float, u & 0xFFFF0000u);
  return make_float2(lo, hi);
}

// ---------------- embedding gather -> bf16 residual ----------------
__global__ __launch_bounds__(256) void embed_kernel(
    const int* __restrict__ idx, const float* __restrict__ emb,
    unsigned short* __restrict__ xb)
{
  int gid = blockIdx.x * 256 + threadIdx.x;
  int n = gid >> 5;
  int c = (gid & 31) << 2;
  if (n >= N_NODES) return;
  int e = idx[n];
  float4 val = *(const float4*)(emb + (size_t)e * DIM + c);
  ushort4 pk;
  pk.x = f2bf(val.x); pk.y = f2bf(val.y); pk.z = f2bf(val.z); pk.w = f2bf(val.w);
  *(ushort4*)(xb + (size_t)n * DIM + c) = pk;
}

// ---------------- CSR build ----------------
__global__ __launch_bounds__(256) void hist_kernel(
    const int* __restrict__ e1, int* __restrict__ counts)
{
  int i = blockIdx.x * 256 + threadIdx.x;
  if (i < N_EDGES) atomicAdd(&counts[e1[i]], 1);
}

__global__ __launch_bounds__(256) void scan_local(
    const int* __restrict__ counts, int* __restrict__ offsets,
    int* __restrict__ bsums)
{
  __shared__ int buf[256];
  int t = threadIdx.x;
  int i = blockIdx.x * 256 + t;
  int v = (i < N_NODES) ? counts[i] : 0;
  buf[t] = v;
  __syncthreads();
  int s = v;
#pragma unroll
  for (int off = 1; off < 256; off <<= 1) {
    int t2 = (t >= off) ? buf[t - off] : 0;
    __syncthreads();
    s += t2;
    buf[t] = s;
    __syncthreads();
  }
  if (i < N_NODES) offsets[i] = s - v;
  if (t == 255) bsums[blockIdx.x] = s;
}

__global__ void scan_bsums(int* __restrict__ bsums, int nblk)
{
  __shared__ int buf[256];
  int t = threadIdx.x;
  int v = (t < nblk) ? bsums[t] : 0;
  buf[t] = v;
  __syncthreads();
  int s = v;
#pragma unroll
  for (int off = 1; off < 256; off <<= 1) {
    int t2 = (t >= off) ? buf[t - off] : 0;
    __syncthreads();
    s += t2;
    buf[t] = s;
    __syncthreads();
  }
  if (t < nblk) bsums[t] = s - v;
}

__global__ __launch_bounds__(256) void scan_add(
    int* __restrict__ offsets, const int* __restrict__ bsums)
{
  int i = blockIdx.x * 256 + threadIdx.x;
  if (i < N_NODES) offsets[i] += bsums[blockIdx.x];
  if (i == 0) offsets[N_NODES] = N_EDGES;
}

__global__ __launch_bounds__(256) void scatter_kernel(
    const int* __restrict__ e0, const int* __restrict__ e1,
    const int* __restrict__ offsets, int* __restrict__ fill,
    int* __restrict__ csr)
{
  int i = blockIdx.x * 256 + threadIdx.x;
  if (i >= N_EDGES) return;
  int d = e1[i];
  int pos = offsets[d] + atomicAdd(&fill[d], 1);
  csr[pos] = e0[i];
}

// ---------------- combined weight prep (single-plane bf16, frag-major) ----------------
// seg A: qkv (q,k,v -> Ndst 384): 18432 frags
// seg B: wo:  3*16*128  = 6144
// seg C: wf1: 3*16*256  = 12288
// seg D: wf2: 3*32*128  = 12288   total 49152
__global__ __launch_bounds__(256) void prep_all(
    const float* __restrict__ Wq, const float* __restrict__ Wk,
    const float* __restrict__ Wv, const float* __restrict__ Wo,
    const float* __restrict__ Wf1, const float* __restrict__ Wf2,
    unsigned short* __restrict__ wqkv, unsigned short* __restrict__ wo,
    unsigned short* __restrict__ wf1, unsigned short* __restrict__ wf2)
{
  int g = blockIdx.x * 256 + threadIdx.x;
  if (g < 18432) {
    int srcId = g / 6144; int rem = g - srcId * 6144;
    const float* W = (srcId == 0) ? Wq : (srcId == 1) ? Wk : Wv;
    int l = rem / 2048; int r2 = rem & 2047; int kq = r2 >> 7; int n = r2 & 127;
    const float* Wl = W + (size_t)l * 128 * 128;
    unsigned short* base = wqkv + (size_t)l * 128 * 384 + (size_t)(kq * 384 + srcId * 128 + n) * 8;
#pragma unroll
    for (int j = 0; j < 8; j++)
      base[j] = f2bf(Wl[(size_t)(kq * 8 + j) * 128 + n]);
    return;
  }
  g -= 18432;
  if (g < 6144) {
    int l = g / 2048; int r2 = g & 2047; int kq = r2 >> 7; int n = r2 & 127;
    const float* Wl = Wo + (size_t)l * 128 * 128;
    unsigned short* base = wo + (size_t)l * 128 * 128 + (size_t)(kq * 128 + n) * 8;
#pragma unroll
    for (int j = 0; j < 8; j++)
      base[j] = f2bf(Wl[(size_t)(kq * 8 + j) * 128 + n]);
    return;
  }
  g -= 6144;
  if (g < 12288) {
    int l = g / 4096; int r2 = g & 4095; int kq = r2 >> 8; int n = r2 & 255;
    const float* Wl = Wf1 + (size_t)l * 128 * 256;
    unsigned short* base = wf1 + (size_t)l * 128 * 256 + (size_t)(kq * 256 + n) * 8;
#pragma unroll
    for (int j = 0; j < 8; j++)
      base[j] = f2bf(Wl[(size_t)(kq * 8 + j) * 256 + n]);
    return;
  }
  g -= 12288;
  if (g < 12288) {
    int l = g / 4096; int r2 = g & 4095; int kq = r2 >> 7; int n = r2 & 127;
    const float* Wl = Wf2 + (size_t)l * 256 * 128;
    unsigned short* base = wf2 + (size_t)l * 256 * 128 + (size_t)(kq * 128 + n) * 8;
#pragma unroll
    for (int j = 0; j < 8; j++)
      base[j] = f2bf(Wl[(size_t)(kq * 8 + j) * 128 + n]);
  }
}

// ---------------- QKV GEMM (layer 0 only) ----------------
__global__ __launch_bounds__(256) void mfma_gemm_qkv(
    const unsigned short* __restrict__ Ab,
    const unsigned short* __restrict__ Wp,
    const float* __restrict__ bq, const float* __restrict__ bk,
    const float* __restrict__ bv,
    unsigned short* __restrict__ out, int nrows)
{
  constexpr int K = 128, N = 384, CT = 8;
  __shared__ unsigned short SW[16 * 128 * 8];   // 32 KB
  int tid = threadIdx.x;
  int c0 = blockIdx.y * 128;
  const float* bias = (blockIdx.y == 0) ? bq : (blockIdx.y == 1) ? bk : bv;
  int wave = tid >> 6, lane = tid & 63;
  int quad = lane >> 4, l16 = lane & 15;
  int row0 = blockIdx.x * 128 + wave * 32;

  floatx4 acc[2][CT];
#pragma unroll
  for (int rt = 0; rt < 2; rt++)
#pragma unroll
    for (int ct = 0; ct < CT; ct++) acc[rt][ct] = (floatx4)(0.f);

  const unsigned short* arow[2];
#pragma unroll
  for (int rt = 0; rt < 2; rt++) {
    int r = min(row0 + rt * 16 + l16, nrows - 1);
    arow[rt] = Ab + (size_t)r * K + quad * 8;
  }
#pragma unroll 4
  for (int f = tid; f < 16 * 128; f += 256) {
    int kq = f >> 7;
    int n = f & 127;
    *(bf16x8*)&SW[f * 8] = *(const bf16x8*)&Wp[(size_t)(kq * N + c0 + n) * 8];
  }
  __syncthreads();
#pragma unroll
  for (int kb = 0; kb < 4; ++kb) {
    bf16x8 av[2];
#pragma unroll
    for (int rt = 0; rt < 2; rt++)
      av[rt] = *(const bf16x8*)(arow[rt] + kb * 32);
#pragma unroll
    for (int ct = 0; ct < CT; ct++) {
      bf16x8 bh = *(bf16x8*)&SW[((kb * 4 + quad) * 128 + ct * 16 + l16) * 8];
#pragma unroll
      for (int rt = 0; rt < 2; rt++)
        acc[rt][ct] = __builtin_amdgcn_mfma_f32_16x16x32_bf16(av[rt], bh, acc[rt][ct], 0, 0, 0);
    }
  }
#pragma unroll
  for (int ct = 0; ct < CT; ct++) {
    float bvv = bias[ct * 16 + l16];
    int col = c0 + ct * 16 + l16;
#pragma unroll
    for (int rt = 0; rt < 2; rt++)
#pragma unroll
      for (int i = 0; i < 4; i++) {
        int r = row0 + rt * 16 + quad * 4 + i;
        if (r < nrows)
          out[(size_t)r * 384 + col] = f2bf(acc[rt][ct][i] + bvv);
      }
  }
}

// ================ chain1: O-GEMM + LN1 + FFN1 (4 waves x 16 rows, single-plane W) ================
#define LSTR 136
__global__ __launch_bounds__(256) void chain1_kernel(
    const unsigned short* __restrict__ a,
    const unsigned short* __restrict__ xb,
    unsigned short* __restrict__ xr,
    unsigned short* __restrict__ ffh,
    const unsigned short* __restrict__ wo, const float* __restrict__ bo,
    const float* __restrict__ g1, const float* __restrict__ be1,
    const unsigned short* __restrict__ wf1, const float* __restrict__ bf1,
    int nrows)
{
  __shared__ unsigned short Y[64 * LSTR];  // 17 KB
  int tid = threadIdx.x;
  int wave = tid >> 6, lane = tid & 63;
  int quad = lane >> 4, l16 = lane & 15;
  int rbase = blockIdx.x * 64;
  int wrow = wave * 16;

  // ---- O-GEMM ----
  floatx4 accO[8];
#pragma unroll
  for (int cc = 0; cc < 8; cc++) accO[cc] = (floatx4)(0.f);
  {
    int grA = min(rbase + wrow + l16, nrows - 1);
    const unsigned short* arow = a + (size_t)grA * 128 + quad * 8;
#pragma unroll
    for (int kb = 0; kb < 4; kb++) {
      bf16x8 av = *(const bf16x8*)(arow + kb * 32);
      int kq = kb * 4 + quad;
      bf16x8 bh[8];
#pragma unroll
      for (int cc = 0; cc < 8; cc++)
        bh[cc] = *(const bf16x8*)&wo[(size_t)(kq * 128 + cc * 16 + l16) * 8];
#pragma unroll
      for (int cc = 0; cc < 8; cc++)
        accO[cc] = __builtin_amdgcn_mfma_f32_16x16x32_bf16(av, bh[cc], accO[cc], 0, 0, 0);
    }
  }

  // ---- LN1 -> xr; y -> Y (per-wave private) ----
  {
    float biasO[8], g1v[8], b1v[8];
#pragma unroll
    for (int cc = 0; cc < 8; cc++) {
      int col = cc * 16 + l16;
      biasO[cc] = bo[col]; g1v[cc] = g1[col]; b1v[cc] = be1[col];
    }
#pragma unroll
    for (int i = 0; i < 4; i++) {
      int lrow = wrow + quad * 4 + i;
      int grow = rbase + lrow;
      int growc = min(grow, nrows - 1);
      float t[8]; float s = 0.f;
#pragma unroll
      for (int cc = 0; cc < 8; cc++) {
        float yv = accO[cc][i] + biasO[cc];
        Y[lrow * LSTR + cc * 16 + l16] = f2bf(yv);
        t[cc] = yv + bf2f(xb[(size_t)growc * 128 + cc * 16 + l16]);
        s += t[cc];
      }
      s += __shfl_xor(s, 1); s += __shfl_xor(s, 2);
      s += __shfl_xor(s, 4); s += __shfl_xor(s, 8);
      float mean = s * (1.f / 128.f);
      float vv = 0.f;
#pragma unroll
      for (int cc = 0; cc < 8; cc++) { float d = t[cc] - mean; vv += d * d; }
      vv += __shfl_xor(vv, 1); vv += __shfl_xor(vv, 2);
      vv += __shfl_xor(vv, 4); vv += __shfl_xor(vv, 8);
      float inv = rsqrtf(vv * (1.f / 128.f) + 1e-5f);
      if (grow < nrows) {
#pragma unroll
        for (int cc = 0; cc < 8; cc++)
          xr[(size_t)grow * 128 + cc * 16 + l16] =
              f2bf((t[cc] - mean) * inv * g1v[cc] + b1v[cc]);
      }
    }
  }

  // ---- FFN1 (K=128, N=256 in two 128-col halves), relu -> ffh ----
  bf16x8 avY[4];
#pragma unroll
  for (int kb = 0; kb < 4; kb++)
    avY[kb] = *(bf16x8*)&Y[(wrow + l16) * LSTR + kb * 32 + quad * 8];
#pragma unroll
  for (int h = 0; h < 2; h++) {
    floatx4 accF[8];
#pragma unroll
    for (int cc = 0; cc < 8; cc++) accF[cc] = (floatx4)(0.f);
#pragma unroll
    for (int kb = 0; kb < 4; kb++) {
      int kq = kb * 4 + quad;
      bf16x8 bh[8];
#pragma unroll
      for (int cc = 0; cc < 8; cc++)
        bh[cc] = *(const bf16x8*)&wf1[(size_t)(kq * 256 + h * 128 + cc * 16 + l16) * 8];
#pragma unroll
      for (int cc = 0; cc < 8; cc++)
        accF[cc] = __builtin_amdgcn_mfma_f32_16x16x32_bf16(avY[kb], bh[cc], accF[cc], 0, 0, 0);
    }
#pragma unroll
    for (int i = 0; i < 4; i++) {
      int grow = rbase + wrow + quad * 4 + i;
      if (grow < nrows) {
#pragma unroll
        for (int cc = 0; cc < 8; cc++) {
          float fv = fmaxf(accF[cc][i] + bf1[h * 128 + cc * 16 + l16], 0.f);
          ffh[(size_t)grow * 256 + h * 128 + cc * 16 + l16] = f2bf(fv);
        }
      }
    }
  }
}

// ================ chain2: FFN2 + LN2 + QKV(next) (4 waves x 16 rows, single-plane W) ================
template<bool LAST>
__global__ __launch_bounds__(256) void chain2_kernel(
    const unsigned short* __restrict__ ffh,
    const unsigned short* __restrict__ xr,
    unsigned short* __restrict__ xb,
    unsigned short* __restrict__ qkv,
    const unsigned short* __restrict__ wf2, const float* __restrict__ bf2,
    const float* __restrict__ g2, const float* __restrict__ be2,
    const unsigned short* __restrict__ wqkv,
    const float* __restrict__ bq, const float* __restrict__ bk,
    const float* __restrict__ bv, int nrows)
{
  __shared__ unsigned short Y[64 * LSTR];  // 17 KB
  int tid = threadIdx.x;
  int wave = tid >> 6, lane = tid & 63;
  int quad = lane >> 4, l16 = lane & 15;
  int rbase = blockIdx.x * 64;
  int wrow = wave * 16;

  // ---- FFN2 (K=256) ----
  floatx4 acc2[8];
#pragma unroll
  for (int cc = 0; cc < 8; cc++) acc2[cc] = (floatx4)(0.f);
  {
    int grA = min(rbase + wrow + l16, nrows - 1);
    const unsigned short* arow = ffh + (size_t)grA * 256 + quad * 8;
#pragma unroll
    for (int h = 0; h < 2; h++) {
#pragma unroll
      for (int kb = 0; kb < 4; kb++) {
        bf16x8 av = *(const bf16x8*)(arow + h * 128 + kb * 32);
        int kq = h * 16 + kb * 4 + quad;
        bf16x8 bh[8];
#pragma unroll
        for (int cc = 0; cc < 8; cc++)
          bh[cc] = *(const bf16x8*)&wf2[(size_t)(kq * 128 + cc * 16 + l16) * 8];
#pragma unroll
        for (int cc = 0; cc < 8; cc++)
          acc2[cc] = __builtin_amdgcn_mfma_f32_16x16x32_bf16(av, bh[cc], acc2[cc], 0, 0, 0);
      }
    }
  }

  // ---- LN2 -> xb; x2 -> Y ----
  {
    float bias2[8], g2v[8], b2v[8];
#pragma unroll
    for (int cc = 0; cc < 8; cc++) {
      int col = cc * 16 + l16;
      bias2[cc] = bf2[col]; g2v[cc] = g2[col]; b2v[cc] = be2[col];
    }
#pragma unroll
    for (int i = 0; i < 4; i++) {
      int lrow = wrow + quad * 4 + i;
      int grow = rbase + lrow;
      int growc = min(grow, nrows - 1);
      float t[8]; float s = 0.f;
#pragma unroll
      for (int cc = 0; cc < 8; cc++) {
        t[cc] = acc2[cc][i] + bias2[cc] + bf2f(xr[(size_t)growc * 128 + cc * 16 + l16]);
        s += t[cc];
      }
      s += __shfl_xor(s, 1); s += __shfl_xor(s, 2);
      s += __shfl_xor(s, 4); s += __shfl_xor(s, 8);
      float mean = s * (1.f / 128.f);
      float vv = 0.f;
#pragma unroll
      for (int cc = 0; cc < 8; cc++) { float d = t[cc] - mean; vv += d * d; }
      vv += __shfl_xor(vv, 1); vv += __shfl_xor(vv, 2);
      vv += __shfl_xor(vv, 4); vv += __shfl_xor(vv, 8);
      float inv = rsqrtf(vv * (1.f / 128.f) + 1e-5f);
#pragma unroll
      for (int cc = 0; cc < 8; cc++) {
        float o = (t[cc] - mean) * inv * g2v[cc] + b2v[cc];
        unsigned short ob = f2bf(o);
        Y[lrow * LSTR + cc * 16 + l16] = ob;
        if (grow < nrows) xb[(size_t)grow * 128 + cc * 16 + l16] = ob;
      }
    }
  }

  // ---- QKV next ----
  if (!LAST) {
    bf16x8 avQ[4];
#pragma unroll
    for (int kb = 0; kb < 4; kb++)
      avQ[kb] = *(bf16x8*)&Y[(wrow + l16) * LSTR + kb * 32 + quad * 8];
#pragma unroll
    for (int c = 0; c < 3; c++) {
      floatx4 accQ[8];
#pragma unroll
      for (int ct = 0; ct < 8; ct++) accQ[ct] = (floatx4)(0.f);
#pragma unroll
      for (int kb = 0; kb < 4; kb++) {
        int kq = kb * 4 + quad;
        bf16x8 bh[8];
#pragma unroll
        for (int ct = 0; ct < 8; ct++)
          bh[ct] = *(const bf16x8*)&wqkv[(size_t)(kq * 384 + c * 128 + ct * 16 + l16) * 8];
#pragma unroll
        for (int ct = 0; ct < 8; ct++)
          accQ[ct] = __builtin_amdgcn_mfma_f32_16x16x32_bf16(avQ[kb], bh[ct], accQ[ct], 0, 0, 0);
      }
      const float* bias = (c == 0) ? bq : (c == 1) ? bk : bv;
#pragma unroll
      for (int ct = 0; ct < 8; ct++) {
        float bvv = bias[ct * 16 + l16];
#pragma unroll
        for (int i = 0; i < 4; i++) {
          int grow = rbase + wrow + quad * 4 + i;
          if (grow < nrows)
            qkv[(size_t)grow * 384 + c * 128 + ct * 16 + l16] = f2bf(accQ[ct][i] + bvv);
        }
      }
    }
  }
}
#undef LSTR

// ---------------- fused edge attention: one wave per dst node, x8 unroll ----------------
#define ATTN_C  0.36067376022f
#define ATTN_L  7.21347520444f
__device__ __forceinline__ float edge_score(float p) {
  float t = fminf(fmaxf(p * ATTN_C, -ATTN_L), ATTN_L);
  return __builtin_amdgcn_exp2f(t);
}
__global__ __launch_bounds__(256) void attn_kernel(
    const unsigned short* __restrict__ qkv,
    const int* __restrict__ offsets, const int* __restrict__ csr,
    unsigned short* __restrict__ attn)
{
  int node = blockIdx.x * 4 + (threadIdx.x >> 6);
  int lane = threadIdx.x & 63;
  if (node >= N_NODES) return;
  float2 q2 = bf2f2(*(const unsigned int*)(qkv + (size_t)node * 384 + lane * 2));
  const unsigned short* kbase = qkv + 128 + lane * 2;
  float wx = 0.f, wy = 0.f, z = 0.f;
  int j = offsets[node], end = offsets[node + 1];
  for (; j + 8 <= end; j += 8) {
    int s[8];
#pragma unroll
    for (int u = 0; u < 8; u++) s[u] = csr[j + u];
    unsigned int ku[8], vu[8];
#pragma unroll
    for (int u = 0; u < 8; u++) {
      const unsigned short* r = kbase + (size_t)s[u] * 384;
      ku[u] = *(const unsigned int*)r;
      vu[u] = *(const unsigned int*)(r + 128);
    }
    float p[8];
#pragma unroll
    for (int u = 0; u < 8; u++) {
      float2 k2 = bf2f2(ku[u]);
      p[u] = k2.x * q2.x + k2.y * q2.y;
    }
#pragma unroll
    for (int u = 0; u < 8; u++) p[u] += __shfl_xor(p[u], 1);
#pragma unroll
    for (int u = 0; u < 8; u++) p[u] += __shfl_xor(p[u], 2);
#pragma unroll
    for (int u = 0; u < 8; u++) p[u] += __shfl_xor(p[u], 4);
#pragma unroll
    for (int u = 0; u < 8; u++) {
      float sc = edge_score(p[u]);
      float2 v2 = bf2f2(vu[u]);
      wx = fmaf(sc, v2.x, wx);
      wy = fmaf(sc, v2.y, wy);
      z += sc;
    }
  }
  for (; j < end; ++j) {
    int s = csr[j];
    const unsigned short* r = kbase + (size_t)s * 384;
    float2 k2 = bf2f2(*(const unsigned int*)r);
    float p = k2.x * q2.x + k2.y * q2.y;
    p += __shfl_xor(p, 1); p += __shfl_xor(p, 2); p += __shfl_xor(p, 4);
    float sc = edge_score(p);
    float2 v2 = bf2f2(*(const unsigned int*)(r + 128));
    wx = fmaf(sc, v2.x, wx); wy = fmaf(sc, v2.y, wy);
    z += sc;
  }
  float inv = 1.f / (z + 1e-6f);
  unsigned int pack = (unsigned int)f2bf(wx * inv) | ((unsigned int)f2bf(wy * inv) << 16);
  *(unsigned int*)(attn + (size_t)node * DIM + lane * 2) = pack;
}

// ---------------- column mean over nodes (bf16 in, fp32 acc) ----------------
__global__ __launch_bounds__(256) void colmean_kernel(
    const unsigned short* __restrict__ xb, float* __restrict__ mean)
{
  int col = threadIdx.x & 127;
  int half = threadIdx.x >> 7;
  float acc = 0.f;
  for (int r = blockIdx.x * 2 + half; r < N_NODES; r += gridDim.x * 2)
    acc += bf2f(xb[(size_t)r * DIM + col]);
  __shared__ float s[256];
  s[threadIdx.x] = acc;
  __syncthreads();
  if (threadIdx.x < 128) atomicAdd(&mean[col], s[threadIdx.x] + s[threadIdx.x + 128]);
}

// ---------------- readout MLP 128->64->32->10 ----------------
__global__ void readout_kernel(
    const float* __restrict__ mean,
    const float* __restrict__ mW0, const float* __restrict__ mb0,
    const float* __restrict__ mW1, const float* __restrict__ mb1,
    const float* __restrict__ mW2, const float* __restrict__ mb2,
    float* __restrict__ out)
{
  __shared__ float sx[128], h0[64], h1[32];
  int t = threadIdx.x;
  sx[t] = mean[t] * (1.f / (float)N_NODES);
  __syncthreads();
  if (t < 64) {
    float a = mb0[t];
    for (int i = 0; i < 128; i++) a = fmaf(sx[i], mW0[i * 64 + t], a);
    h0[t] = fmaxf(a, 0.f);
  }
  __syncthreads();
  if (t < 32) {
    float a = mb1[t];
    for (int i = 0; i < 64; i++) a = fmaf(h0[i], mW1[i * 32 + t], a);
    h1[t] = fmaxf(a, 0.f);
  }
  __syncthreads();
  if (t < 10) {
    float a = mb2[t];
    for (int i = 0; i < 32; i++) a = fmaf(h1[i], mW2[i * 10 + t], a);
    out[t] = a;
  }
}

extern "C" void kernel_launch(void* const* d_in, const int* in_sizes, int n_in,
                              void* d_out, int out_size, void* d_ws, size_t ws_size,
                              hipStream_t stream) {
  const int*   x_idx = (const int*)d_in[0];
  const int*   eidx  = (const int*)d_in[1];
  const float* emb   = (const float*)d_in[2];
  const float* Wq = (const float*)d_in[3];  const float* bq = (const float*)d_in[4];
  const float* Wk = (const float*)d_in[5];  const float* bk = (const float*)d_in[6];
  const float* Wv = (const float*)d_in[7];  const float* bv = (const float*)d_in[8];
  const float* Wo = (const float*)d_in[9];  const float* bo = (const float*)d_in[10];
  const float* g1 = (const float*)d_in[11]; const float* be1 = (const float*)d_in[12];
  const float* Wf1 = (const float*)d_in[13]; const float* bf1 = (const float*)d_in[14];
  const float* Wf2 = (const float*)d_in[15]; const float* bf2 = (const float*)d_in[16];
  const float* g2 = (const float*)d_in[17]; const float* be2 = (const float*)d_in[18];
  const float* mW0 = (const float*)d_in[19]; const float* mb0 = (const float*)d_in[20];
  const float* mW1 = (const float*)d_in[21]; const float* mb1 = (const float*)d_in[22];
  const float* mW2 = (const float*)d_in[23]; const float* mb2 = (const float*)d_in[24];
  float* out = (float*)d_out;

  const size_t NX = (size_t)N_NODES * DIM;
  unsigned short* xb  = (unsigned short*)d_ws;
  unsigned short* qkv = xb + NX;
  unsigned short* a   = qkv + (size_t)N_NODES * 384;
  unsigned short* xr  = a + NX;
  unsigned short* ffh = xr + NX;

  unsigned short* wqkv_p = ffh + (size_t)N_NODES * 256;   // 3*128*384
  unsigned short* wo_p   = wqkv_p + 3 * 128 * 384;        // 3*128*128
  unsigned short* wf1_p  = wo_p   + 3 * 128 * 128;        // 3*128*256
  unsigned short* wf2_p  = wf1_p  + 3 * 128 * 256;        // 3*256*128
  unsigned short* wend   = wf2_p  + 3 * 256 * 128;

  int* counts  = (int*)wend;
  int* fill    = counts + N_NODES;
  float* meanb = (float*)(fill + N_NODES);
  int* offsets = (int*)(meanb + DIM);
  int* bsums   = offsets + N_NODES + 1;
  int* csr     = bsums + 256;

  const int* e0 = eidx;
  const int* e1 = eidx + N_EDGES;

  hipMemsetAsync(counts, 0, (2 * N_NODES + DIM) * sizeof(int), stream);

  prep_all<<<192, 256, 0, stream>>>(Wq, Wk, Wv, Wo, Wf1, Wf2,
                                    wqkv_p, wo_p, wf1_p, wf2_p);

  embed_kernel<<<(N_NODES * 32 + 255) / 256, 256, 0, stream>>>(x_idx, emb, xb);
  hist_kernel<<<(N_EDGES + 255) / 256, 256, 0, stream>>>(e1, counts);
  int nblk = (N_NODES + 255) / 256;
  scan_local<<<nblk, 256, 0, stream>>>(counts, offsets, bsums);
  scan_bsums<<<1, 256, 0, stream>>>(bsums, nblk);
  scan_add<<<nblk, 256, 0, stream>>>(offsets, bsums);
  scatter_kernel<<<(N_EDGES + 255) / 256, 256, 0, stream>>>(e0, e1, offsets, fill, csr);

  int gx = (N_NODES + 127) / 128;
  int gc = (N_NODES + 63) / 64;        // 782, 256-thread blocks
  int nb4 = (N_NODES + 3) / 4;

  mfma_gemm_qkv<<<dim3(gx, 3), 256, 0, stream>>>(xb, wqkv_p, bq, bk, bv, qkv, N_NODES);

  for (int l = 0; l < NLAYERS; ++l) {
    const unsigned short* wo_l   = wo_p   + (size_t)l * 128 * 128;
    const unsigned short* wf1_l  = wf1_p  + (size_t)l * 128 * 256;
    const unsigned short* wf2_l  = wf2_p  + (size_t)l * 256 * 128;
    const unsigned short* wqkv_n = wqkv_p + (size_t)(l + 1) * 128 * 384;
    const float* bo_l  = bo  + (size_t)l * DIM;
    const float* g1_l  = g1  + (size_t)l * DIM;
    const float* be1_l = be1 + (size_t)l * DIM;
    const float* bf1_l = bf1 + (size_t)l * 2 * DIM;
    const float* bf2_l = bf2 + (size_t)l * DIM;
    const float* g2_l  = g2  + (size_t)l * DIM;
    const float* be2_l = be2 + (size_t)l * DIM;

    attn_kernel<<<nb4, 256, 0, stream>>>(qkv, offsets, csr, a);
    chain1_kernel<<<gc, 256, 0, stream>>>(
        a, xb, xr, ffh, wo_l, bo_l, g1_l, be1_l, wf1_l, bf1_l, N_NODES);
    if (l < NLAYERS - 1) {
      chain2_kernel<false><<<gc, 256, 0, stream>>>(
          ffh, xr, xb, qkv, wf2_l, bf2_l, g2_l, be2_l, wqkv_n,
          bq + (size_t)(l + 1) * DIM, bk + (size_t)(l + 1) * DIM,
          bv + (size_t)(l + 1) * DIM, N_NODES);
    } else {
      chain2_kernel<true><<<gc, 256, 0, stream>>>(
          ffh, xr, xb, qkv, wf2_l, bf2_l, g2_l, be2_l, wqkv_p,
          bq, bk, bv, N_NODES);
    }
  }

  colmean_kernel<<<128, 256, 0, stream>>>(xb, meanb);
  readout_kernel<<<1, 128, 0, stream>>>(meanb, mW0, mb0, mW1, mb1, mW2, mb2, out);
}

// Round 11
// 639.003 us; speedup vs baseline: 1.1119x; 1.0064x over previous
//
#include <hip/hip_runtime.h>
#include <hip/hip_bf16.h>

#define N_NODES 50000
#define N_EDGES 800000
#define DIM 128
#define NLAYERS 3

typedef short bf16x8 __attribute__((ext_vector_type(8)));
typedef float floatx4 __attribute__((ext_vector_type(4)));

__device__ __forceinline__ unsigned short f2bf(float f) {
  unsigned int u = __builtin_bit_cast(unsigned int, f);
  return (unsigned short)((u + 0x7FFFu + ((u >> 16) & 1u)) >> 16);
}
__device__ __forceinline__ float bf2f(unsigned short h) {
  return __builtin_bit_cast(float, (unsigned int)h << 16);
}
__device__ __forceinline__ float2 bf2f2(unsigned int u) {
  float lo = __builtin_bit_cast(float, u << 16);
  float hi = __builtin_bit_cast(float, u & 0xFFFF0000u);
  return make_float2(lo, hi);
}

// ---------------- embedding gather -> bf16 residual ----------------
__global__ __launch_bounds__(256) void embed_kernel(
    const int* __restrict__ idx, const float* __restrict__ emb,
    unsigned short* __restrict__ xb)
{
  int gid = blockIdx.x * 256 + threadIdx.x;
  int n = gid >> 5;
  int c = (gid & 31) << 2;
  if (n >= N_NODES) return;
  int e = idx[n];
  float4 val = *(const float4*)(emb + (size_t)e * DIM + c);
  ushort4 pk;
  pk.x = f2bf(val.x); pk.y = f2bf(val.y); pk.z = f2bf(val.z); pk.w = f2bf(val.w);
  *(ushort4*)(xb + (size_t)n * DIM + c) = pk;
}

// ---------------- CSR build ----------------
__global__ __launch_bounds__(256) void hist_kernel(
    const int* __restrict__ e1, int* __restrict__ counts)
{
  int i = blockIdx.x * 256 + threadIdx.x;
  if (i < N_EDGES) atomicAdd(&counts[e1[i]], 1);
}

__global__ __launch_bounds__(256) void scan_local(
    const int* __restrict__ counts, int* __restrict__ offsets,
    int* __restrict__ bsums)
{
  __shared__ int buf[256];
  int t = threadIdx.x;
  int i = blockIdx.x * 256 + t;
  int v = (i < N_NODES) ? counts[i] : 0;
  buf[t] = v;
  __syncthreads();
  int s = v;
#pragma unroll
  for (int off = 1; off < 256; off <<= 1) {
    int t2 = (t >= off) ? buf[t - off] : 0;
    __syncthreads();
    s += t2;
    buf[t] = s;
    __syncthreads();
  }
  if (i < N_NODES) offsets[i] = s - v;
  if (t == 255) bsums[blockIdx.x] = s;
}

__global__ void scan_bsums(int* __restrict__ bsums, int nblk)
{
  __shared__ int buf[256];
  int t = threadIdx.x;
  int v = (t < nblk) ? bsums[t] : 0;
  buf[t] = v;
  __syncthreads();
  int s = v;
#pragma unroll
  for (int off = 1; off < 256; off <<= 1) {
    int t2 = (t >= off) ? buf[t - off] : 0;
    __syncthreads();
    s += t2;
    buf[t] = s;
    __syncthreads();
  }
  if (t < nblk) bsums[t] = s - v;
}

__global__ __launch_bounds__(256) void scan_add(
    int* __restrict__ offsets, const int* __restrict__ bsums)
{
  int i = blockIdx.x * 256 + threadIdx.x;
  if (i < N_NODES) offsets[i] += bsums[blockIdx.x];
  if (i == 0) offsets[N_NODES] = N_EDGES;
}

__global__ __launch_bounds__(256) void scatter_kernel(
    const int* __restrict__ e0, const int* __restrict__ e1,
    const int* __restrict__ offsets, int* __restrict__ fill,
    int* __restrict__ csr)
{
  int i = blockIdx.x * 256 + threadIdx.x;
  if (i >= N_EDGES) return;
  int d = e1[i];
  int pos = offsets[d] + atomicAdd(&fill[d], 1);
  csr[pos] = e0[i];
}

// ---------------- combined weight prep (single-plane bf16, frag-major) ----------------
__global__ __launch_bounds__(256) void prep_all(
    const float* __restrict__ Wq, const float* __restrict__ Wk,
    const float* __restrict__ Wv, const float* __restrict__ Wo,
    const float* __restrict__ Wf1, const float* __restrict__ Wf2,
    unsigned short* __restrict__ wqkv, unsigned short* __restrict__ wo,
    unsigned short* __restrict__ wf1, unsigned short* __restrict__ wf2)
{
  int g = blockIdx.x * 256 + threadIdx.x;
  if (g < 18432) {
    int srcId = g / 6144; int rem = g - srcId * 6144;
    const float* W = (srcId == 0) ? Wq : (srcId == 1) ? Wk : Wv;
    int l = rem / 2048; int r2 = rem & 2047; int kq = r2 >> 7; int n = r2 & 127;
    const float* Wl = W + (size_t)l * 128 * 128;
    unsigned short* base = wqkv + (size_t)l * 128 * 384 + (size_t)(kq * 384 + srcId * 128 + n) * 8;
#pragma unroll
    for (int j = 0; j < 8; j++)
      base[j] = f2bf(Wl[(size_t)(kq * 8 + j) * 128 + n]);
    return;
  }
  g -= 18432;
  if (g < 6144) {
    int l = g / 2048; int r2 = g & 2047; int kq = r2 >> 7; int n = r2 & 127;
    const float* Wl = Wo + (size_t)l * 128 * 128;
    unsigned short* base = wo + (size_t)l * 128 * 128 + (size_t)(kq * 128 + n) * 8;
#pragma unroll
    for (int j = 0; j < 8; j++)
      base[j] = f2bf(Wl[(size_t)(kq * 8 + j) * 128 + n]);
    return;
  }
  g -= 6144;
  if (g < 12288) {
    int l = g / 4096; int r2 = g & 4095; int kq = r2 >> 8; int n = r2 & 255;
    const float* Wl = Wf1 + (size_t)l * 128 * 256;
    unsigned short* base = wf1 + (size_t)l * 128 * 256 + (size_t)(kq * 256 + n) * 8;
#pragma unroll
    for (int j = 0; j < 8; j++)
      base[j] = f2bf(Wl[(size_t)(kq * 8 + j) * 256 + n]);
    return;
  }
  g -= 12288;
  if (g < 12288) {
    int l = g / 4096; int r2 = g & 4095; int kq = r2 >> 7; int n = r2 & 127;
    const float* Wl = Wf2 + (size_t)l * 256 * 128;
    unsigned short* base = wf2 + (size_t)l * 256 * 128 + (size_t)(kq * 128 + n) * 8;
#pragma unroll
    for (int j = 0; j < 8; j++)
      base[j] = f2bf(Wl[(size_t)(kq * 8 + j) * 128 + n]);
  }
}

// ---------------- QKV GEMM (layer 0 only) ----------------
__global__ __launch_bounds__(256) void mfma_gemm_qkv(
    const unsigned short* __restrict__ Ab,
    const unsigned short* __restrict__ Wp,
    const float* __restrict__ bq, const float* __restrict__ bk,
    const float* __restrict__ bv,
    unsigned short* __restrict__ out, int nrows)
{
  constexpr int K = 128, N = 384, CT = 8;
  __shared__ unsigned short SW[16 * 128 * 8];   // 32 KB
  int tid = threadIdx.x;
  int c0 = blockIdx.y * 128;
  const float* bias = (blockIdx.y == 0) ? bq : (blockIdx.y == 1) ? bk : bv;
  int wave = tid >> 6, lane = tid & 63;
  int quad = lane >> 4, l16 = lane & 15;
  int row0 = blockIdx.x * 128 + wave * 32;

  floatx4 acc[2][CT];
#pragma unroll
  for (int rt = 0; rt < 2; rt++)
#pragma unroll
    for (int ct = 0; ct < CT; ct++) acc[rt][ct] = (floatx4)(0.f);

  const unsigned short* arow[2];
#pragma unroll
  for (int rt = 0; rt < 2; rt++) {
    int r = min(row0 + rt * 16 + l16, nrows - 1);
    arow[rt] = Ab + (size_t)r * K + quad * 8;
  }
#pragma unroll 4
  for (int f = tid; f < 16 * 128; f += 256) {
    int kq = f >> 7;
    int n = f & 127;
    *(bf16x8*)&SW[f * 8] = *(const bf16x8*)&Wp[(size_t)(kq * N + c0 + n) * 8];
  }
  __syncthreads();
#pragma unroll
  for (int kb = 0; kb < 4; ++kb) {
    bf16x8 av[2];
#pragma unroll
    for (int rt = 0; rt < 2; rt++)
      av[rt] = *(const bf16x8*)(arow[rt] + kb * 32);
#pragma unroll
    for (int ct = 0; ct < CT; ct++) {
      bf16x8 bh = *(bf16x8*)&SW[((kb * 4 + quad) * 128 + ct * 16 + l16) * 8];
#pragma unroll
      for (int rt = 0; rt < 2; rt++)
        acc[rt][ct] = __builtin_amdgcn_mfma_f32_16x16x32_bf16(av[rt], bh, acc[rt][ct], 0, 0, 0);
    }
  }
#pragma unroll
  for (int ct = 0; ct < CT; ct++) {
    float bvv = bias[ct * 16 + l16];
    int col = c0 + ct * 16 + l16;
#pragma unroll
    for (int rt = 0; rt < 2; rt++)
#pragma unroll
      for (int i = 0; i < 4; i++) {
        int r = row0 + rt * 16 + quad * 4 + i;
        if (r < nrows)
          out[(size_t)r * 384 + col] = f2bf(acc[rt][ct][i] + bvv);
      }
  }
}

// ================ chain1: O-GEMM + LN1 + FFN1 (4 waves x 16 rows) ================
// All residual global I/O staged through per-wave-private LDS (no barriers):
// scattered C-layout values <-> LDS (cheap), global <-> LDS as 16B/lane coalesced.
#define LSTR 136
__global__ __launch_bounds__(256) void chain1_kernel(
    const unsigned short* __restrict__ a,
    const unsigned short* __restrict__ xb,
    unsigned short* __restrict__ xr,
    unsigned short* __restrict__ ffh,
    const unsigned short* __restrict__ wo, const float* __restrict__ bo,
    const float* __restrict__ g1, const float* __restrict__ be1,
    const unsigned short* __restrict__ wf1, const float* __restrict__ bf1,
    int nrows)
{
  __shared__ unsigned short Y[64 * LSTR];  // 17 KB: y (FFN1 A-source)
  __shared__ unsigned short F[64 * LSTR];  // 17 KB: xb-in / x1-out / ffh-out staging
  int tid = threadIdx.x;
  int wave = tid >> 6, lane = tid & 63;
  int quad = lane >> 4, l16 = lane & 15;
  int rbase = blockIdx.x * 64;
  int wrow = wave * 16;
  int rowg = min(rbase + wrow + l16, nrows - 1);   // this lane's coalesced-I/O row
  int lrow_v = (wrow + l16) * LSTR + quad * 8;      // LDS addr base for vector I/O

  // stage xb -> F (4 coalesced 16B loads/lane)
#pragma unroll
  for (int kb = 0; kb < 4; kb++)
    *(bf16x8*)&F[lrow_v + kb * 32] =
        *(const bf16x8*)&xb[(size_t)rowg * 128 + kb * 32 + quad * 8];

  // ---- O-GEMM ----
  floatx4 accO[8];
#pragma unroll
  for (int cc = 0; cc < 8; cc++) accO[cc] = (floatx4)(0.f);
  {
    const unsigned short* arow = a + (size_t)rowg * 128 + quad * 8;
#pragma unroll
    for (int kb = 0; kb < 4; kb++) {
      bf16x8 av = *(const bf16x8*)(arow + kb * 32);
      int kq = kb * 4 + quad;
      bf16x8 bh[8];
#pragma unroll
      for (int cc = 0; cc < 8; cc++)
        bh[cc] = *(const bf16x8*)&wo[(size_t)(kq * 128 + cc * 16 + l16) * 8];
#pragma unroll
      for (int cc = 0; cc < 8; cc++)
        accO[cc] = __builtin_amdgcn_mfma_f32_16x16x32_bf16(av, bh[cc], accO[cc], 0, 0, 0);
    }
  }

  // ---- LN1: t = y + xb(F); x1 -> F (in-place); y -> Y ----
  {
    float biasO[8], g1v[8], b1v[8];
#pragma unroll
    for (int cc = 0; cc < 8; cc++) {
      int col = cc * 16 + l16;
      biasO[cc] = bo[col]; g1v[cc] = g1[col]; b1v[cc] = be1[col];
    }
#pragma unroll
    for (int i = 0; i < 4; i++) {
      int lrow = wrow + quad * 4 + i;
      float t[8]; float s = 0.f;
#pragma unroll
      for (int cc = 0; cc < 8; cc++) {
        float yv = accO[cc][i] + biasO[cc];
        Y[lrow * LSTR + cc * 16 + l16] = f2bf(yv);
        t[cc] = yv + bf2f(F[lrow * LSTR + cc * 16 + l16]);
        s += t[cc];
      }
      s += __shfl_xor(s, 1); s += __shfl_xor(s, 2);
      s += __shfl_xor(s, 4); s += __shfl_xor(s, 8);
      float mean = s * (1.f / 128.f);
      float vv = 0.f;
#pragma unroll
      for (int cc = 0; cc < 8; cc++) { float d = t[cc] - mean; vv += d * d; }
      vv += __shfl_xor(vv, 1); vv += __shfl_xor(vv, 2);
      vv += __shfl_xor(vv, 4); vv += __shfl_xor(vv, 8);
      float inv = rsqrtf(vv * (1.f / 128.f) + 1e-5f);
#pragma unroll
      for (int cc = 0; cc < 8; cc++)
        F[lrow * LSTR + cc * 16 + l16] =
            f2bf((t[cc] - mean) * inv * g1v[cc] + b1v[cc]);
    }
  }
  // vector-store x1 (F) -> xr
  if (rbase + wrow + l16 < nrows) {
#pragma unroll
    for (int kb = 0; kb < 4; kb++)
      *(bf16x8*)&xr[(size_t)(rbase + wrow + l16) * 128 + kb * 32 + quad * 8] =
          *(bf16x8*)&F[lrow_v + kb * 32];
  }

  // ---- FFN1 (K=128, N=256 in two 128-col halves), relu -> ffh via F staging ----
  bf16x8 avY[4];
#pragma unroll
  for (int kb = 0; kb < 4; kb++)
    avY[kb] = *(bf16x8*)&Y[lrow_v + kb * 32];
#pragma unroll
  for (int h = 0; h < 2; h++) {
    floatx4 accF[8];
#pragma unroll
    for (int cc = 0; cc < 8; cc++) accF[cc] = (floatx4)(0.f);
#pragma unroll
    for (int kb = 0; kb < 4; kb++) {
      int kq = kb * 4 + quad;
      bf16x8 bh[8];
#pragma unroll
      for (int cc = 0; cc < 8; cc++)
        bh[cc] = *(const bf16x8*)&wf1[(size_t)(kq * 256 + h * 128 + cc * 16 + l16) * 8];
#pragma unroll
      for (int cc = 0; cc < 8; cc++)
        accF[cc] = __builtin_amdgcn_mfma_f32_16x16x32_bf16(avY[kb], bh[cc], accF[cc], 0, 0, 0);
    }
#pragma unroll
    for (int i = 0; i < 4; i++) {
      int lrow = wrow + quad * 4 + i;
#pragma unroll
      for (int cc = 0; cc < 8; cc++)
        F[lrow * LSTR + cc * 16 + l16] =
            f2bf(fmaxf(accF[cc][i] + bf1[h * 128 + cc * 16 + l16], 0.f));
    }
    if (rbase + wrow + l16 < nrows) {
#pragma unroll
      for (int kb = 0; kb < 4; kb++)
        *(bf16x8*)&ffh[(size_t)(rbase + wrow + l16) * 256 + h * 128 + kb * 32 + quad * 8] =
            *(bf16x8*)&F[lrow_v + kb * 32];
    }
  }
}

// ================ chain2: FFN2 + LN2 + QKV(next) (4 waves x 16 rows) ================
template<bool LAST>
__global__ __launch_bounds__(256) void chain2_kernel(
    const unsigned short* __restrict__ ffh,
    const unsigned short* __restrict__ xr,
    unsigned short* __restrict__ xb,
    unsigned short* __restrict__ qkv,
    const unsigned short* __restrict__ wf2, const float* __restrict__ bf2,
    const float* __restrict__ g2, const float* __restrict__ be2,
    const unsigned short* __restrict__ wqkv,
    const float* __restrict__ bq, const float* __restrict__ bk,
    const float* __restrict__ bv, int nrows)
{
  __shared__ unsigned short Y[64 * LSTR];   // x2 (QKV A-source + xb store staging)
  __shared__ unsigned short XR[64 * LSTR];  // xr-in / qkv-out staging
  int tid = threadIdx.x;
  int wave = tid >> 6, lane = tid & 63;
  int quad = lane >> 4, l16 = lane & 15;
  int rbase = blockIdx.x * 64;
  int wrow = wave * 16;
  int rowg = min(rbase + wrow + l16, nrows - 1);
  int lrow_v = (wrow + l16) * LSTR + quad * 8;
  bool wr = (rbase + wrow + l16 < nrows);

  // stage xr -> XR
#pragma unroll
  for (int kb = 0; kb < 4; kb++)
    *(bf16x8*)&XR[lrow_v + kb * 32] =
        *(const bf16x8*)&xr[(size_t)rowg * 128 + kb * 32 + quad * 8];

  // ---- FFN2 (K=256) ----
  floatx4 acc2[8];
#pragma unroll
  for (int cc = 0; cc < 8; cc++) acc2[cc] = (floatx4)(0.f);
  {
    const unsigned short* arow = ffh + (size_t)rowg * 256 + quad * 8;
#pragma unroll
    for (int h = 0; h < 2; h++) {
#pragma unroll
      for (int kb = 0; kb < 4; kb++) {
        bf16x8 av = *(const bf16x8*)(arow + h * 128 + kb * 32);
        int kq = h * 16 + kb * 4 + quad;
        bf16x8 bh[8];
#pragma unroll
        for (int cc = 0; cc < 8; cc++)
          bh[cc] = *(const bf16x8*)&wf2[(size_t)(kq * 128 + cc * 16 + l16) * 8];
#pragma unroll
        for (int cc = 0; cc < 8; cc++)
          acc2[cc] = __builtin_amdgcn_mfma_f32_16x16x32_bf16(av, bh[cc], acc2[cc], 0, 0, 0);
      }
    }
  }

  // ---- LN2: t = ffn2 + x1(XR); x2 -> Y ----
  {
    float bias2[8], g2v[8], b2v[8];
#pragma unroll
    for (int cc = 0; cc < 8; cc++) {
      int col = cc * 16 + l16;
      bias2[cc] = bf2[col]; g2v[cc] = g2[col]; b2v[cc] = be2[col];
    }
#pragma unroll
    for (int i = 0; i < 4; i++) {
      int lrow = wrow + quad * 4 + i;
      float t[8]; float s = 0.f;
#pragma unroll
      for (int cc = 0; cc < 8; cc++) {
        t[cc] = acc2[cc][i] + bias2[cc] + bf2f(XR[lrow * LSTR + cc * 16 + l16]);
        s += t[cc];
      }
      s += __shfl_xor(s, 1); s += __shfl_xor(s, 2);
      s += __shfl_xor(s, 4); s += __shfl_xor(s, 8);
      float mean = s * (1.f / 128.f);
      float vv = 0.f;
#pragma unroll
      for (int cc = 0; cc < 8; cc++) { float d = t[cc] - mean; vv += d * d; }
      vv += __shfl_xor(vv, 1); vv += __shfl_xor(vv, 2);
      vv += __shfl_xor(vv, 4); vv += __shfl_xor(vv, 8);
      float inv = rsqrtf(vv * (1.f / 128.f) + 1e-5f);
#pragma unroll
      for (int cc = 0; cc < 8; cc++)
        Y[lrow * LSTR + cc * 16 + l16] =
            f2bf((t[cc] - mean) * inv * g2v[cc] + b2v[cc]);
    }
  }
  // vector-store x2 (Y) -> xb
  if (wr) {
#pragma unroll
    for (int kb = 0; kb < 4; kb++)
      *(bf16x8*)&xb[(size_t)(rbase + wrow + l16) * 128 + kb * 32 + quad * 8] =
          *(bf16x8*)&Y[lrow_v + kb * 32];
  }

  // ---- QKV next (A from Y, out staged via XR) ----
  if (!LAST) {
    bf16x8 avQ[4];
#pragma unroll
    for (int kb = 0; kb < 4; kb++)
      avQ[kb] = *(bf16x8*)&Y[lrow_v + kb * 32];
#pragma unroll
    for (int c = 0; c < 3; c++) {
      floatx4 accQ[8];
#pragma unroll
      for (int ct = 0; ct < 8; ct++) accQ[ct] = (floatx4)(0.f);
#pragma unroll
      for (int kb = 0; kb < 4; kb++) {
        int kq = kb * 4 + quad;
        bf16x8 bh[8];
#pragma unroll
        for (int ct = 0; ct < 8; ct++)
          bh[ct] = *(const bf16x8*)&wqkv[(size_t)(kq * 384 + c * 128 + ct * 16 + l16) * 8];
#pragma unroll
        for (int ct = 0; ct < 8; ct++)
          accQ[ct] = __builtin_amdgcn_mfma_f32_16x16x32_bf16(avQ[kb], bh[ct], accQ[ct], 0, 0, 0);
      }
      const float* bias = (c == 0) ? bq : (c == 1) ? bk : bv;
#pragma unroll
      for (int ct = 0; ct < 8; ct++) {
        float bvv = bias[ct * 16 + l16];
#pragma unroll
        for (int i = 0; i < 4; i++)
          XR[(wrow + quad * 4 + i) * LSTR + ct * 16 + l16] = f2bf(accQ[ct][i] + bvv);
      }
      if (wr) {
#pragma unroll
        for (int kb = 0; kb < 4; kb++)
          *(bf16x8*)&qkv[(size_t)(rbase + wrow + l16) * 384 + c * 128 + kb * 32 + quad * 8] =
              *(bf16x8*)&XR[lrow_v + kb * 32];
      }
    }
  }
}
#undef LSTR

// ---------------- fused edge attention: one wave per dst node, x8 unroll ----------------
#define ATTN_C  0.36067376022f
#define ATTN_L  7.21347520444f
__device__ __forceinline__ float edge_score(float p) {
  float t = fminf(fmaxf(p * ATTN_C, -ATTN_L), ATTN_L);
  return __builtin_amdgcn_exp2f(t);
}
__global__ __launch_bounds__(256) void attn_kernel(
    const unsigned short* __restrict__ qkv,
    const int* __restrict__ offsets, const int* __restrict__ csr,
    unsigned short* __restrict__ attn)
{
  int node = blockIdx.x * 4 + (threadIdx.x >> 6);
  int lane = threadIdx.x & 63;
  if (node >= N_NODES) return;
  float2 q2 = bf2f2(*(const unsigned int*)(qkv + (size_t)node * 384 + lane * 2));
  const unsigned short* kbase = qkv + 128 + lane * 2;
  float wx = 0.f, wy = 0.f, z = 0.f;
  int j = offsets[node], end = offsets[node + 1];
  for (; j + 8 <= end; j += 8) {
    int s[8];
#pragma unroll
    for (int u = 0; u < 8; u++) s[u] = csr[j + u];
    unsigned int ku[8], vu[8];
#pragma unroll
    for (int u = 0; u < 8; u++) {
      const unsigned short* r = kbase + (size_t)s[u] * 384;
      ku[u] = *(const unsigned int*)r;
      vu[u] = *(const unsigned int*)(r + 128);
    }
    float p[8];
#pragma unroll
    for (int u = 0; u < 8; u++) {
      float2 k2 = bf2f2(ku[u]);
      p[u] = k2.x * q2.x + k2.y * q2.y;
    }
#pragma unroll
    for (int u = 0; u < 8; u++) p[u] += __shfl_xor(p[u], 1);
#pragma unroll
    for (int u = 0; u < 8; u++) p[u] += __shfl_xor(p[u], 2);
#pragma unroll
    for (int u = 0; u < 8; u++) p[u] += __shfl_xor(p[u], 4);
#pragma unroll
    for (int u = 0; u < 8; u++) {
      float sc = edge_score(p[u]);
      float2 v2 = bf2f2(vu[u]);
      wx = fmaf(sc, v2.x, wx);
      wy = fmaf(sc, v2.y, wy);
      z += sc;
    }
  }
  for (; j < end; ++j) {
    int s = csr[j];
    const unsigned short* r = kbase + (size_t)s * 384;
    float2 k2 = bf2f2(*(const unsigned int*)r);
    float p = k2.x * q2.x + k2.y * q2.y;
    p += __shfl_xor(p, 1); p += __shfl_xor(p, 2); p += __shfl_xor(p, 4);
    float sc = edge_score(p);
    float2 v2 = bf2f2(*(const unsigned int*)(r + 128));
    wx = fmaf(sc, v2.x, wx); wy = fmaf(sc, v2.y, wy);
    z += sc;
  }
  float inv = 1.f / (z + 1e-6f);
  unsigned int pack = (unsigned int)f2bf(wx * inv) | ((unsigned int)f2bf(wy * inv) << 16);
  *(unsigned int*)(attn + (size_t)node * DIM + lane * 2) = pack;
}

// ---------------- column mean over nodes (bf16 in, fp32 acc) ----------------
__global__ __launch_bounds__(256) void colmean_kernel(
    const unsigned short* __restrict__ xb, float* __restrict__ mean)
{
  int col = threadIdx.x & 127;
  int half = threadIdx.x >> 7;
  float acc = 0.f;
  for (int r = blockIdx.x * 2 + half; r < N_NODES; r += gridDim.x * 2)
    acc += bf2f(xb[(size_t)r * DIM + col]);
  __shared__ float s[256];
  s[threadIdx.x] = acc;
  __syncthreads();
  if (threadIdx.x < 128) atomicAdd(&mean[col], s[threadIdx.x] + s[threadIdx.x + 128]);
}

// ---------------- readout MLP 128->64->32->10 ----------------
__global__ void readout_kernel(
    const float* __restrict__ mean,
    const float* __restrict__ mW0, const float* __restrict__ mb0,
    const float* __restrict__ mW1, const float* __restrict__ mb1,
    const float* __restrict__ mW2, const float* __restrict__ mb2,
    float* __restrict__ out)
{
  __shared__ float sx[128], h0[64], h1[32];
  int t = threadIdx.x;
  sx[t] = mean[t] * (1.f / (float)N_NODES);
  __syncthreads();
  if (t < 64) {
    float a = mb0[t];
    for (int i = 0; i < 128; i++) a = fmaf(sx[i], mW0[i * 64 + t], a);
    h0[t] = fmaxf(a, 0.f);
  }
  __syncthreads();
  if (t < 32) {
    float a = mb1[t];
    for (int i = 0; i < 64; i++) a = fmaf(h0[i], mW1[i * 32 + t], a);
    h1[t] = fmaxf(a, 0.f);
  }
  __syncthreads();
  if (t < 10) {
    float a = mb2[t];
    for (int i = 0; i < 32; i++) a = fmaf(h1[i], mW2[i * 10 + t], a);
    out[t] = a;
  }
}

extern "C" void kernel_launch(void* const* d_in, const int* in_sizes, int n_in,
                              void* d_out, int out_size, void* d_ws, size_t ws_size,
                              hipStream_t stream) {
  const int*   x_idx = (const int*)d_in[0];
  const int*   eidx  = (const int*)d_in[1];
  const float* emb   = (const float*)d_in[2];
  const float* Wq = (const float*)d_in[3];  const float* bq = (const float*)d_in[4];
  const float* Wk = (const float*)d_in[5];  const float* bk = (const float*)d_in[6];
  const float* Wv = (const float*)d_in[7];  const float* bv = (const float*)d_in[8];
  const float* Wo = (const float*)d_in[9];  const float* bo = (const float*)d_in[10];
  const float* g1 = (const float*)d_in[11]; const float* be1 = (const float*)d_in[12];
  const float* Wf1 = (const float*)d_in[13]; const float* bf1 = (const float*)d_in[14];
  const float* Wf2 = (const float*)d_in[15]; const float* bf2 = (const float*)d_in[16];
  const float* g2 = (const float*)d_in[17]; const float* be2 = (const float*)d_in[18];
  const float* mW0 = (const float*)d_in[19]; const float* mb0 = (const float*)d_in[20];
  const float* mW1 = (const float*)d_in[21]; const float* mb1 = (const float*)d_in[22];
  const float* mW2 = (const float*)d_in[23]; const float* mb2 = (const float*)d_in[24];
  float* out = (float*)d_out;

  const size_t NX = (size_t)N_NODES * DIM;
  unsigned short* xb  = (unsigned short*)d_ws;
  unsigned short* qkv = xb + NX;
  unsigned short* a   = qkv + (size_t)N_NODES * 384;
  unsigned short* xr  = a + NX;
  unsigned short* ffh = xr + NX;

  unsigned short* wqkv_p = ffh + (size_t)N_NODES * 256;   // 3*128*384
  unsigned short* wo_p   = wqkv_p + 3 * 128 * 384;        // 3*128*128
  unsigned short* wf1_p  = wo_p   + 3 * 128 * 128;        // 3*128*256
  unsigned short* wf2_p  = wf1_p  + 3 * 128 * 256;        // 3*256*128
  unsigned short* wend   = wf2_p  + 3 * 256 * 128;

  int* counts  = (int*)wend;
  int* fill    = counts + N_NODES;
  float* meanb = (float*)(fill + N_NODES);
  int* offsets = (int*)(meanb + DIM);
  int* bsums   = offsets + N_NODES + 1;
  int* csr     = bsums + 256;

  const int* e0 = eidx;
  const int* e1 = eidx + N_EDGES;

  hipMemsetAsync(counts, 0, (2 * N_NODES + DIM) * sizeof(int), stream);

  prep_all<<<192, 256, 0, stream>>>(Wq, Wk, Wv, Wo, Wf1, Wf2,
                                    wqkv_p, wo_p, wf1_p, wf2_p);

  embed_kernel<<<(N_NODES * 32 + 255) / 256, 256, 0, stream>>>(x_idx, emb, xb);
  hist_kernel<<<(N_EDGES + 255) / 256, 256, 0, stream>>>(e1, counts);
  int nblk = (N_NODES + 255) / 256;
  scan_local<<<nblk, 256, 0, stream>>>(counts, offsets, bsums);
  scan_bsums<<<1, 256, 0, stream>>>(bsums, nblk);
  scan_add<<<nblk, 256, 0, stream>>>(offsets, bsums);
  scatter_kernel<<<(N_EDGES + 255) / 256, 256, 0, stream>>>(e0, e1, offsets, fill, csr);

  int gx = (N_NODES + 127) / 128;
  int gc = (N_NODES + 63) / 64;
  int nb4 = (N_NODES + 3) / 4;

  mfma_gemm_qkv<<<dim3(gx, 3), 256, 0, stream>>>(xb, wqkv_p, bq, bk, bv, qkv, N_NODES);

  for (int l = 0; l < NLAYERS; ++l) {
    const unsigned short* wo_l   = wo_p   + (size_t)l * 128 * 128;
    const unsigned short* wf1_l  = wf1_p  + (size_t)l * 128 * 256;
    const unsigned short* wf2_l  = wf2_p  + (size_t)l * 256 * 128;
    const unsigned short* wqkv_n = wqkv_p + (size_t)(l + 1) * 128 * 384;
    const float* bo_l  = bo  + (size_t)l * DIM;
    const float* g1_l  = g1  + (size_t)l * DIM;
    const float* be1_l = be1 + (size_t)l * DIM;
    const float* bf1_l = bf1 + (size_t)l * 2 * DIM;
    const float* bf2_l = bf2 + (size_t)l * DIM;
    const float* g2_l  = g2  + (size_t)l * DIM;
    const float* be2_l = be2 + (size_t)l * DIM;

    attn_kernel<<<nb4, 256, 0, stream>>>(qkv, offsets, csr, a);
    chain1_kernel<<<gc, 256, 0, stream>>>(
        a, xb, xr, ffh, wo_l, bo_l, g1_l, be1_l, wf1_l, bf1_l, N_NODES);
    if (l < NLAYERS - 1) {
      chain2_kernel<false><<<gc, 256, 0, stream>>>(
          ffh, xr, xb, qkv, wf2_l, bf2_l, g2_l, be2_l, wqkv_n,
          bq + (size_t)(l + 1) * DIM, bk + (size_t)(l + 1) * DIM,
          bv + (size_t)(l + 1) * DIM, N_NODES);
    } else {
      chain2_kernel<true><<<gc, 256, 0, stream>>>(
          ffh, xr, xb, qkv, wf2_l, bf2_l, g2_l, be2_l, wqkv_p,
          bq, bk, bv, N_NODES);
    }
  }

  colmean_kernel<<<128, 256, 0, stream>>>(xb, meanb);
  readout_kernel<<<1, 128, 0, stream>>>(meanb, mW0, mb0, mW1, mb1, mW2, mb2, out);
}

// Round 12
// 589.996 us; speedup vs baseline: 1.2042x; 1.0831x over previous
//
#include <hip/hip_runtime.h>
#include <hip/hip_bf16.h>

#define N_NODES 50000
#define N_EDGES 800000
#define DIM 128
#define NLAYERS 3

typedef short bf16x8 __attribute__((ext_vector_type(8)));
typedef float floatx4 __attribute__((ext_vector_type(4)));
typedef float floatx2 __attribute__((ext_vector_type(2)));

__device__ __forceinline__ unsigned short f2bf(float f) {
  unsigned int u = __builtin_bit_cast(unsigned int, f);
  return (unsigned short)((u + 0x7FFFu + ((u >> 16) & 1u)) >> 16);
}
__device__ __forceinline__ float bf2f(unsigned short h) {
  return __builtin_bit_cast(float, (unsigned int)h << 16);
}
__device__ __forceinline__ float2 bf2f2(unsigned int u) {
  float lo = __builtin_bit_cast(float, u << 16);
  float hi = __builtin_bit_cast(float, u & 0xFFFF0000u);
  return make_float2(lo, hi);
}

// ---------------- embedding gather -> bf16 residual ----------------
__global__ __launch_bounds__(256) void embed_kernel(
    const int* __restrict__ idx, const float* __restrict__ emb,
    unsigned short* __restrict__ xb)
{
  int gid = blockIdx.x * 256 + threadIdx.x;
  int n = gid >> 5;
  int c = (gid & 31) << 2;
  if (n >= N_NODES) return;
  int e = idx[n];
  float4 val = *(const float4*)(emb + (size_t)e * DIM + c);
  ushort4 pk;
  pk.x = f2bf(val.x); pk.y = f2bf(val.y); pk.z = f2bf(val.z); pk.w = f2bf(val.w);
  *(ushort4*)(xb + (size_t)n * DIM + c) = pk;
}

// ---------------- CSR build ----------------
__global__ __launch_bounds__(256) void hist_kernel(
    const int* __restrict__ e1, int* __restrict__ counts)
{
  int i = blockIdx.x * 256 + threadIdx.x;
  if (i < N_EDGES) atomicAdd(&counts[e1[i]], 1);
}

__global__ __launch_bounds__(256) void scan_local(
    const int* __restrict__ counts, int* __restrict__ offsets,
    int* __restrict__ bsums)
{
  __shared__ int buf[256];
  int t = threadIdx.x;
  int i = blockIdx.x * 256 + t;
  int v = (i < N_NODES) ? counts[i] : 0;
  buf[t] = v;
  __syncthreads();
  int s = v;
#pragma unroll
  for (int off = 1; off < 256; off <<= 1) {
    int t2 = (t >= off) ? buf[t - off] : 0;
    __syncthreads();
    s += t2;
    buf[t] = s;
    __syncthreads();
  }
  if (i < N_NODES) offsets[i] = s - v;
  if (t == 255) bsums[blockIdx.x] = s;
}

__global__ void scan_bsums(int* __restrict__ bsums, int nblk)
{
  __shared__ int buf[256];
  int t = threadIdx.x;
  int v = (t < nblk) ? bsums[t] : 0;
  buf[t] = v;
  __syncthreads();
  int s = v;
#pragma unroll
  for (int off = 1; off < 256; off <<= 1) {
    int t2 = (t >= off) ? buf[t - off] : 0;
    __syncthreads();
    s += t2;
    buf[t] = s;
    __syncthreads();
  }
  if (t < nblk) bsums[t] = s - v;
}

__global__ __launch_bounds__(256) void scan_add(
    int* __restrict__ offsets, const int* __restrict__ bsums)
{
  int i = blockIdx.x * 256 + threadIdx.x;
  if (i < N_NODES) offsets[i] += bsums[blockIdx.x];
  if (i == 0) offsets[N_NODES] = N_EDGES;
}

__global__ __launch_bounds__(256) void scatter_kernel(
    const int* __restrict__ e0, const int* __restrict__ e1,
    const int* __restrict__ offsets, int* __restrict__ fill,
    int* __restrict__ csr)
{
  int i = blockIdx.x * 256 + threadIdx.x;
  if (i >= N_EDGES) return;
  int d = e1[i];
  int pos = offsets[d] + atomicAdd(&fill[d], 1);
  csr[pos] = e0[i];
}

// ---------------- combined weight prep (single-plane bf16, frag-major) ----------------
__global__ __launch_bounds__(256) void prep_all(
    const float* __restrict__ Wq, const float* __restrict__ Wk,
    const float* __restrict__ Wv, const float* __restrict__ Wo,
    const float* __restrict__ Wf1, const float* __restrict__ Wf2,
    unsigned short* __restrict__ wqkv, unsigned short* __restrict__ wo,
    unsigned short* __restrict__ wf1, unsigned short* __restrict__ wf2)
{
  int g = blockIdx.x * 256 + threadIdx.x;
  if (g < 18432) {
    int srcId = g / 6144; int rem = g - srcId * 6144;
    const float* W = (srcId == 0) ? Wq : (srcId == 1) ? Wk : Wv;
    int l = rem / 2048; int r2 = rem & 2047; int kq = r2 >> 7; int n = r2 & 127;
    const float* Wl = W + (size_t)l * 128 * 128;
    unsigned short* base = wqkv + (size_t)l * 128 * 384 + (size_t)(kq * 384 + srcId * 128 + n) * 8;
#pragma unroll
    for (int j = 0; j < 8; j++)
      base[j] = f2bf(Wl[(size_t)(kq * 8 + j) * 128 + n]);
    return;
  }
  g -= 18432;
  if (g < 6144) {
    int l = g / 2048; int r2 = g & 2047; int kq = r2 >> 7; int n = r2 & 127;
    const float* Wl = Wo + (size_t)l * 128 * 128;
    unsigned short* base = wo + (size_t)l * 128 * 128 + (size_t)(kq * 128 + n) * 8;
#pragma unroll
    for (int j = 0; j < 8; j++)
      base[j] = f2bf(Wl[(size_t)(kq * 8 + j) * 128 + n]);
    return;
  }
  g -= 6144;
  if (g < 12288) {
    int l = g / 4096; int r2 = g & 4095; int kq = r2 >> 8; int n = r2 & 255;
    const float* Wl = Wf1 + (size_t)l * 128 * 256;
    unsigned short* base = wf1 + (size_t)l * 128 * 256 + (size_t)(kq * 256 + n) * 8;
#pragma unroll
    for (int j = 0; j < 8; j++)
      base[j] = f2bf(Wl[(size_t)(kq * 8 + j) * 256 + n]);
    return;
  }
  g -= 12288;
  if (g < 12288) {
    int l = g / 4096; int r2 = g & 4095; int kq = r2 >> 7; int n = r2 & 127;
    const float* Wl = Wf2 + (size_t)l * 256 * 128;
    unsigned short* base = wf2 + (size_t)l * 256 * 128 + (size_t)(kq * 128 + n) * 8;
#pragma unroll
    for (int j = 0; j < 8; j++)
      base[j] = f2bf(Wl[(size_t)(kq * 8 + j) * 128 + n]);
  }
}

// ---------------- QKV GEMM (layer 0): q bf16, k/v fp8x8 into [N,256] layout ----------------
// qkv row (256 ushorts): q bf16 [0,128) | k fp8 pairs [128,192) | v fp8 pairs [192,256)
__global__ __launch_bounds__(256) void mfma_gemm_qkv(
    const unsigned short* __restrict__ Ab,
    const unsigned short* __restrict__ Wp,
    const float* __restrict__ bq, const float* __restrict__ bk,
    const float* __restrict__ bv,
    unsigned short* __restrict__ out, int nrows)
{
  constexpr int K = 128, N = 384, CT = 8;
  __shared__ unsigned short SW[16 * 128 * 8];   // 32 KB
  int tid = threadIdx.x;
  int cQ = blockIdx.y;          // 0=q, 1=k, 2=v
  int c0 = cQ * 128;
  const float* bias = (cQ == 0) ? bq : (cQ == 1) ? bk : bv;
  int wave = tid >> 6, lane = tid & 63;
  int quad = lane >> 4, l16 = lane & 15;
  int row0 = blockIdx.x * 128 + wave * 32;

  floatx4 acc[2][CT];
#pragma unroll
  for (int rt = 0; rt < 2; rt++)
#pragma unroll
    for (int ct = 0; ct < CT; ct++) acc[rt][ct] = (floatx4)(0.f);

  const unsigned short* arow[2];
#pragma unroll
  for (int rt = 0; rt < 2; rt++) {
    int r = min(row0 + rt * 16 + l16, nrows - 1);
    arow[rt] = Ab + (size_t)r * K + quad * 8;
  }
#pragma unroll 4
  for (int f = tid; f < 16 * 128; f += 256) {
    int kq = f >> 7;
    int n = f & 127;
    *(bf16x8*)&SW[f * 8] = *(const bf16x8*)&Wp[(size_t)(kq * N + c0 + n) * 8];
  }
  __syncthreads();
#pragma unroll
  for (int kb = 0; kb < 4; ++kb) {
    bf16x8 av[2];
#pragma unroll
    for (int rt = 0; rt < 2; rt++)
      av[rt] = *(const bf16x8*)(arow[rt] + kb * 32);
#pragma unroll
    for (int ct = 0; ct < CT; ct++) {
      bf16x8 bh = *(bf16x8*)&SW[((kb * 4 + quad) * 128 + ct * 16 + l16) * 8];
#pragma unroll
      for (int rt = 0; rt < 2; rt++)
        acc[rt][ct] = __builtin_amdgcn_mfma_f32_16x16x32_bf16(av[rt], bh, acc[rt][ct], 0, 0, 0);
    }
  }
#pragma unroll
  for (int ct = 0; ct < CT; ct++) {
    float bvv = bias[ct * 16 + l16];
#pragma unroll
    for (int rt = 0; rt < 2; rt++)
#pragma unroll
      for (int i = 0; i < 4; i++) {
        int r = row0 + rt * 16 + quad * 4 + i;
        float o = acc[rt][ct][i] + bvv;
        if (cQ == 0) {
          if (r < nrows)
            out[(size_t)r * 256 + ct * 16 + l16] = f2bf(o);
        } else {
          float o8 = o * 8.f;
          float nb = __shfl_xor(o8, 1);     // neighbor column (same row/quad)
          if (!(l16 & 1) && r < nrows) {
            int pk = __builtin_amdgcn_cvt_pk_fp8_f32(o8, nb, 0, false);
            out[(size_t)r * 256 + 128 + (cQ - 1) * 64 + ct * 8 + (l16 >> 1)] =
                (unsigned short)(pk & 0xffff);
          }
        }
      }
  }
}

// ================ chain1: O-GEMM + LN1 + FFN1 (4 waves x 16 rows) ================
#define LSTR 136
__global__ __launch_bounds__(256) void chain1_kernel(
    const unsigned short* __restrict__ a,
    const unsigned short* __restrict__ xb,
    unsigned short* __restrict__ xr,
    unsigned short* __restrict__ ffh,
    const unsigned short* __restrict__ wo, const float* __restrict__ bo,
    const float* __restrict__ g1, const float* __restrict__ be1,
    const unsigned short* __restrict__ wf1, const float* __restrict__ bf1,
    int nrows)
{
  __shared__ unsigned short Y[64 * LSTR];
  __shared__ unsigned short F[64 * LSTR];
  int tid = threadIdx.x;
  int wave = tid >> 6, lane = tid & 63;
  int quad = lane >> 4, l16 = lane & 15;
  int rbase = blockIdx.x * 64;
  int wrow = wave * 16;
  int rowg = min(rbase + wrow + l16, nrows - 1);
  int lrow_v = (wrow + l16) * LSTR + quad * 8;

#pragma unroll
  for (int kb = 0; kb < 4; kb++)
    *(bf16x8*)&F[lrow_v + kb * 32] =
        *(const bf16x8*)&xb[(size_t)rowg * 128 + kb * 32 + quad * 8];

  floatx4 accO[8];
#pragma unroll
  for (int cc = 0; cc < 8; cc++) accO[cc] = (floatx4)(0.f);
  {
    const unsigned short* arow = a + (size_t)rowg * 128 + quad * 8;
#pragma unroll
    for (int kb = 0; kb < 4; kb++) {
      bf16x8 av = *(const bf16x8*)(arow + kb * 32);
      int kq = kb * 4 + quad;
      bf16x8 bh[8];
#pragma unroll
      for (int cc = 0; cc < 8; cc++)
        bh[cc] = *(const bf16x8*)&wo[(size_t)(kq * 128 + cc * 16 + l16) * 8];
#pragma unroll
      for (int cc = 0; cc < 8; cc++)
        accO[cc] = __builtin_amdgcn_mfma_f32_16x16x32_bf16(av, bh[cc], accO[cc], 0, 0, 0);
    }
  }

  {
    float biasO[8], g1v[8], b1v[8];
#pragma unroll
    for (int cc = 0; cc < 8; cc++) {
      int col = cc * 16 + l16;
      biasO[cc] = bo[col]; g1v[cc] = g1[col]; b1v[cc] = be1[col];
    }
#pragma unroll
    for (int i = 0; i < 4; i++) {
      int lrow = wrow + quad * 4 + i;
      float t[8]; float s = 0.f;
#pragma unroll
      for (int cc = 0; cc < 8; cc++) {
        float yv = accO[cc][i] + biasO[cc];
        Y[lrow * LSTR + cc * 16 + l16] = f2bf(yv);
        t[cc] = yv + bf2f(F[lrow * LSTR + cc * 16 + l16]);
        s += t[cc];
      }
      s += __shfl_xor(s, 1); s += __shfl_xor(s, 2);
      s += __shfl_xor(s, 4); s += __shfl_xor(s, 8);
      float mean = s * (1.f / 128.f);
      float vv = 0.f;
#pragma unroll
      for (int cc = 0; cc < 8; cc++) { float d = t[cc] - mean; vv += d * d; }
      vv += __shfl_xor(vv, 1); vv += __shfl_xor(vv, 2);
      vv += __shfl_xor(vv, 4); vv += __shfl_xor(vv, 8);
      float inv = rsqrtf(vv * (1.f / 128.f) + 1e-5f);
#pragma unroll
      for (int cc = 0; cc < 8; cc++)
        F[lrow * LSTR + cc * 16 + l16] =
            f2bf((t[cc] - mean) * inv * g1v[cc] + b1v[cc]);
    }
  }
  if (rbase + wrow + l16 < nrows) {
#pragma unroll
    for (int kb = 0; kb < 4; kb++)
      *(bf16x8*)&xr[(size_t)(rbase + wrow + l16) * 128 + kb * 32 + quad * 8] =
          *(bf16x8*)&F[lrow_v + kb * 32];
  }

  bf16x8 avY[4];
#pragma unroll
  for (int kb = 0; kb < 4; kb++)
    avY[kb] = *(bf16x8*)&Y[lrow_v + kb * 32];
#pragma unroll
  for (int h = 0; h < 2; h++) {
    floatx4 accF[8];
#pragma unroll
    for (int cc = 0; cc < 8; cc++) accF[cc] = (floatx4)(0.f);
#pragma unroll
    for (int kb = 0; kb < 4; kb++) {
      int kq = kb * 4 + quad;
      bf16x8 bh[8];
#pragma unroll
      for (int cc = 0; cc < 8; cc++)
        bh[cc] = *(const bf16x8*)&wf1[(size_t)(kq * 256 + h * 128 + cc * 16 + l16) * 8];
#pragma unroll
      for (int cc = 0; cc < 8; cc++)
        accF[cc] = __builtin_amdgcn_mfma_f32_16x16x32_bf16(avY[kb], bh[cc], accF[cc], 0, 0, 0);
    }
#pragma unroll
    for (int i = 0; i < 4; i++) {
      int lrow = wrow + quad * 4 + i;
#pragma unroll
      for (int cc = 0; cc < 8; cc++)
        F[lrow * LSTR + cc * 16 + l16] =
            f2bf(fmaxf(accF[cc][i] + bf1[h * 128 + cc * 16 + l16], 0.f));
    }
    if (rbase + wrow + l16 < nrows) {
#pragma unroll
      for (int kb = 0; kb < 4; kb++)
        *(bf16x8*)&ffh[(size_t)(rbase + wrow + l16) * 256 + h * 128 + kb * 32 + quad * 8] =
            *(bf16x8*)&F[lrow_v + kb * 32];
    }
  }
}

// ================ chain2: FFN2 + LN2 + QKV(next, q bf16 + k/v fp8) ================
template<bool LAST>
__global__ __launch_bounds__(256) void chain2_kernel(
    const unsigned short* __restrict__ ffh,
    const unsigned short* __restrict__ xr,
    unsigned short* __restrict__ xb,
    unsigned short* __restrict__ qkv,
    const unsigned short* __restrict__ wf2, const float* __restrict__ bf2,
    const float* __restrict__ g2, const float* __restrict__ be2,
    const unsigned short* __restrict__ wqkv,
    const float* __restrict__ bq, const float* __restrict__ bk,
    const float* __restrict__ bv, int nrows)
{
  __shared__ unsigned short Y[64 * LSTR];
  __shared__ unsigned short XR[64 * LSTR];
  int tid = threadIdx.x;
  int wave = tid >> 6, lane = tid & 63;
  int quad = lane >> 4, l16 = lane & 15;
  int rbase = blockIdx.x * 64;
  int wrow = wave * 16;
  int rowg = min(rbase + wrow + l16, nrows - 1);
  int lrow_v = (wrow + l16) * LSTR + quad * 8;
  bool wr = (rbase + wrow + l16 < nrows);

#pragma unroll
  for (int kb = 0; kb < 4; kb++)
    *(bf16x8*)&XR[lrow_v + kb * 32] =
        *(const bf16x8*)&xr[(size_t)rowg * 128 + kb * 32 + quad * 8];

  floatx4 acc2[8];
#pragma unroll
  for (int cc = 0; cc < 8; cc++) acc2[cc] = (floatx4)(0.f);
  {
    const unsigned short* arow = ffh + (size_t)rowg * 256 + quad * 8;
#pragma unroll
    for (int h = 0; h < 2; h++) {
#pragma unroll
      for (int kb = 0; kb < 4; kb++) {
        bf16x8 av = *(const bf16x8*)(arow + h * 128 + kb * 32);
        int kq = h * 16 + kb * 4 + quad;
        bf16x8 bh[8];
#pragma unroll
        for (int cc = 0; cc < 8; cc++)
          bh[cc] = *(const bf16x8*)&wf2[(size_t)(kq * 128 + cc * 16 + l16) * 8];
#pragma unroll
        for (int cc = 0; cc < 8; cc++)
          acc2[cc] = __builtin_amdgcn_mfma_f32_16x16x32_bf16(av, bh[cc], acc2[cc], 0, 0, 0);
      }
    }
  }

  {
    float bias2[8], g2v[8], b2v[8];
#pragma unroll
    for (int cc = 0; cc < 8; cc++) {
      int col = cc * 16 + l16;
      bias2[cc] = bf2[col]; g2v[cc] = g2[col]; b2v[cc] = be2[col];
    }
#pragma unroll
    for (int i = 0; i < 4; i++) {
      int lrow = wrow + quad * 4 + i;
      float t[8]; float s = 0.f;
#pragma unroll
      for (int cc = 0; cc < 8; cc++) {
        t[cc] = acc2[cc][i] + bias2[cc] + bf2f(XR[lrow * LSTR + cc * 16 + l16]);
        s += t[cc];
      }
      s += __shfl_xor(s, 1); s += __shfl_xor(s, 2);
      s += __shfl_xor(s, 4); s += __shfl_xor(s, 8);
      float mean = s * (1.f / 128.f);
      float vv = 0.f;
#pragma unroll
      for (int cc = 0; cc < 8; cc++) { float d = t[cc] - mean; vv += d * d; }
      vv += __shfl_xor(vv, 1); vv += __shfl_xor(vv, 2);
      vv += __shfl_xor(vv, 4); vv += __shfl_xor(vv, 8);
      float inv = rsqrtf(vv * (1.f / 128.f) + 1e-5f);
#pragma unroll
      for (int cc = 0; cc < 8; cc++)
        Y[lrow * LSTR + cc * 16 + l16] =
            f2bf((t[cc] - mean) * inv * g2v[cc] + b2v[cc]);
    }
  }
  if (wr) {
#pragma unroll
    for (int kb = 0; kb < 4; kb++)
      *(bf16x8*)&xb[(size_t)(rbase + wrow + l16) * 128 + kb * 32 + quad * 8] =
          *(bf16x8*)&Y[lrow_v + kb * 32];
  }

  if (!LAST) {
    bf16x8 avQ[4];
#pragma unroll
    for (int kb = 0; kb < 4; kb++)
      avQ[kb] = *(bf16x8*)&Y[lrow_v + kb * 32];
#pragma unroll
    for (int c = 0; c < 3; c++) {
      floatx4 accQ[8];
#pragma unroll
      for (int ct = 0; ct < 8; ct++) accQ[ct] = (floatx4)(0.f);
#pragma unroll
      for (int kb = 0; kb < 4; kb++) {
        int kq = kb * 4 + quad;
        bf16x8 bh[8];
#pragma unroll
        for (int ct = 0; ct < 8; ct++)
          bh[ct] = *(const bf16x8*)&wqkv[(size_t)(kq * 384 + c * 128 + ct * 16 + l16) * 8];
#pragma unroll
        for (int ct = 0; ct < 8; ct++)
          accQ[ct] = __builtin_amdgcn_mfma_f32_16x16x32_bf16(avQ[kb], bh[ct], accQ[ct], 0, 0, 0);
      }
      const float* bias = (c == 0) ? bq : (c == 1) ? bk : bv;
#pragma unroll
      for (int ct = 0; ct < 8; ct++) {
        float bvv = bias[ct * 16 + l16];
#pragma unroll
        for (int i = 0; i < 4; i++)
          XR[(wrow + quad * 4 + i) * LSTR + ct * 16 + l16] = f2bf(accQ[ct][i] + bvv);
      }
      if (wr) {
        if (c == 0) {
#pragma unroll
          for (int kb = 0; kb < 4; kb++)
            *(bf16x8*)&qkv[(size_t)(rbase + wrow + l16) * 256 + kb * 32 + quad * 8] =
                *(bf16x8*)&XR[lrow_v + kb * 32];
        } else {
#pragma unroll
          for (int kb = 0; kb < 4; kb++) {
            bf16x8 w = *(bf16x8*)&XR[lrow_v + kb * 32];
            int p0 = __builtin_amdgcn_cvt_pk_fp8_f32(
                bf2f((unsigned short)w[0]) * 8.f, bf2f((unsigned short)w[1]) * 8.f, 0, false);
            int p1 = __builtin_amdgcn_cvt_pk_fp8_f32(
                bf2f((unsigned short)w[2]) * 8.f, bf2f((unsigned short)w[3]) * 8.f, 0, false);
            int p2 = __builtin_amdgcn_cvt_pk_fp8_f32(
                bf2f((unsigned short)w[4]) * 8.f, bf2f((unsigned short)w[5]) * 8.f, 0, false);
            int p3 = __builtin_amdgcn_cvt_pk_fp8_f32(
                bf2f((unsigned short)w[6]) * 8.f, bf2f((unsigned short)w[7]) * 8.f, 0, false);
            int2 st;
            st.x = (p0 & 0xffff) | (p1 << 16);
            st.y = (p2 & 0xffff) | (p3 << 16);
            *(int2*)&qkv[(size_t)(rbase + wrow + l16) * 256 + 128 + (c - 1) * 64 +
                         kb * 16 + quad * 4] = st;
          }
        }
      }
    }
  }
}
#undef LSTR

// ---------------- fused edge attention: fp8 k/v (scale 8), one wave per node, x8 unroll ----------------
// sc = exp(clip((k.q)/4,-5,5)); k,v stored as fp8 of 8*value; p here = 8*(k.q)
#define ATTN_C8 0.04508422003f   // 0.25*log2(e)/8
#define ATTN_L  7.21347520444f
__device__ __forceinline__ float edge_score8(float p) {
  float t = fminf(fmaxf(p * ATTN_C8, -ATTN_L), ATTN_L);
  return __builtin_amdgcn_exp2f(t);
}
__global__ __launch_bounds__(256) void attn_kernel(
    const unsigned short* __restrict__ qkv,
    const int* __restrict__ offsets, const int* __restrict__ csr,
    unsigned short* __restrict__ attn)
{
  int node = blockIdx.x * 4 + (threadIdx.x >> 6);
  int lane = threadIdx.x & 63;
  if (node >= N_NODES) return;
  float2 q2 = bf2f2(*(const unsigned int*)(qkv + (size_t)node * 256 + lane * 2));
  const unsigned short* kb8 = qkv + 128 + lane;   // + row*256
  const unsigned short* vb8 = qkv + 192 + lane;
  float wx = 0.f, wy = 0.f, z = 0.f;
  int j = offsets[node], end = offsets[node + 1];
  for (; j + 8 <= end; j += 8) {
    int s[8];
#pragma unroll
    for (int u = 0; u < 8; u++) s[u] = csr[j + u];
    unsigned short ku[8], vu[8];
#pragma unroll
    for (int u = 0; u < 8; u++) {
      ku[u] = kb8[(size_t)s[u] * 256];
      vu[u] = vb8[(size_t)s[u] * 256];
    }
    float p[8];
#pragma unroll
    for (int u = 0; u < 8; u++) {
      floatx2 kf = __builtin_amdgcn_cvt_pk_f32_fp8((int)ku[u], false);
      p[u] = kf[0] * q2.x + kf[1] * q2.y;
    }
#pragma unroll
    for (int u = 0; u < 8; u++) p[u] += __shfl_xor(p[u], 1);
#pragma unroll
    for (int u = 0; u < 8; u++) p[u] += __shfl_xor(p[u], 2);
#pragma unroll
    for (int u = 0; u < 8; u++) p[u] += __shfl_xor(p[u], 4);
#pragma unroll
    for (int u = 0; u < 8; u++) {
      float sc = edge_score8(p[u]);
      floatx2 vf = __builtin_amdgcn_cvt_pk_f32_fp8((int)vu[u], false);
      wx = fmaf(sc, vf[0], wx);
      wy = fmaf(sc, vf[1], wy);
      z += sc;
    }
  }
  for (; j < end; ++j) {
    int s = csr[j];
    floatx2 kf = __builtin_amdgcn_cvt_pk_f32_fp8((int)kb8[(size_t)s * 256], false);
    float p = kf[0] * q2.x + kf[1] * q2.y;
    p += __shfl_xor(p, 1); p += __shfl_xor(p, 2); p += __shfl_xor(p, 4);
    float sc = edge_score8(p);
    floatx2 vf = __builtin_amdgcn_cvt_pk_f32_fp8((int)vb8[(size_t)s * 256], false);
    wx = fmaf(sc, vf[0], wx); wy = fmaf(sc, vf[1], wy);
    z += sc;
  }
  // out = (wx/8) / (z + 1e-6)  (k,v were scaled by 8; z is unscaled)
  float inv = 1.f / (8.f * z + 8e-6f);
  unsigned int pack = (unsigned int)f2bf(wx * inv) | ((unsigned int)f2bf(wy * inv) << 16);
  *(unsigned int*)(attn + (size_t)node * DIM + lane * 2) = pack;
}

// ---------------- column mean over nodes (bf16 in, fp32 acc) ----------------
__global__ __launch_bounds__(256) void colmean_kernel(
    const unsigned short* __restrict__ xb, float* __restrict__ mean)
{
  int col = threadIdx.x & 127;
  int half = threadIdx.x >> 7;
  float acc = 0.f;
  for (int r = blockIdx.x * 2 + half; r < N_NODES; r += gridDim.x * 2)
    acc += bf2f(xb[(size_t)r * DIM + col]);
  __shared__ float s[256];
  s[threadIdx.x] = acc;
  __syncthreads();
  if (threadIdx.x < 128) atomicAdd(&mean[col], s[threadIdx.x] + s[threadIdx.x + 128]);
}

// ---------------- readout MLP 128->64->32->10 ----------------
__global__ void readout_kernel(
    const float* __restrict__ mean,
    const float* __restrict__ mW0, const float* __restrict__ mb0,
    const float* __restrict__ mW1, const float* __restrict__ mb1,
    const float* __restrict__ mW2, const float* __restrict__ mb2,
    float* __restrict__ out)
{
  __shared__ float sx[128], h0[64], h1[32];
  int t = threadIdx.x;
  sx[t] = mean[t] * (1.f / (float)N_NODES);
  __syncthreads();
  if (t < 64) {
    float a = mb0[t];
    for (int i = 0; i < 128; i++) a = fmaf(sx[i], mW0[i * 64 + t], a);
    h0[t] = fmaxf(a, 0.f);
  }
  __syncthreads();
  if (t < 32) {
    float a = mb1[t];
    for (int i = 0; i < 64; i++) a = fmaf(h0[i], mW1[i * 32 + t], a);
    h1[t] = fmaxf(a, 0.f);
  }
  __syncthreads();
  if (t < 10) {
    float a = mb2[t];
    for (int i = 0; i < 32; i++) a = fmaf(h1[i], mW2[i * 10 + t], a);
    out[t] = a;
  }
}

extern "C" void kernel_launch(void* const* d_in, const int* in_sizes, int n_in,
                              void* d_out, int out_size, void* d_ws, size_t ws_size,
                              hipStream_t stream) {
  const int*   x_idx = (const int*)d_in[0];
  const int*   eidx  = (const int*)d_in[1];
  const float* emb   = (const float*)d_in[2];
  const float* Wq = (const float*)d_in[3];  const float* bq = (const float*)d_in[4];
  const float* Wk = (const float*)d_in[5];  const float* bk = (const float*)d_in[6];
  const float* Wv = (const float*)d_in[7];  const float* bv = (const float*)d_in[8];
  const float* Wo = (const float*)d_in[9];  const float* bo = (const float*)d_in[10];
  const float* g1 = (const float*)d_in[11]; const float* be1 = (const float*)d_in[12];
  const float* Wf1 = (const float*)d_in[13]; const float* bf1 = (const float*)d_in[14];
  const float* Wf2 = (const float*)d_in[15]; const float* bf2 = (const float*)d_in[16];
  const float* g2 = (const float*)d_in[17]; const float* be2 = (const float*)d_in[18];
  const float* mW0 = (const float*)d_in[19]; const float* mb0 = (const float*)d_in[20];
  const float* mW1 = (const float*)d_in[21]; const float* mb1 = (const float*)d_in[22];
  const float* mW2 = (const float*)d_in[23]; const float* mb2 = (const float*)d_in[24];
  float* out = (float*)d_out;

  const size_t NX = (size_t)N_NODES * DIM;
  unsigned short* xb  = (unsigned short*)d_ws;
  unsigned short* qkv = xb + NX;                        // [N,256] q|k8|v8
  unsigned short* a   = qkv + (size_t)N_NODES * 256;
  unsigned short* xr  = a + NX;
  unsigned short* ffh = xr + NX;

  unsigned short* wqkv_p = ffh + (size_t)N_NODES * 256;
  unsigned short* wo_p   = wqkv_p + 3 * 128 * 384;
  unsigned short* wf1_p  = wo_p   + 3 * 128 * 128;
  unsigned short* wf2_p  = wf1_p  + 3 * 128 * 256;
  unsigned short* wend   = wf2_p  + 3 * 256 * 128;

  int* counts  = (int*)wend;
  int* fill    = counts + N_NODES;
  float* meanb = (float*)(fill + N_NODES);
  int* offsets = (int*)(meanb + DIM);
  int* bsums   = offsets + N_NODES + 1;
  int* csr     = bsums + 256;

  const int* e0 = eidx;
  const int* e1 = eidx + N_EDGES;

  hipMemsetAsync(counts, 0, (2 * N_NODES + DIM) * sizeof(int), stream);

  prep_all<<<192, 256, 0, stream>>>(Wq, Wk, Wv, Wo, Wf1, Wf2,
                                    wqkv_p, wo_p, wf1_p, wf2_p);

  embed_kernel<<<(N_NODES * 32 + 255) / 256, 256, 0, stream>>>(x_idx, emb, xb);
  hist_kernel<<<(N_EDGES + 255) / 256, 256, 0, stream>>>(e1, counts);
  int nblk = (N_NODES + 255) / 256;
  scan_local<<<nblk, 256, 0, stream>>>(counts, offsets, bsums);
  scan_bsums<<<1, 256, 0, stream>>>(bsums, nblk);
  scan_add<<<nblk, 256, 0, stream>>>(offsets, bsums);
  scatter_kernel<<<(N_EDGES + 255) / 256, 256, 0, stream>>>(e0, e1, offsets, fill, csr);

  int gx = (N_NODES + 127) / 128;
  int gc = (N_NODES + 63) / 64;
  int nb4 = (N_NODES + 3) / 4;

  mfma_gemm_qkv<<<dim3(gx, 3), 256, 0, stream>>>(xb, wqkv_p, bq, bk, bv, qkv, N_NODES);

  for (int l = 0; l < NLAYERS; ++l) {
    const unsigned short* wo_l   = wo_p   + (size_t)l * 128 * 128;
    const unsigned short* wf1_l  = wf1_p  + (size_t)l * 128 * 256;
    const unsigned short* wf2_l  = wf2_p  + (size_t)l * 256 * 128;
    const unsigned short* wqkv_n = wqkv_p + (size_t)(l + 1) * 128 * 384;
    const float* bo_l  = bo  + (size_t)l * DIM;
    const float* g1_l  = g1  + (size_t)l * DIM;
    const float* be1_l = be1 + (size_t)l * DIM;
    const float* bf1_l = bf1 + (size_t)l * 2 * DIM;
    const float* bf2_l = bf2 + (size_t)l * DIM;
    const float* g2_l  = g2  + (size_t)l * DIM;
    const float* be2_l = be2 + (size_t)l * DIM;

    attn_kernel<<<nb4, 256, 0, stream>>>(qkv, offsets, csr, a);
    chain1_kernel<<<gc, 256, 0, stream>>>(
        a, xb, xr, ffh, wo_l, bo_l, g1_l, be1_l, wf1_l, bf1_l, N_NODES);
    if (l < NLAYERS - 1) {
      chain2_kernel<false><<<gc, 256, 0, stream>>>(
          ffh, xr, xb, qkv, wf2_l, bf2_l, g2_l, be2_l, wqkv_n,
          bq + (size_t)(l + 1) * DIM, bk + (size_t)(l + 1) * DIM,
          bv + (size_t)(l + 1) * DIM, N_NODES);
    } else {
      chain2_kernel<true><<<gc, 256, 0, stream>>>(
          ffh, xr, xb, qkv, wf2_l, bf2_l, g2_l, be2_l, wqkv_p,
          bq, bk, bv, N_NODES);
    }
  }

  colmean_kernel<<<128, 256, 0, stream>>>(xb, meanb);
  readout_kernel<<<1, 128, 0, stream>>>(meanb, mW0, mb0, mW1, mb1, mW2, mb2, out);
}

// Round 13
// 567.108 us; speedup vs baseline: 1.2528x; 1.0404x over previous
//
#include <hip/hip_runtime.h>
#include <hip/hip_bf16.h>

#define N_NODES 50000
#define N_EDGES 800000
#define DIM 128
#define NLAYERS 3

typedef short bf16x8 __attribute__((ext_vector_type(8)));
typedef float floatx4 __attribute__((ext_vector_type(4)));
typedef float floatx2 __attribute__((ext_vector_type(2)));

__device__ __forceinline__ unsigned short f2bf(float f) {
  unsigned int u = __builtin_bit_cast(unsigned int, f);
  return (unsigned short)((u + 0x7FFFu + ((u >> 16) & 1u)) >> 16);
}
__device__ __forceinline__ float bf2f(unsigned short h) {
  return __builtin_bit_cast(float, (unsigned int)h << 16);
}
__device__ __forceinline__ float2 bf2f2(unsigned int u) {
  float lo = __builtin_bit_cast(float, u << 16);
  float hi = __builtin_bit_cast(float, u & 0xFFFF0000u);
  return make_float2(lo, hi);
}

// ---------------- embedding gather -> bf16 residual ----------------
__global__ __launch_bounds__(256) void embed_kernel(
    const int* __restrict__ idx, const float* __restrict__ emb,
    unsigned short* __restrict__ xb)
{
  int gid = blockIdx.x * 256 + threadIdx.x;
  int n = gid >> 5;
  int c = (gid & 31) << 2;
  if (n >= N_NODES) return;
  int e = idx[n];
  float4 val = *(const float4*)(emb + (size_t)e * DIM + c);
  ushort4 pk;
  pk.x = f2bf(val.x); pk.y = f2bf(val.y); pk.z = f2bf(val.z); pk.w = f2bf(val.w);
  *(ushort4*)(xb + (size_t)n * DIM + c) = pk;
}

// ---------------- CSR build ----------------
// hist: one atomic pass; atomic return value = edge's rank within its dst node
__global__ __launch_bounds__(256) void hist_kernel(
    const int* __restrict__ e1, int* __restrict__ counts,
    int* __restrict__ rank)
{
  int i = blockIdx.x * 256 + threadIdx.x;
  if (i < N_EDGES) rank[i] = atomicAdd(&counts[e1[i]], 1);
}

__global__ __launch_bounds__(256) void scan_local(
    const int* __restrict__ counts, int* __restrict__ offsets,
    int* __restrict__ bsums)
{
  __shared__ int buf[256];
  int t = threadIdx.x;
  int i = blockIdx.x * 256 + t;
  int v = (i < N_NODES) ? counts[i] : 0;
  buf[t] = v;
  __syncthreads();
  int s = v;
#pragma unroll
  for (int off = 1; off < 256; off <<= 1) {
    int t2 = (t >= off) ? buf[t - off] : 0;
    __syncthreads();
    s += t2;
    buf[t] = s;
    __syncthreads();
  }
  if (i < N_NODES) offsets[i] = s - v;
  if (t == 255) bsums[blockIdx.x] = s;
}

__global__ void scan_bsums(int* __restrict__ bsums, int nblk)
{
  __shared__ int buf[256];
  int t = threadIdx.x;
  int v = (t < nblk) ? bsums[t] : 0;
  buf[t] = v;
  __syncthreads();
  int s = v;
#pragma unroll
  for (int off = 1; off < 256; off <<= 1) {
    int t2 = (t >= off) ? buf[t - off] : 0;
    __syncthreads();
    s += t2;
    buf[t] = s;
    __syncthreads();
  }
  if (t < nblk) bsums[t] = s - v;
}

__global__ __launch_bounds__(256) void scan_add(
    int* __restrict__ offsets, const int* __restrict__ bsums)
{
  int i = blockIdx.x * 256 + threadIdx.x;
  if (i < N_NODES) offsets[i] += bsums[blockIdx.x];
  if (i == 0) offsets[N_NODES] = N_EDGES;
}

// scatter: atomic-free (rank precomputed in hist)
__global__ __launch_bounds__(256) void scatter_kernel(
    const int* __restrict__ e0, const int* __restrict__ e1,
    const int* __restrict__ offsets, const int* __restrict__ rank,
    int* __restrict__ csr)
{
  int i = blockIdx.x * 256 + threadIdx.x;
  if (i >= N_EDGES) return;
  csr[offsets[e1[i]] + rank[i]] = e0[i];
}

// ---------------- combined weight prep (single-plane bf16, frag-major) ----------------
__global__ __launch_bounds__(256) void prep_all(
    const float* __restrict__ Wq, const float* __restrict__ Wk,
    const float* __restrict__ Wv, const float* __restrict__ Wo,
    const float* __restrict__ Wf1, const float* __restrict__ Wf2,
    unsigned short* __restrict__ wqkv, unsigned short* __restrict__ wo,
    unsigned short* __restrict__ wf1, unsigned short* __restrict__ wf2)
{
  int g = blockIdx.x * 256 + threadIdx.x;
  if (g < 18432) {
    int srcId = g / 6144; int rem = g - srcId * 6144;
    const float* W = (srcId == 0) ? Wq : (srcId == 1) ? Wk : Wv;
    int l = rem / 2048; int r2 = rem & 2047; int kq = r2 >> 7; int n = r2 & 127;
    const float* Wl = W + (size_t)l * 128 * 128;
    unsigned short* base = wqkv + (size_t)l * 128 * 384 + (size_t)(kq * 384 + srcId * 128 + n) * 8;
#pragma unroll
    for (int j = 0; j < 8; j++)
      base[j] = f2bf(Wl[(size_t)(kq * 8 + j) * 128 + n]);
    return;
  }
  g -= 18432;
  if (g < 6144) {
    int l = g / 2048; int r2 = g & 2047; int kq = r2 >> 7; int n = r2 & 127;
    const float* Wl = Wo + (size_t)l * 128 * 128;
    unsigned short* base = wo + (size_t)l * 128 * 128 + (size_t)(kq * 128 + n) * 8;
#pragma unroll
    for (int j = 0; j < 8; j++)
      base[j] = f2bf(Wl[(size_t)(kq * 8 + j) * 128 + n]);
    return;
  }
  g -= 6144;
  if (g < 12288) {
    int l = g / 4096; int r2 = g & 4095; int kq = r2 >> 8; int n = r2 & 255;
    const float* Wl = Wf1 + (size_t)l * 128 * 256;
    unsigned short* base = wf1 + (size_t)l * 128 * 256 + (size_t)(kq * 256 + n) * 8;
#pragma unroll
    for (int j = 0; j < 8; j++)
      base[j] = f2bf(Wl[(size_t)(kq * 8 + j) * 256 + n]);
    return;
  }
  g -= 12288;
  if (g < 12288) {
    int l = g / 4096; int r2 = g & 4095; int kq = r2 >> 7; int n = r2 & 127;
    const float* Wl = Wf2 + (size_t)l * 256 * 128;
    unsigned short* base = wf2 + (size_t)l * 256 * 128 + (size_t)(kq * 128 + n) * 8;
#pragma unroll
    for (int j = 0; j < 8; j++)
      base[j] = f2bf(Wl[(size_t)(kq * 8 + j) * 128 + n]);
  }
}

// ---------------- QKV GEMM (layer 0): q bf16, k/v fp8x8 into [N,256] layout ----------------
__global__ __launch_bounds__(256) void mfma_gemm_qkv(
    const unsigned short* __restrict__ Ab,
    const unsigned short* __restrict__ Wp,
    const float* __restrict__ bq, const float* __restrict__ bk,
    const float* __restrict__ bv,
    unsigned short* __restrict__ out, int nrows)
{
  constexpr int K = 128, N = 384, CT = 8;
  __shared__ unsigned short SW[16 * 128 * 8];   // 32 KB
  int tid = threadIdx.x;
  int cQ = blockIdx.y;          // 0=q, 1=k, 2=v
  int c0 = cQ * 128;
  const float* bias = (cQ == 0) ? bq : (cQ == 1) ? bk : bv;
  int wave = tid >> 6, lane = tid & 63;
  int quad = lane >> 4, l16 = lane & 15;
  int row0 = blockIdx.x * 128 + wave * 32;

  floatx4 acc[2][CT];
#pragma unroll
  for (int rt = 0; rt < 2; rt++)
#pragma unroll
    for (int ct = 0; ct < CT; ct++) acc[rt][ct] = (floatx4)(0.f);

  const unsigned short* arow[2];
#pragma unroll
  for (int rt = 0; rt < 2; rt++) {
    int r = min(row0 + rt * 16 + l16, nrows - 1);
    arow[rt] = Ab + (size_t)r * K + quad * 8;
  }
#pragma unroll 4
  for (int f = tid; f < 16 * 128; f += 256) {
    int kq = f >> 7;
    int n = f & 127;
    *(bf16x8*)&SW[f * 8] = *(const bf16x8*)&Wp[(size_t)(kq * N + c0 + n) * 8];
  }
  __syncthreads();
#pragma unroll
  for (int kb = 0; kb < 4; ++kb) {
    bf16x8 av[2];
#pragma unroll
    for (int rt = 0; rt < 2; rt++)
      av[rt] = *(const bf16x8*)(arow[rt] + kb * 32);
#pragma unroll
    for (int ct = 0; ct < CT; ct++) {
      bf16x8 bh = *(bf16x8*)&SW[((kb * 4 + quad) * 128 + ct * 16 + l16) * 8];
#pragma unroll
      for (int rt = 0; rt < 2; rt++)
        acc[rt][ct] = __builtin_amdgcn_mfma_f32_16x16x32_bf16(av[rt], bh, acc[rt][ct], 0, 0, 0);
    }
  }
#pragma unroll
  for (int ct = 0; ct < CT; ct++) {
    float bvv = bias[ct * 16 + l16];
#pragma unroll
    for (int rt = 0; rt < 2; rt++)
#pragma unroll
      for (int i = 0; i < 4; i++) {
        int r = row0 + rt * 16 + quad * 4 + i;
        float o = acc[rt][ct][i] + bvv;
        if (cQ == 0) {
          if (r < nrows)
            out[(size_t)r * 256 + ct * 16 + l16] = f2bf(o);
        } else {
          float o8 = o * 8.f;
          float nb = __shfl_xor(o8, 1);
          if (!(l16 & 1) && r < nrows) {
            int pk = __builtin_amdgcn_cvt_pk_fp8_f32(o8, nb, 0, false);
            out[(size_t)r * 256 + 128 + (cQ - 1) * 64 + ct * 8 + (l16 >> 1)] =
                (unsigned short)(pk & 0xffff);
          }
        }
      }
  }
}

// ================ chain1: O-GEMM + LN1 + FFN1 (4 waves x 16 rows) ================
#define LSTR 136
__global__ __launch_bounds__(256) void chain1_kernel(
    const unsigned short* __restrict__ a,
    const unsigned short* __restrict__ xb,
    unsigned short* __restrict__ xr,
    unsigned short* __restrict__ ffh,
    const unsigned short* __restrict__ wo, const float* __restrict__ bo,
    const float* __restrict__ g1, const float* __restrict__ be1,
    const unsigned short* __restrict__ wf1, const float* __restrict__ bf1,
    int nrows)
{
  __shared__ unsigned short Y[64 * LSTR];
  __shared__ unsigned short F[64 * LSTR];
  int tid = threadIdx.x;
  int wave = tid >> 6, lane = tid & 63;
  int quad = lane >> 4, l16 = lane & 15;
  int rbase = blockIdx.x * 64;
  int wrow = wave * 16;
  int rowg = min(rbase + wrow + l16, nrows - 1);
  int lrow_v = (wrow + l16) * LSTR + quad * 8;

#pragma unroll
  for (int kb = 0; kb < 4; kb++)
    *(bf16x8*)&F[lrow_v + kb * 32] =
        *(const bf16x8*)&xb[(size_t)rowg * 128 + kb * 32 + quad * 8];

  floatx4 accO[8];
#pragma unroll
  for (int cc = 0; cc < 8; cc++) accO[cc] = (floatx4)(0.f);
  {
    const unsigned short* arow = a + (size_t)rowg * 128 + quad * 8;
#pragma unroll
    for (int kb = 0; kb < 4; kb++) {
      bf16x8 av = *(const bf16x8*)(arow + kb * 32);
      int kq = kb * 4 + quad;
      bf16x8 bh[8];
#pragma unroll
      for (int cc = 0; cc < 8; cc++)
        bh[cc] = *(const bf16x8*)&wo[(size_t)(kq * 128 + cc * 16 + l16) * 8];
#pragma unroll
      for (int cc = 0; cc < 8; cc++)
        accO[cc] = __builtin_amdgcn_mfma_f32_16x16x32_bf16(av, bh[cc], accO[cc], 0, 0, 0);
    }
  }

  {
    float biasO[8], g1v[8], b1v[8];
#pragma unroll
    for (int cc = 0; cc < 8; cc++) {
      int col = cc * 16 + l16;
      biasO[cc] = bo[col]; g1v[cc] = g1[col]; b1v[cc] = be1[col];
    }
#pragma unroll
    for (int i = 0; i < 4; i++) {
      int lrow = wrow + quad * 4 + i;
      float t[8]; float s = 0.f;
#pragma unroll
      for (int cc = 0; cc < 8; cc++) {
        float yv = accO[cc][i] + biasO[cc];
        Y[lrow * LSTR + cc * 16 + l16] = f2bf(yv);
        t[cc] = yv + bf2f(F[lrow * LSTR + cc * 16 + l16]);
        s += t[cc];
      }
      s += __shfl_xor(s, 1); s += __shfl_xor(s, 2);
      s += __shfl_xor(s, 4); s += __shfl_xor(s, 8);
      float mean = s * (1.f / 128.f);
      float vv = 0.f;
#pragma unroll
      for (int cc = 0; cc < 8; cc++) { float d = t[cc] - mean; vv += d * d; }
      vv += __shfl_xor(vv, 1); vv += __shfl_xor(vv, 2);
      vv += __shfl_xor(vv, 4); vv += __shfl_xor(vv, 8);
      float inv = rsqrtf(vv * (1.f / 128.f) + 1e-5f);
#pragma unroll
      for (int cc = 0; cc < 8; cc++)
        F[lrow * LSTR + cc * 16 + l16] =
            f2bf((t[cc] - mean) * inv * g1v[cc] + b1v[cc]);
    }
  }
  if (rbase + wrow + l16 < nrows) {
#pragma unroll
    for (int kb = 0; kb < 4; kb++)
      *(bf16x8*)&xr[(size_t)(rbase + wrow + l16) * 128 + kb * 32 + quad * 8] =
          *(bf16x8*)&F[lrow_v + kb * 32];
  }

  bf16x8 avY[4];
#pragma unroll
  for (int kb = 0; kb < 4; kb++)
    avY[kb] = *(bf16x8*)&Y[lrow_v + kb * 32];
#pragma unroll
  for (int h = 0; h < 2; h++) {
    floatx4 accF[8];
#pragma unroll
    for (int cc = 0; cc < 8; cc++) accF[cc] = (floatx4)(0.f);
#pragma unroll
    for (int kb = 0; kb < 4; kb++) {
      int kq = kb * 4 + quad;
      bf16x8 bh[8];
#pragma unroll
      for (int cc = 0; cc < 8; cc++)
        bh[cc] = *(const bf16x8*)&wf1[(size_t)(kq * 256 + h * 128 + cc * 16 + l16) * 8];
#pragma unroll
      for (int cc = 0; cc < 8; cc++)
        accF[cc] = __builtin_amdgcn_mfma_f32_16x16x32_bf16(avY[kb], bh[cc], accF[cc], 0, 0, 0);
    }
#pragma unroll
    for (int i = 0; i < 4; i++) {
      int lrow = wrow + quad * 4 + i;
#pragma unroll
      for (int cc = 0; cc < 8; cc++)
        F[lrow * LSTR + cc * 16 + l16] =
            f2bf(fmaxf(accF[cc][i] + bf1[h * 128 + cc * 16 + l16], 0.f));
    }
    if (rbase + wrow + l16 < nrows) {
#pragma unroll
      for (int kb = 0; kb < 4; kb++)
        *(bf16x8*)&ffh[(size_t)(rbase + wrow + l16) * 256 + h * 128 + kb * 32 + quad * 8] =
            *(bf16x8*)&F[lrow_v + kb * 32];
    }
  }
}

// ================ chain2: FFN2 + LN2 + QKV(next, q bf16 + k/v fp8) ================
template<bool LAST>
__global__ __launch_bounds__(256) void chain2_kernel(
    const unsigned short* __restrict__ ffh,
    const unsigned short* __restrict__ xr,
    unsigned short* __restrict__ xb,
    unsigned short* __restrict__ qkv,
    const unsigned short* __restrict__ wf2, const float* __restrict__ bf2,
    const float* __restrict__ g2, const float* __restrict__ be2,
    const unsigned short* __restrict__ wqkv,
    const float* __restrict__ bq, const float* __restrict__ bk,
    const float* __restrict__ bv, int nrows)
{
  __shared__ unsigned short Y[64 * LSTR];
  __shared__ unsigned short XR[64 * LSTR];
  int tid = threadIdx.x;
  int wave = tid >> 6, lane = tid & 63;
  int quad = lane >> 4, l16 = lane & 15;
  int rbase = blockIdx.x * 64;
  int wrow = wave * 16;
  int rowg = min(rbase + wrow + l16, nrows - 1);
  int lrow_v = (wrow + l16) * LSTR + quad * 8;
  bool wr = (rbase + wrow + l16 < nrows);

#pragma unroll
  for (int kb = 0; kb < 4; kb++)
    *(bf16x8*)&XR[lrow_v + kb * 32] =
        *(const bf16x8*)&xr[(size_t)rowg * 128 + kb * 32 + quad * 8];

  floatx4 acc2[8];
#pragma unroll
  for (int cc = 0; cc < 8; cc++) acc2[cc] = (floatx4)(0.f);
  {
    const unsigned short* arow = ffh + (size_t)rowg * 256 + quad * 8;
#pragma unroll
    for (int h = 0; h < 2; h++) {
#pragma unroll
      for (int kb = 0; kb < 4; kb++) {
        bf16x8 av = *(const bf16x8*)(arow + h * 128 + kb * 32);
        int kq = h * 16 + kb * 4 + quad;
        bf16x8 bh[8];
#pragma unroll
        for (int cc = 0; cc < 8; cc++)
          bh[cc] = *(const bf16x8*)&wf2[(size_t)(kq * 128 + cc * 16 + l16) * 8];
#pragma unroll
        for (int cc = 0; cc < 8; cc++)
          acc2[cc] = __builtin_amdgcn_mfma_f32_16x16x32_bf16(av, bh[cc], acc2[cc], 0, 0, 0);
      }
    }
  }

  {
    float bias2[8], g2v[8], b2v[8];
#pragma unroll
    for (int cc = 0; cc < 8; cc++) {
      int col = cc * 16 + l16;
      bias2[cc] = bf2[col]; g2v[cc] = g2[col]; b2v[cc] = be2[col];
    }
#pragma unroll
    for (int i = 0; i < 4; i++) {
      int lrow = wrow + quad * 4 + i;
      float t[8]; float s = 0.f;
#pragma unroll
      for (int cc = 0; cc < 8; cc++) {
        t[cc] = acc2[cc][i] + bias2[cc] + bf2f(XR[lrow * LSTR + cc * 16 + l16]);
        s += t[cc];
      }
      s += __shfl_xor(s, 1); s += __shfl_xor(s, 2);
      s += __shfl_xor(s, 4); s += __shfl_xor(s, 8);
      float mean = s * (1.f / 128.f);
      float vv = 0.f;
#pragma unroll
      for (int cc = 0; cc < 8; cc++) { float d = t[cc] - mean; vv += d * d; }
      vv += __shfl_xor(vv, 1); vv += __shfl_xor(vv, 2);
      vv += __shfl_xor(vv, 4); vv += __shfl_xor(vv, 8);
      float inv = rsqrtf(vv * (1.f / 128.f) + 1e-5f);
#pragma unroll
      for (int cc = 0; cc < 8; cc++)
        Y[lrow * LSTR + cc * 16 + l16] =
            f2bf((t[cc] - mean) * inv * g2v[cc] + b2v[cc]);
    }
  }
  if (wr) {
#pragma unroll
    for (int kb = 0; kb < 4; kb++)
      *(bf16x8*)&xb[(size_t)(rbase + wrow + l16) * 128 + kb * 32 + quad * 8] =
          *(bf16x8*)&Y[lrow_v + kb * 32];
  }

  if (!LAST) {
    bf16x8 avQ[4];
#pragma unroll
    for (int kb = 0; kb < 4; kb++)
      avQ[kb] = *(bf16x8*)&Y[lrow_v + kb * 32];
#pragma unroll
    for (int c = 0; c < 3; c++) {
      floatx4 accQ[8];
#pragma unroll
      for (int ct = 0; ct < 8; ct++) accQ[ct] = (floatx4)(0.f);
#pragma unroll
      for (int kb = 0; kb < 4; kb++) {
        int kq = kb * 4 + quad;
        bf16x8 bh[8];
#pragma unroll
        for (int ct = 0; ct < 8; ct++)
          bh[ct] = *(const bf16x8*)&wqkv[(size_t)(kq * 384 + c * 128 + ct * 16 + l16) * 8];
#pragma unroll
        for (int ct = 0; ct < 8; ct++)
          accQ[ct] = __builtin_amdgcn_mfma_f32_16x16x32_bf16(avQ[kb], bh[ct], accQ[ct], 0, 0, 0);
      }
      const float* bias = (c == 0) ? bq : (c == 1) ? bk : bv;
#pragma unroll
      for (int ct = 0; ct < 8; ct++) {
        float bvv = bias[ct * 16 + l16];
#pragma unroll
        for (int i = 0; i < 4; i++)
          XR[(wrow + quad * 4 + i) * LSTR + ct * 16 + l16] = f2bf(accQ[ct][i] + bvv);
      }
      if (wr) {
        if (c == 0) {
#pragma unroll
          for (int kb = 0; kb < 4; kb++)
            *(bf16x8*)&qkv[(size_t)(rbase + wrow + l16) * 256 + kb * 32 + quad * 8] =
                *(bf16x8*)&XR[lrow_v + kb * 32];
        } else {
#pragma unroll
          for (int kb = 0; kb < 4; kb++) {
            bf16x8 w = *(bf16x8*)&XR[lrow_v + kb * 32];
            int p0 = __builtin_amdgcn_cvt_pk_fp8_f32(
                bf2f((unsigned short)w[0]) * 8.f, bf2f((unsigned short)w[1]) * 8.f, 0, false);
            int p1 = __builtin_amdgcn_cvt_pk_fp8_f32(
                bf2f((unsigned short)w[2]) * 8.f, bf2f((unsigned short)w[3]) * 8.f, 0, false);
            int p2 = __builtin_amdgcn_cvt_pk_fp8_f32(
                bf2f((unsigned short)w[4]) * 8.f, bf2f((unsigned short)w[5]) * 8.f, 0, false);
            int p3 = __builtin_amdgcn_cvt_pk_fp8_f32(
                bf2f((unsigned short)w[6]) * 8.f, bf2f((unsigned short)w[7]) * 8.f, 0, false);
            int2 st;
            st.x = (p0 & 0xffff) | (p1 << 16);
            st.y = (p2 & 0xffff) | (p3 << 16);
            *(int2*)&qkv[(size_t)(rbase + wrow + l16) * 256 + 128 + (c - 1) * 64 +
                         kb * 16 + quad * 4] = st;
          }
        }
      }
    }
  }
}
#undef LSTR

// ---------------- fused edge attention: fp8 k/v (scale 8), one wave per node, x8 unroll ----------------
#define ATTN_C8 0.04508422003f   // 0.25*log2(e)/8
#define ATTN_L  7.21347520444f
__device__ __forceinline__ float edge_score8(float p) {
  float t = fminf(fmaxf(p * ATTN_C8, -ATTN_L), ATTN_L);
  return __builtin_amdgcn_exp2f(t);
}
__global__ __launch_bounds__(256) void attn_kernel(
    const unsigned short* __restrict__ qkv,
    const int* __restrict__ offsets, const int* __restrict__ csr,
    unsigned short* __restrict__ attn)
{
  int node = blockIdx.x * 4 + (threadIdx.x >> 6);
  int lane = threadIdx.x & 63;
  if (node >= N_NODES) return;
  float2 q2 = bf2f2(*(const unsigned int*)(qkv + (size_t)node * 256 + lane * 2));
  const unsigned short* kb8 = qkv + 128 + lane;
  const unsigned short* vb8 = qkv + 192 + lane;
  float wx = 0.f, wy = 0.f, z = 0.f;
  int j = offsets[node], end = offsets[node + 1];
  for (; j + 8 <= end; j += 8) {
    int s[8];
#pragma unroll
    for (int u = 0; u < 8; u++) s[u] = csr[j + u];
    unsigned short ku[8], vu[8];
#pragma unroll
    for (int u = 0; u < 8; u++) {
      ku[u] = kb8[(size_t)s[u] * 256];
      vu[u] = vb8[(size_t)s[u] * 256];
    }
    float p[8];
#pragma unroll
    for (int u = 0; u < 8; u++) {
      floatx2 kf = __builtin_amdgcn_cvt_pk_f32_fp8((int)ku[u], false);
      p[u] = kf[0] * q2.x + kf[1] * q2.y;
    }
#pragma unroll
    for (int u = 0; u < 8; u++) p[u] += __shfl_xor(p[u], 1);
#pragma unroll
    for (int u = 0; u < 8; u++) p[u] += __shfl_xor(p[u], 2);
#pragma unroll
    for (int u = 0; u < 8; u++) p[u] += __shfl_xor(p[u], 4);
#pragma unroll
    for (int u = 0; u < 8; u++) {
      float sc = edge_score8(p[u]);
      floatx2 vf = __builtin_amdgcn_cvt_pk_f32_fp8((int)vu[u], false);
      wx = fmaf(sc, vf[0], wx);
      wy = fmaf(sc, vf[1], wy);
      z += sc;
    }
  }
  for (; j < end; ++j) {
    int s = csr[j];
    floatx2 kf = __builtin_amdgcn_cvt_pk_f32_fp8((int)kb8[(size_t)s * 256], false);
    float p = kf[0] * q2.x + kf[1] * q2.y;
    p += __shfl_xor(p, 1); p += __shfl_xor(p, 2); p += __shfl_xor(p, 4);
    float sc = edge_score8(p);
    floatx2 vf = __builtin_amdgcn_cvt_pk_f32_fp8((int)vb8[(size_t)s * 256], false);
    wx = fmaf(sc, vf[0], wx); wy = fmaf(sc, vf[1], wy);
    z += sc;
  }
  float inv = 1.f / (8.f * z + 8e-6f);
  unsigned int pack = (unsigned int)f2bf(wx * inv) | ((unsigned int)f2bf(wy * inv) << 16);
  *(unsigned int*)(attn + (size_t)node * DIM + lane * 2) = pack;
}

// ---------------- column mean over nodes (bf16 in, fp32 acc) ----------------
__global__ __launch_bounds__(256) void colmean_kernel(
    const unsigned short* __restrict__ xb, float* __restrict__ mean)
{
  int col = threadIdx.x & 127;
  int half = threadIdx.x >> 7;
  float acc = 0.f;
  for (int r = blockIdx.x * 2 + half; r < N_NODES; r += gridDim.x * 2)
    acc += bf2f(xb[(size_t)r * DIM + col]);
  __shared__ float s[256];
  s[threadIdx.x] = acc;
  __syncthreads();
  if (threadIdx.x < 128) atomicAdd(&mean[col], s[threadIdx.x] + s[threadIdx.x + 128]);
}

// ---------------- readout MLP 128->64->32->10 ----------------
__global__ void readout_kernel(
    const float* __restrict__ mean,
    const float* __restrict__ mW0, const float* __restrict__ mb0,
    const float* __restrict__ mW1, const float* __restrict__ mb1,
    const float* __restrict__ mW2, const float* __restrict__ mb2,
    float* __restrict__ out)
{
  __shared__ float sx[128], h0[64], h1[32];
  int t = threadIdx.x;
  sx[t] = mean[t] * (1.f / (float)N_NODES);
  __syncthreads();
  if (t < 64) {
    float a = mb0[t];
    for (int i = 0; i < 128; i++) a = fmaf(sx[i], mW0[i * 64 + t], a);
    h0[t] = fmaxf(a, 0.f);
  }
  __syncthreads();
  if (t < 32) {
    float a = mb1[t];
    for (int i = 0; i < 64; i++) a = fmaf(h0[i], mW1[i * 32 + t], a);
    h1[t] = fmaxf(a, 0.f);
  }
  __syncthreads();
  if (t < 10) {
    float a = mb2[t];
    for (int i = 0; i < 32; i++) a = fmaf(h1[i], mW2[i * 10 + t], a);
    out[t] = a;
  }
}

extern "C" void kernel_launch(void* const* d_in, const int* in_sizes, int n_in,
                              void* d_out, int out_size, void* d_ws, size_t ws_size,
                              hipStream_t stream) {
  const int*   x_idx = (const int*)d_in[0];
  const int*   eidx  = (const int*)d_in[1];
  const float* emb   = (const float*)d_in[2];
  const float* Wq = (const float*)d_in[3];  const float* bq = (const float*)d_in[4];
  const float* Wk = (const float*)d_in[5];  const float* bk = (const float*)d_in[6];
  const float* Wv = (const float*)d_in[7];  const float* bv = (const float*)d_in[8];
  const float* Wo = (const float*)d_in[9];  const float* bo = (const float*)d_in[10];
  const float* g1 = (const float*)d_in[11]; const float* be1 = (const float*)d_in[12];
  const float* Wf1 = (const float*)d_in[13]; const float* bf1 = (const float*)d_in[14];
  const float* Wf2 = (const float*)d_in[15]; const float* bf2 = (const float*)d_in[16];
  const float* g2 = (const float*)d_in[17]; const float* be2 = (const float*)d_in[18];
  const float* mW0 = (const float*)d_in[19]; const float* mb0 = (const float*)d_in[20];
  const float* mW1 = (const float*)d_in[21]; const float* mb1 = (const float*)d_in[22];
  const float* mW2 = (const float*)d_in[23]; const float* mb2 = (const float*)d_in[24];
  float* out = (float*)d_out;

  const size_t NX = (size_t)N_NODES * DIM;
  unsigned short* xb  = (unsigned short*)d_ws;
  unsigned short* qkv = xb + NX;                        // [N,256] q|k8|v8
  unsigned short* a   = qkv + (size_t)N_NODES * 256;
  unsigned short* xr  = a + NX;
  unsigned short* ffh = xr + NX;

  unsigned short* wqkv_p = ffh + (size_t)N_NODES * 256;
  unsigned short* wo_p   = wqkv_p + 3 * 128 * 384;
  unsigned short* wf1_p  = wo_p   + 3 * 128 * 128;
  unsigned short* wf2_p  = wf1_p  + 3 * 128 * 256;
  unsigned short* wend   = wf2_p  + 3 * 256 * 128;

  int* counts  = (int*)wend;
  float* meanb = (float*)(counts + N_NODES);
  int* offsets = (int*)(meanb + DIM);
  int* bsums   = offsets + N_NODES + 1;
  int* csr     = bsums + 256;
  int* rank    = csr + N_EDGES;

  const int* e0 = eidx;
  const int* e1 = eidx + N_EDGES;

  hipMemsetAsync(counts, 0, (N_NODES + DIM) * sizeof(int), stream);

  prep_all<<<192, 256, 0, stream>>>(Wq, Wk, Wv, Wo, Wf1, Wf2,
                                    wqkv_p, wo_p, wf1_p, wf2_p);

  embed_kernel<<<(N_NODES * 32 + 255) / 256, 256, 0, stream>>>(x_idx, emb, xb);
  hist_kernel<<<(N_EDGES + 255) / 256, 256, 0, stream>>>(e1, counts, rank);
  int nblk = (N_NODES + 255) / 256;
  scan_local<<<nblk, 256, 0, stream>>>(counts, offsets, bsums);
  scan_bsums<<<1, 256, 0, stream>>>(bsums, nblk);
  scan_add<<<nblk, 256, 0, stream>>>(offsets, bsums);
  scatter_kernel<<<(N_EDGES + 255) / 256, 256, 0, stream>>>(e0, e1, offsets, rank, csr);

  int gx = (N_NODES + 127) / 128;
  int gc = (N_NODES + 63) / 64;
  int nb4 = (N_NODES + 3) / 4;

  mfma_gemm_qkv<<<dim3(gx, 3), 256, 0, stream>>>(xb, wqkv_p, bq, bk, bv, qkv, N_NODES);

  for (int l = 0; l < NLAYERS; ++l) {
    const unsigned short* wo_l   = wo_p   + (size_t)l * 128 * 128;
    const unsigned short* wf1_l  = wf1_p  + (size_t)l * 128 * 256;
    const unsigned short* wf2_l  = wf2_p  + (size_t)l * 256 * 128;
    const unsigned short* wqkv_n = wqkv_p + (size_t)(l + 1) * 128 * 384;
    const float* bo_l  = bo  + (size_t)l * DIM;
    const float* g1_l  = g1  + (size_t)l * DIM;
    const float* be1_l = be1 + (size_t)l * DIM;
    const float* bf1_l = bf1 + (size_t)l * 2 * DIM;
    const float* bf2_l = bf2 + (size_t)l * DIM;
    const float* g2_l  = g2  + (size_t)l * DIM;
    const float* be2_l = be2 + (size_t)l * DIM;

    attn_kernel<<<nb4, 256, 0, stream>>>(qkv, offsets, csr, a);
    chain1_kernel<<<gc, 256, 0, stream>>>(
        a, xb, xr, ffh, wo_l, bo_l, g1_l, be1_l, wf1_l, bf1_l, N_NODES);
    if (l < NLAYERS - 1) {
      chain2_kernel<false><<<gc, 256, 0, stream>>>(
          ffh, xr, xb, qkv, wf2_l, bf2_l, g2_l, be2_l, wqkv_n,
          bq + (size_t)(l + 1) * DIM, bk + (size_t)(l + 1) * DIM,
          bv + (size_t)(l + 1) * DIM, N_NODES);
    } else {
      chain2_kernel<true><<<gc, 256, 0, stream>>>(
          ffh, xr, xb, qkv, wf2_l, bf2_l, g2_l, be2_l, wqkv_p,
          bq, bk, bv, N_NODES);
    }
  }

  colmean_kernel<<<128, 256, 0, stream>>>(xb, meanb);
  readout_kernel<<<1, 128, 0, stream>>>(meanb, mW0, mb0, mW1, mb1, mW2, mb2, out);
}